// Round 7
// baseline (455.332 us; speedup 1.0000x reference)
//
#include <hip/hip_runtime.h>
#include <math.h>

// ---------------------------------------------------------------------------
// HOGGraphNet: 2x GCNConv(+LN+ReLU) -> GATConv(4 heads, mean) -> mean/max pool
// N=50000, E=600000, D=128, H=4, G=64. CSR gather-side aggregation.
// bf16 feature pipeline; GEMMs on MFMA (16x16x32 bf16, fp32 accumulate).
// Gathers: 16B/lane, multi-edge in flight (latency hiding).
// ---------------------------------------------------------------------------

#define TPB 256

typedef __attribute__((ext_vector_type(8))) short short8;
typedef __attribute__((ext_vector_type(4))) float f32x4;
union U4S8 { uint4 u; short8 s; };

__device__ __forceinline__ float lrelu(float x) { return x > 0.f ? x : 0.2f * x; }

__device__ __forceinline__ unsigned short f2bf(float f) {  // RTNE
    unsigned int u = __float_as_uint(f);
    u += 0x7fffu + ((u >> 16) & 1u);
    return (unsigned short)(u >> 16);
}
__device__ __forceinline__ float2 bf2x(unsigned int u) {   // [lo,hi] bf16 pair
    return make_float2(__uint_as_float(u << 16), __uint_as_float(u & 0xffff0000u));
}
__device__ __forceinline__ float sel4(float4 v, int h) {
    float r = v.x;
    r = (h == 1) ? v.y : r;
    r = (h == 2) ? v.z : r;
    r = (h == 3) ? v.w : r;
    return r;
}

// ---------------- CSR build ----------------
__global__ __launch_bounds__(TPB) void k_hist(const int* __restrict__ dst,
                                              int* __restrict__ deg, int e) {
    int i = blockIdx.x * TPB + threadIdx.x;
    if (i < e) atomicAdd(&deg[dst[i]], 1);
}

__global__ __launch_bounds__(TPB) void k_scan_part(const int* __restrict__ deg,
                                                   int* __restrict__ part, int n) {
    int i = blockIdx.x * TPB + threadIdx.x;
    int v = (i < n) ? deg[i] : 0;
#pragma unroll
    for (int o = 32; o > 0; o >>= 1) v += __shfl_xor(v, o);
    __shared__ int sw[4];
    if ((threadIdx.x & 63) == 0) sw[threadIdx.x >> 6] = v;
    __syncthreads();
    if (threadIdx.x == 0) part[blockIdx.x] = sw[0] + sw[1] + sw[2] + sw[3];
}

__global__ __launch_bounds__(TPB) void k_scan_top(int* __restrict__ part, int nb) {
    __shared__ int sm[TPB];
    int t = threadIdx.x;
    int v = (t < nb) ? part[t] : 0;
    sm[t] = v;
    __syncthreads();
    for (int off = 1; off < TPB; off <<= 1) {
        int u = (t >= off) ? sm[t - off] : 0;
        __syncthreads();
        sm[t] += u;
        __syncthreads();
    }
    if (t < nb) part[t] = sm[t] - v;  // exclusive
}

__global__ __launch_bounds__(TPB) void k_scan_apply(const int* __restrict__ deg,
                                                    const int* __restrict__ part,
                                                    int* __restrict__ row_start,
                                                    int* __restrict__ cursor,
                                                    float* __restrict__ dis,
                                                    int n, int e_total) {
    __shared__ int sm[TPB];
    int i = blockIdx.x * TPB + threadIdx.x;
    int t = threadIdx.x;
    int d = (i < n) ? deg[i] : 0;
    sm[t] = d;
    __syncthreads();
    for (int off = 1; off < TPB; off <<= 1) {
        int u = (t >= off) ? sm[t - off] : 0;
        __syncthreads();
        sm[t] += u;
        __syncthreads();
    }
    if (i < n) {
        int rs = part[blockIdx.x] + sm[t] - d;
        row_start[i] = rs;
        cursor[i] = rs;
        dis[i] = rsqrtf((float)(d + 1));
    }
    if (blockIdx.x == 0 && t == 0) row_start[n] = e_total;
}

__global__ __launch_bounds__(TPB) void k_scatter(const int* __restrict__ src,
                                                 const int* __restrict__ dst,
                                                 int* __restrict__ cursor,
                                                 int* __restrict__ csr_src, int e) {
    int i = blockIdx.x * TPB + threadIdx.x;
    if (i < e) {
        int p = atomicAdd(&cursor[dst[i]], 1);
        csr_src[p] = src[i];
    }
}

// ---------------- conversions ----------------
__global__ __launch_bounds__(TPB) void k_f2bf(const float* __restrict__ in,
                                              unsigned short* __restrict__ out, int n4) {
    int i = blockIdx.x * TPB + threadIdx.x;
    if (i >= n4) return;
    float4 v = ((const float4*)in)[i];
    unsigned int p0 = (unsigned int)f2bf(v.x) | ((unsigned int)f2bf(v.y) << 16);
    unsigned int p1 = (unsigned int)f2bf(v.z) | ((unsigned int)f2bf(v.w) << 16);
    ((uint2*)out)[i] = make_uint2(p0, p1);
}

__global__ __launch_bounds__(TPB) void k_wt(const float* __restrict__ W,
                                            unsigned short* __restrict__ Wt, int ocols) {
    int i = blockIdx.x * TPB + threadIdx.x;
    if (i >= 128 * ocols) return;
    int k = i / ocols, n = i - k * ocols;
    Wt[n * 128 + k] = f2bf(W[i]);
}

// ---------------- MFMA GEMM: C[node][chan] = feat[node][:] . Wt[chan][:] ----
__global__ __launch_bounds__(TPB, 2) void k_gemm_mfma(const unsigned short* __restrict__ feat,
                                                      const unsigned short* __restrict__ Wt,
                                                      unsigned short* __restrict__ C,
                                                      int nrows, int ocols) {
    __shared__ uint4 wl[2048];
    int t = threadIdx.x;
    int cb = blockIdx.y << 7;
#pragma unroll
    for (int i = 0; i < 8; ++i) {
        int fi = i * 256 + t;
        int l = fi & 63, ct = (fi >> 6) & 7, ks = fi >> 9;
        int chan = cb + ct * 16 + (l & 15);
        wl[fi] = ((const uint4*)(Wt + (size_t)chan * 128))[ks * 4 + (l >> 4)];
    }
    __syncthreads();

    int wave = t >> 6, lane = t & 63;
    int wr = wave >> 1, wc = wave & 1;
    int nbase = (blockIdx.x << 7) + (wc << 6);
    const uint4* brow[4];
#pragma unroll
    for (int nt = 0; nt < 4; ++nt) {
        int node = nbase + nt * 16 + (lane & 15);
        node = node < nrows ? node : (nrows - 1);
        brow[nt] = (const uint4*)(feat + (size_t)node * 128);
    }
    f32x4 acc[4][4];
#pragma unroll
    for (int mt = 0; mt < 4; ++mt)
#pragma unroll
        for (int nt = 0; nt < 4; ++nt) acc[mt][nt] = (f32x4)0.f;

    int kq = lane >> 4;
#pragma unroll
    for (int ks = 0; ks < 4; ++ks) {
        U4S8 a[4], b[4];
#pragma unroll
        for (int mt = 0; mt < 4; ++mt)
            a[mt].u = wl[(ks * 8 + wr * 4 + mt) * 64 + lane];
#pragma unroll
        for (int nt = 0; nt < 4; ++nt)
            b[nt].u = brow[nt][ks * 4 + kq];
#pragma unroll
        for (int mt = 0; mt < 4; ++mt)
#pragma unroll
            for (int nt = 0; nt < 4; ++nt)
                acc[mt][nt] = __builtin_amdgcn_mfma_f32_16x16x32_bf16(
                    a[mt].s, b[nt].s, acc[mt][nt], 0, 0, 0);
    }
#pragma unroll
    for (int nt = 0; nt < 4; ++nt) {
        int node = nbase + nt * 16 + (lane & 15);
        if (node >= nrows) continue;
#pragma unroll
        for (int mt = 0; mt < 4; ++mt) {
            int chan = cb + (wr << 6) + mt * 16 + (lane >> 4) * 4;
            f32x4 v = acc[mt][nt];
            unsigned int p0 = (unsigned int)f2bf(v.x) | ((unsigned int)f2bf(v.y) << 16);
            unsigned int p1 = (unsigned int)f2bf(v.z) | ((unsigned int)f2bf(v.w) << 16);
            *(uint2*)(C + (size_t)node * ocols + chan) = make_uint2(p0, p1);
        }
    }
}

// ---------------- fused GCN: 16B/lane gather (4 edges/iter) + LN + ReLU -----
// wave per node; lane = (quarter q=lane>>4, fl=lane&15); 8 feats/lane.
__global__ __launch_bounds__(TPB) void k_gcn_fused(const unsigned short* __restrict__ hb,
                                                   const int* __restrict__ csr_src,
                                                   const int* __restrict__ row_start,
                                                   const float* __restrict__ dis,
                                                   const float* __restrict__ b,
                                                   const float* __restrict__ g,
                                                   const float* __restrict__ beta,
                                                   unsigned short* __restrict__ out, int n) {
    __shared__ int   ssrc[4][64];
    __shared__ float swt[4][64];
    int node = (blockIdx.x * TPB + threadIdx.x) >> 6;
    int lane = threadIdx.x & 63;
    int wid = threadIdx.x >> 6;
    if (node >= n) return;
    int s0 = row_start[node], s1 = row_start[node + 1];
    float dn = dis[node];
    const uint4* hq = (const uint4*)hb;   // row = 16 uint4 (128 bf16)
    int q = lane >> 4, fl = lane & 15;
    float acc[8];
#pragma unroll
    for (int i = 0; i < 8; ++i) acc[i] = 0.f;
    for (int base = s0; base < s1; base += 64) {
        int cnt = min(64, s1 - base);
        int sidx = 0; float w = 0.f;
        if (lane < cnt) { sidx = csr_src[base + lane]; w = dis[sidx]; }
        ssrc[wid][lane] = sidx;
        swt[wid][lane] = w;
        for (int j = 0; j < cnt; j += 4) {
            int jj = j + q;                     // 4 edges per wave-iteration
            int ok = jj < cnt;
            int s = ssrc[wid][ok ? jj : 0];
            float wj = ok ? swt[wid][jj] : 0.f;
            uint4 u = hq[(size_t)s * 16 + fl];
            float2 p0 = bf2x(u.x), p1 = bf2x(u.y), p2 = bf2x(u.z), p3 = bf2x(u.w);
            acc[0] += wj * p0.x; acc[1] += wj * p0.y;
            acc[2] += wj * p1.x; acc[3] += wj * p1.y;
            acc[4] += wj * p2.x; acc[5] += wj * p2.y;
            acc[6] += wj * p3.x; acc[7] += wj * p3.y;
        }
    }
    // combine quarters: lanes with same fl hold disjoint edge subsets
#pragma unroll
    for (int i = 0; i < 8; ++i) {
        acc[i] += __shfl_xor(acc[i], 16);
        acc[i] += __shfl_xor(acc[i], 32);
    }
    float sl = dn * dn;
    uint4 us = hq[(size_t)node * 16 + fl];
    float2 h0 = bf2x(us.x), h1 = bf2x(us.y), h2 = bf2x(us.z), h3 = bf2x(us.w);
    float4 b0 = ((const float4*)b)[fl * 2], b1 = ((const float4*)b)[fl * 2 + 1];
    float v[8];
    v[0] = dn * acc[0] + sl * h0.x + b0.x;
    v[1] = dn * acc[1] + sl * h0.y + b0.y;
    v[2] = dn * acc[2] + sl * h1.x + b0.z;
    v[3] = dn * acc[3] + sl * h1.y + b0.w;
    v[4] = dn * acc[4] + sl * h2.x + b1.x;
    v[5] = dn * acc[5] + sl * h2.y + b1.y;
    v[6] = dn * acc[6] + sl * h3.x + b1.z;
    v[7] = dn * acc[7] + sl * h3.y + b1.w;
    float s = 0.f, sq = 0.f;
#pragma unroll
    for (int i = 0; i < 8; ++i) { s += v[i]; sq += v[i] * v[i]; }
#pragma unroll
    for (int o = 8; o > 0; o >>= 1) {
        s  += __shfl_xor(s, o);
        sq += __shfl_xor(sq, o);
    }
    float mu = s * (1.f / 128.f);
    float var = sq * (1.f / 128.f) - mu * mu;
    float rstd = rsqrtf(var + 1e-5f);
    float4 g0  = ((const float4*)g)[fl * 2],    g1v = ((const float4*)g)[fl * 2 + 1];
    float4 bt0 = ((const float4*)beta)[fl * 2], bt1 = ((const float4*)beta)[fl * 2 + 1];
    float o0 = fmaxf((v[0] - mu) * rstd * g0.x + bt0.x, 0.f);
    float o1 = fmaxf((v[1] - mu) * rstd * g0.y + bt0.y, 0.f);
    float o2 = fmaxf((v[2] - mu) * rstd * g0.z + bt0.z, 0.f);
    float o3 = fmaxf((v[3] - mu) * rstd * g0.w + bt0.w, 0.f);
    float o4 = fmaxf((v[4] - mu) * rstd * g1v.x + bt1.x, 0.f);
    float o5 = fmaxf((v[5] - mu) * rstd * g1v.y + bt1.y, 0.f);
    float o6 = fmaxf((v[6] - mu) * rstd * g1v.z + bt1.z, 0.f);
    float o7 = fmaxf((v[7] - mu) * rstd * g1v.w + bt1.w, 0.f);
    if (q == 0) {
        uint4 pk;
        pk.x = (unsigned int)f2bf(o0) | ((unsigned int)f2bf(o1) << 16);
        pk.y = (unsigned int)f2bf(o2) | ((unsigned int)f2bf(o3) << 16);
        pk.z = (unsigned int)f2bf(o4) | ((unsigned int)f2bf(o5) << 16);
        pk.w = (unsigned int)f2bf(o6) | ((unsigned int)f2bf(o7) << 16);
        ((uint4*)out)[(size_t)node * 16 + fl] = pk;
    }
}

// ---------------- GAT attention dots (bf16 hg) ------------------------------
__global__ __launch_bounds__(TPB) void k_att_dots(const unsigned short* __restrict__ hgb,
                                                  const float* __restrict__ att_s,
                                                  const float* __restrict__ att_d,
                                                  float* __restrict__ a_s,
                                                  float* __restrict__ a_d, int n) {
    int wave = (blockIdx.x * TPB + threadIdx.x) >> 6;
    int lane = threadIdx.x & 63;
    if (wave >= n) return;
    int h = lane >> 4, j = lane & 15;
    const uint4* hq = (const uint4*)hgb;
    uint4 u = hq[(size_t)wave * 64 + lane];
    float2 p0 = bf2x(u.x), p1 = bf2x(u.y), p2 = bf2x(u.z), p3 = bf2x(u.w);
    const float4* s4 = (const float4*)(att_s + h * 128 + j * 8);
    const float4* d4 = (const float4*)(att_d + h * 128 + j * 8);
    float4 s0 = s4[0], s1 = s4[1];
    float4 d0 = d4[0], d1 = d4[1];
    float ps = p0.x * s0.x + p0.y * s0.y + p1.x * s0.z + p1.y * s0.w
             + p2.x * s1.x + p2.y * s1.y + p3.x * s1.z + p3.y * s1.w;
    float pd = p0.x * d0.x + p0.y * d0.y + p1.x * d0.z + p1.y * d0.w
             + p2.x * d1.x + p2.y * d1.y + p3.x * d1.z + p3.y * d1.w;
#pragma unroll
    for (int o = 8; o > 0; o >>= 1) {
        ps += __shfl_xor(ps, o);
        pd += __shfl_xor(pd, o);
    }
    if (j == 0) {
        a_s[wave * 4 + h] = ps;
        a_d[wave * 4 + h] = pd;
    }
}

// ---------------- fused GAT: softmax + gather (x4 unroll) + bias/relu -------
__global__ __launch_bounds__(TPB) void k_gat_fused(const unsigned short* __restrict__ hgb,
                                                   const float* __restrict__ a_s,
                                                   const float* __restrict__ a_d,
                                                   const int* __restrict__ csr_src,
                                                   const int* __restrict__ row_start,
                                                   const float* __restrict__ gat_b,
                                                   float* __restrict__ node_out, int n) {
    __shared__ int   ssrc[4][64];
    __shared__ float swt[4][4][65];
    int node = (blockIdx.x * TPB + threadIdx.x) >> 6;
    int lane = threadIdx.x & 63;
    int wid = threadIdx.x >> 6;
    if (node >= n) return;
    int s0 = row_start[node], s1 = row_start[node + 1];
    int h = lane >> 4;
    const float4* as4 = (const float4*)a_s;
    float4 ad = ((const float4*)a_d)[node];
    float4 asn = as4[node];
    float4 wself;
    wself.x = __expf(lrelu(asn.x + ad.x));
    wself.y = __expf(lrelu(asn.y + ad.y));
    wself.z = __expf(lrelu(asn.z + ad.z));
    wself.w = __expf(lrelu(asn.w + ad.w));
    const uint4* hq = (const uint4*)hgb;
    float acc[8];
    {
        float wsh = sel4(wself, h);
        uint4 u = hq[(size_t)node * 64 + lane];
        float2 p0 = bf2x(u.x), p1 = bf2x(u.y), p2 = bf2x(u.z), p3 = bf2x(u.w);
        acc[0] = wsh * p0.x; acc[1] = wsh * p0.y;
        acc[2] = wsh * p1.x; acc[3] = wsh * p1.y;
        acc[4] = wsh * p2.x; acc[5] = wsh * p2.y;
        acc[6] = wsh * p3.x; acc[7] = wsh * p3.y;
    }
    float4 den = make_float4(0.f, 0.f, 0.f, 0.f);
    for (int base = s0; base < s1; base += 64) {
        int cnt = min(64, s1 - base);
        int sidx = 0;
        float4 w4 = make_float4(0.f, 0.f, 0.f, 0.f);
        if (lane < cnt) {
            sidx = csr_src[base + lane];
            float4 a = as4[sidx];
            w4.x = __expf(lrelu(a.x + ad.x));
            w4.y = __expf(lrelu(a.y + ad.y));
            w4.z = __expf(lrelu(a.z + ad.z));
            w4.w = __expf(lrelu(a.w + ad.w));
            den.x += w4.x; den.y += w4.y; den.z += w4.z; den.w += w4.w;
        }
        ssrc[wid][lane] = sidx;
        swt[wid][0][lane] = w4.x;
        swt[wid][1][lane] = w4.y;
        swt[wid][2][lane] = w4.z;
        swt[wid][3][lane] = w4.w;
        int j = 0;
        for (; j + 4 <= cnt; j += 4) {   // 4 independent 1KB row loads in flight
            int sa = ssrc[wid][j + 0], sb = ssrc[wid][j + 1];
            int sc = ssrc[wid][j + 2], sd = ssrc[wid][j + 3];
            float wa = swt[wid][h][j + 0], wb = swt[wid][h][j + 1];
            float wc = swt[wid][h][j + 2], wd = swt[wid][h][j + 3];
            uint4 ua = hq[(size_t)sa * 64 + lane];
            uint4 ub = hq[(size_t)sb * 64 + lane];
            uint4 uc = hq[(size_t)sc * 64 + lane];
            uint4 ud = hq[(size_t)sd * 64 + lane];
            float2 p0, p1, p2, p3;
            p0 = bf2x(ua.x); p1 = bf2x(ua.y); p2 = bf2x(ua.z); p3 = bf2x(ua.w);
            acc[0] += wa * p0.x; acc[1] += wa * p0.y; acc[2] += wa * p1.x; acc[3] += wa * p1.y;
            acc[4] += wa * p2.x; acc[5] += wa * p2.y; acc[6] += wa * p3.x; acc[7] += wa * p3.y;
            p0 = bf2x(ub.x); p1 = bf2x(ub.y); p2 = bf2x(ub.z); p3 = bf2x(ub.w);
            acc[0] += wb * p0.x; acc[1] += wb * p0.y; acc[2] += wb * p1.x; acc[3] += wb * p1.y;
            acc[4] += wb * p2.x; acc[5] += wb * p2.y; acc[6] += wb * p3.x; acc[7] += wb * p3.y;
            p0 = bf2x(uc.x); p1 = bf2x(uc.y); p2 = bf2x(uc.z); p3 = bf2x(uc.w);
            acc[0] += wc * p0.x; acc[1] += wc * p0.y; acc[2] += wc * p1.x; acc[3] += wc * p1.y;
            acc[4] += wc * p2.x; acc[5] += wc * p2.y; acc[6] += wc * p3.x; acc[7] += wc * p3.y;
            p0 = bf2x(ud.x); p1 = bf2x(ud.y); p2 = bf2x(ud.z); p3 = bf2x(ud.w);
            acc[0] += wd * p0.x; acc[1] += wd * p0.y; acc[2] += wd * p1.x; acc[3] += wd * p1.y;
            acc[4] += wd * p2.x; acc[5] += wd * p2.y; acc[6] += wd * p3.x; acc[7] += wd * p3.y;
        }
        for (; j < cnt; ++j) {
            int s = ssrc[wid][j];
            float wj = swt[wid][h][j];
            uint4 u = hq[(size_t)s * 64 + lane];
            float2 p0 = bf2x(u.x), p1 = bf2x(u.y), p2 = bf2x(u.z), p3 = bf2x(u.w);
            acc[0] += wj * p0.x; acc[1] += wj * p0.y;
            acc[2] += wj * p1.x; acc[3] += wj * p1.y;
            acc[4] += wj * p2.x; acc[5] += wj * p2.y;
            acc[6] += wj * p3.x; acc[7] += wj * p3.y;
        }
    }
#pragma unroll
    for (int o = 32; o > 0; o >>= 1) {
        den.x += __shfl_xor(den.x, o);
        den.y += __shfl_xor(den.y, o);
        den.z += __shfl_xor(den.z, o);
        den.w += __shfl_xor(den.w, o);
    }
    den.x += wself.x; den.y += wself.y; den.z += wself.z; den.w += wself.w;
    float winv = 0.25f / sel4(den, h);
#pragma unroll
    for (int j = 0; j < 8; ++j) acc[j] *= winv;
#pragma unroll
    for (int j = 0; j < 8; ++j) acc[j] += __shfl_xor(acc[j], 16);
#pragma unroll
    for (int j = 0; j < 8; ++j) acc[j] += __shfl_xor(acc[j], 32);
    // bias + relu + store node embeddings (features (lane&15)*8..+7)
    int fl = lane & 15;
    float4 gb0 = ((const float4*)gat_b)[fl * 2], gb1 = ((const float4*)gat_b)[fl * 2 + 1];
    if (lane < 16) {
        float4* o4 = (float4*)(node_out + (size_t)node * 128 + fl * 8);
        o4[0] = make_float4(fmaxf(acc[0] + gb0.x, 0.f), fmaxf(acc[1] + gb0.y, 0.f),
                            fmaxf(acc[2] + gb0.z, 0.f), fmaxf(acc[3] + gb0.w, 0.f));
        o4[1] = make_float4(fmaxf(acc[4] + gb1.x, 0.f), fmaxf(acc[5] + gb1.y, 0.f),
                            fmaxf(acc[6] + gb1.z, 0.f), fmaxf(acc[7] + gb1.w, 0.f));
    }
}

// ---------------- pooling: run-batched atomics over sorted batch ------------
__global__ __launch_bounds__(TPB) void k_pool(const float* __restrict__ node_out,
                                              const int* __restrict__ batch,
                                              float* __restrict__ mean_acc,
                                              float* __restrict__ max_acc,
                                              float* __restrict__ cnt, int n) {
    int wave = (blockIdx.x * TPB + threadIdx.x) >> 6;
    int lane = threadIdx.x & 63;
    int n0 = wave * 16;
    if (n0 >= n) return;
    int n1 = min(n0 + 16, n);
    float2 bsum = make_float2(0.f, 0.f), bmax = make_float2(0.f, 0.f);
    int cur_g = batch[n0];
    int cntloc = 0;
    for (int nn = n0; nn < n1; ++nn) {
        int g = batch[nn];
        if (g != cur_g) {
            float* ma = mean_acc + cur_g * 128 + lane * 2;
            atomicAdd(ma + 0, bsum.x);
            atomicAdd(ma + 1, bsum.y);
            int* mxp = (int*)(max_acc + cur_g * 128 + lane * 2);
            atomicMax(mxp + 0, __float_as_int(bmax.x));
            atomicMax(mxp + 1, __float_as_int(bmax.y));
            if (lane == 0) atomicAdd(&cnt[cur_g], (float)cntloc);
            bsum = make_float2(0.f, 0.f);
            bmax = make_float2(0.f, 0.f);
            cntloc = 0;
            cur_g = g;
        }
        float2 o = ((const float2*)node_out)[(size_t)nn * 64 + lane];
        bsum.x += o.x; bsum.y += o.y;
        bmax.x = fmaxf(bmax.x, o.x); bmax.y = fmaxf(bmax.y, o.y);
        ++cntloc;
    }
    float* ma = mean_acc + cur_g * 128 + lane * 2;
    atomicAdd(ma + 0, bsum.x);
    atomicAdd(ma + 1, bsum.y);
    int* mxp = (int*)(max_acc + cur_g * 128 + lane * 2);
    atomicMax(mxp + 0, __float_as_int(bmax.x));
    atomicMax(mxp + 1, __float_as_int(bmax.y));
    if (lane == 0) atomicAdd(&cnt[cur_g], (float)cntloc);
}

__global__ __launch_bounds__(TPB) void k_pool_final(const float* __restrict__ mean_acc,
                                                    const float* __restrict__ max_acc,
                                                    const float* __restrict__ cnt,
                                                    float* __restrict__ gout, int g128) {
    int i = blockIdx.x * TPB + threadIdx.x;
    if (i >= g128) return;
    int g = i >> 7, d = i & 127;
    float c = fmaxf(cnt[g], 1.f);
    gout[g * 256 + d] = mean_acc[i] / c;
    gout[g * 256 + 128 + d] = max_acc[i];
}

// ---------------------------------------------------------------------------
extern "C" void kernel_launch(void* const* d_in, const int* in_sizes, int n_in,
                              void* d_out, int out_size, void* d_ws, size_t ws_size,
                              hipStream_t stream) {
    const float* x       = (const float*)d_in[0];
    const int*   ei      = (const int*)d_in[1];
    const int*   batch   = (const int*)d_in[2];
    const float* W1      = (const float*)d_in[3];
    const float* b1      = (const float*)d_in[4];
    const float* g1      = (const float*)d_in[5];
    const float* beta1   = (const float*)d_in[6];
    const float* W2      = (const float*)d_in[7];
    const float* b2      = (const float*)d_in[8];
    const float* g2      = (const float*)d_in[9];
    const float* beta2   = (const float*)d_in[10];
    const float* gat_W   = (const float*)d_in[11];
    const float* att_src = (const float*)d_in[12];
    const float* att_dst = (const float*)d_in[13];
    const float* gat_b   = (const float*)d_in[14];

    const int N = in_sizes[0] / 128;
    const int E = in_sizes[1] / 2;
    const int G = (out_size - N * 128) / 256;
    const int* src = ei;
    const int* dst = ei + E;

    float* ws = (float*)d_ws;
    float* dis      = ws; ws += N;
    float* a_s      = ws; ws += N * 4;
    float* a_d      = ws; ws += N * 4;
    float* mean_acc = ws; ws += G * 128;
    float* max_acc  = ws; ws += G * 128;
    float* cnt      = ws; ws += G;
    unsigned short* xb  = (unsigned short*)ws; ws += (size_t)N * 64;
    unsigned short* Hbf = (unsigned short*)ws; ws += (size_t)N * 64;
    unsigned short* Bbf = (unsigned short*)ws; ws += (size_t)N * 64;
    unsigned short* Cbf = (unsigned short*)ws; ws += (size_t)N * 64;
    unsigned short* hgb = (unsigned short*)ws; ws += (size_t)N * 256;
    unsigned short* Wt1 = (unsigned short*)ws; ws += 128 * 64;
    unsigned short* Wt2 = (unsigned short*)ws; ws += 128 * 64;
    unsigned short* Wtg = (unsigned short*)ws; ws += 512 * 64;
    int* deg       = (int*)ws; ws += N;
    int* part      = (int*)ws; ws += 256;
    int* row_start = (int*)ws; ws += N + 1;
    int* cursor    = (int*)ws; ws += N + 1;
    int* csr_src   = (int*)ws; ws += E;

    float* gout = (float*)d_out;        // [G, 256]
    float* node_out = gout + G * 256;   // [N, 128]

    auto cdiv = [](long a, long b) { return (int)((a + b - 1) / b); };
    const int nb = cdiv(N, TPB);

    // CSR build (by dst) + degrees; parallel 3-pass scan
    hipMemsetAsync(deg, 0, (size_t)N * 4, stream);
    k_hist<<<cdiv(E, TPB), TPB, 0, stream>>>(dst, deg, E);
    k_scan_part<<<nb, TPB, 0, stream>>>(deg, part, N);
    k_scan_top<<<1, TPB, 0, stream>>>(part, nb);
    k_scan_apply<<<nb, TPB, 0, stream>>>(deg, part, row_start, cursor, dis, N, E);
    k_scatter<<<cdiv(E, TPB), TPB, 0, stream>>>(src, dst, cursor, csr_src, E);

    // conversions
    k_f2bf<<<cdiv((long)N * 32, TPB), TPB, 0, stream>>>(x, xb, N * 32);
    k_wt<<<cdiv(128 * 128, TPB), TPB, 0, stream>>>(W1, Wt1, 128);
    k_wt<<<cdiv(128 * 128, TPB), TPB, 0, stream>>>(W2, Wt2, 128);
    k_wt<<<cdiv(128 * 512, TPB), TPB, 0, stream>>>(gat_W, Wtg, 512);

    // GCN layer 1
    k_gemm_mfma<<<dim3(cdiv(N, 128), 1), TPB, 0, stream>>>(xb, Wt1, Hbf, N, 128);
    k_gcn_fused<<<cdiv((long)N * 64, TPB), TPB, 0, stream>>>(Hbf, csr_src, row_start, dis,
                                                             b1, g1, beta1, Bbf, N);
    // GCN layer 2
    k_gemm_mfma<<<dim3(cdiv(N, 128), 1), TPB, 0, stream>>>(Bbf, Wt2, Hbf, N, 128);
    k_gcn_fused<<<cdiv((long)N * 64, TPB), TPB, 0, stream>>>(Hbf, csr_src, row_start, dis,
                                                             b2, g2, beta2, Cbf, N);
    // GAT
    k_gemm_mfma<<<dim3(cdiv(N, 128), 4), TPB, 0, stream>>>(Cbf, Wtg, hgb, N, 512);
    k_att_dots<<<cdiv((long)N * 64, TPB), TPB, 0, stream>>>(hgb, att_src, att_dst, a_s, a_d, N);
    k_gat_fused<<<cdiv((long)N * 64, TPB), TPB, 0, stream>>>(hgb, a_s, a_d, csr_src, row_start,
                                                             gat_b, node_out, N);

    // pooling
    hipMemsetAsync(mean_acc, 0, (size_t)(G * 256 + G) * 4, stream);
    k_pool<<<cdiv((long)cdiv(N, 16) * 64, TPB), TPB, 0, stream>>>(node_out, batch,
                                                                  mean_acc, max_acc, cnt, N);
    k_pool_final<<<cdiv((long)G * 128, TPB), TPB, 0, stream>>>(mean_acc, max_acc, cnt, gout, G * 128);
}

// Round 8
// 431.985 us; speedup vs baseline: 1.0540x; 1.0540x over previous
//
#include <hip/hip_runtime.h>
#include <math.h>

// ---------------------------------------------------------------------------
// HOGGraphNet: 2x GCNConv(+LN+ReLU) -> GATConv(4 heads, mean) -> mean/max pool
// N=50000, E=600000, D=128, H=4, G=64. CSR gather-side aggregation.
// bf16 feature pipeline; GEMMs on MFMA (16x16x32 bf16, fp32 accumulate).
// GAT gemm computes attention dots in-epilogue (head == blockIdx.y slice).
// k_gat_fused is at the ~6 TB/s random-gather roofline (600MB/106us).
// ---------------------------------------------------------------------------

#define TPB 256

typedef __attribute__((ext_vector_type(8))) short short8;
typedef __attribute__((ext_vector_type(4))) float f32x4;
union U4S8 { uint4 u; short8 s; };

__device__ __forceinline__ float lrelu(float x) { return x > 0.f ? x : 0.2f * x; }

__device__ __forceinline__ unsigned short f2bf(float f) {  // RTNE
    unsigned int u = __float_as_uint(f);
    u += 0x7fffu + ((u >> 16) & 1u);
    return (unsigned short)(u >> 16);
}
__device__ __forceinline__ float2 bf2x(unsigned int u) {   // [lo,hi] bf16 pair
    return make_float2(__uint_as_float(u << 16), __uint_as_float(u & 0xffff0000u));
}
__device__ __forceinline__ float sel4(float4 v, int h) {
    float r = v.x;
    r = (h == 1) ? v.y : r;
    r = (h == 2) ? v.z : r;
    r = (h == 3) ? v.w : r;
    return r;
}
__device__ __forceinline__ float dot4(f32x4 a, float4 b) {
    return a.x * b.x + a.y * b.y + a.z * b.z + a.w * b.w;
}

// ---------------- CSR build ----------------
__global__ __launch_bounds__(TPB) void k_hist(const int* __restrict__ dst,
                                              int* __restrict__ deg, int e) {
    int i = blockIdx.x * TPB + threadIdx.x;
    if (i < e) atomicAdd(&deg[dst[i]], 1);
}

__global__ __launch_bounds__(TPB) void k_scan_part(const int* __restrict__ deg,
                                                   int* __restrict__ part, int n) {
    int i = blockIdx.x * TPB + threadIdx.x;
    int v = (i < n) ? deg[i] : 0;
#pragma unroll
    for (int o = 32; o > 0; o >>= 1) v += __shfl_xor(v, o);
    __shared__ int sw[4];
    if ((threadIdx.x & 63) == 0) sw[threadIdx.x >> 6] = v;
    __syncthreads();
    if (threadIdx.x == 0) part[blockIdx.x] = sw[0] + sw[1] + sw[2] + sw[3];
}

__global__ __launch_bounds__(TPB) void k_scan_top(int* __restrict__ part, int nb) {
    __shared__ int sm[TPB];
    int t = threadIdx.x;
    int v = (t < nb) ? part[t] : 0;
    sm[t] = v;
    __syncthreads();
    for (int off = 1; off < TPB; off <<= 1) {
        int u = (t >= off) ? sm[t - off] : 0;
        __syncthreads();
        sm[t] += u;
        __syncthreads();
    }
    if (t < nb) part[t] = sm[t] - v;  // exclusive
}

__global__ __launch_bounds__(TPB) void k_scan_apply(const int* __restrict__ deg,
                                                    const int* __restrict__ part,
                                                    int* __restrict__ row_start,
                                                    int* __restrict__ cursor,
                                                    float* __restrict__ dis,
                                                    int n, int e_total) {
    __shared__ int sm[TPB];
    int i = blockIdx.x * TPB + threadIdx.x;
    int t = threadIdx.x;
    int d = (i < n) ? deg[i] : 0;
    sm[t] = d;
    __syncthreads();
    for (int off = 1; off < TPB; off <<= 1) {
        int u = (t >= off) ? sm[t - off] : 0;
        __syncthreads();
        sm[t] += u;
        __syncthreads();
    }
    if (i < n) {
        int rs = part[blockIdx.x] + sm[t] - d;
        row_start[i] = rs;
        cursor[i] = rs;
        dis[i] = rsqrtf((float)(d + 1));
    }
    if (blockIdx.x == 0 && t == 0) row_start[n] = e_total;
}

__global__ __launch_bounds__(TPB) void k_scatter(const int* __restrict__ src,
                                                 const int* __restrict__ dst,
                                                 int* __restrict__ cursor,
                                                 int* __restrict__ csr_src, int e) {
    int i = blockIdx.x * TPB + threadIdx.x;
    if (i < e) {
        int p = atomicAdd(&cursor[dst[i]], 1);
        csr_src[p] = src[i];
    }
}

// ---------------- weight transposes (all three in one launch) ---------------
// W[k][n] fp32 -> Wt[n][k] bf16 (K=128) for W1, W2, gat_W
__global__ __launch_bounds__(TPB) void k_wt_all(const float* __restrict__ W1,
                                                const float* __restrict__ W2,
                                                const float* __restrict__ Wg,
                                                unsigned short* __restrict__ Wt1,
                                                unsigned short* __restrict__ Wt2,
                                                unsigned short* __restrict__ Wtg) {
    int i = blockIdx.x * TPB + threadIdx.x;
    if (i < 16384) {
        int k = i >> 7, n = i & 127;
        Wt1[n * 128 + k] = f2bf(W1[i]);
    } else if (i < 32768) {
        int j = i - 16384;
        int k = j >> 7, n = j & 127;
        Wt2[n * 128 + k] = f2bf(W2[j]);
    } else if (i < 98304) {
        int j = i - 32768;
        int k = j >> 9, n = j & 511;
        Wtg[n * 128 + k] = f2bf(Wg[j]);
    }
}

// ---------------- MFMA GEMM core (bf16 features in) -------------------------
// C[node][chan] = feat[node][:] . Wt[chan][:]; 128 chan x 128 node per block.
// If att_s != null (GAT gemm): blockIdx.y == head; epilogue computes the full
// per-node head dots a_s/a_d from the fp32 accumulators.
__global__ __launch_bounds__(TPB, 2) void k_gemm_mfma(const unsigned short* __restrict__ feat,
                                                      const unsigned short* __restrict__ Wt,
                                                      unsigned short* __restrict__ C,
                                                      int nrows, int ocols,
                                                      const float* __restrict__ att_s,
                                                      const float* __restrict__ att_d,
                                                      float* __restrict__ a_s,
                                                      float* __restrict__ a_d) {
    __shared__ uint4 wl[2048];  // 32KB fragment-linear Wt tile
    __shared__ float sas[128], sad[128];
    int t = threadIdx.x;
    int cb = blockIdx.y << 7;
#pragma unroll
    for (int i = 0; i < 8; ++i) {
        int fi = i * 256 + t;
        int l = fi & 63, ct = (fi >> 6) & 7, ks = fi >> 9;
        int chan = cb + ct * 16 + (l & 15);
        wl[fi] = ((const uint4*)(Wt + (size_t)chan * 128))[ks * 4 + (l >> 4)];
    }
    __syncthreads();

    int wave = t >> 6, lane = t & 63;
    int wr = wave >> 1, wc = wave & 1;
    int nbase = (blockIdx.x << 7) + (wc << 6);
    const uint4* brow[4];
#pragma unroll
    for (int nt = 0; nt < 4; ++nt) {
        int node = nbase + nt * 16 + (lane & 15);
        node = node < nrows ? node : (nrows - 1);
        brow[nt] = (const uint4*)(feat + (size_t)node * 128);
    }
    f32x4 acc[4][4];
#pragma unroll
    for (int mt = 0; mt < 4; ++mt)
#pragma unroll
        for (int nt = 0; nt < 4; ++nt) acc[mt][nt] = (f32x4)0.f;

    int kq = lane >> 4;
#pragma unroll
    for (int ks = 0; ks < 4; ++ks) {
        U4S8 a[4], b[4];
#pragma unroll
        for (int mt = 0; mt < 4; ++mt)
            a[mt].u = wl[(ks * 8 + wr * 4 + mt) * 64 + lane];
#pragma unroll
        for (int nt = 0; nt < 4; ++nt)
            b[nt].u = brow[nt][ks * 4 + kq];
#pragma unroll
        for (int mt = 0; mt < 4; ++mt)
#pragma unroll
            for (int nt = 0; nt < 4; ++nt)
                acc[mt][nt] = __builtin_amdgcn_mfma_f32_16x16x32_bf16(
                    a[mt].s, b[nt].s, acc[mt][nt], 0, 0, 0);
    }
    // C/D layout: col(node)=lane&15, row(chan)=(lane>>4)*4+reg
#pragma unroll
    for (int nt = 0; nt < 4; ++nt) {
        int node = nbase + nt * 16 + (lane & 15);
        if (node >= nrows) continue;
#pragma unroll
        for (int mt = 0; mt < 4; ++mt) {
            int chan = cb + (wr << 6) + mt * 16 + (lane >> 4) * 4;
            f32x4 v = acc[mt][nt];
            unsigned int p0 = (unsigned int)f2bf(v.x) | ((unsigned int)f2bf(v.y) << 16);
            unsigned int p1 = (unsigned int)f2bf(v.z) | ((unsigned int)f2bf(v.w) << 16);
            *(uint2*)(C + (size_t)node * ocols + chan) = make_uint2(p0, p1);
        }
    }
    // ---- fused attention dots (GAT gemm only): head h = blockIdx.y ----
    if (att_s) {
        if (t < 128) { sas[t] = 0.f; sad[t] = 0.f; }
        __syncthreads();
        int h = blockIdx.y;
        float4 asv[4], adv[4];
#pragma unroll
        for (int mt = 0; mt < 4; ++mt) {
            int cbase = h * 128 + (wr << 6) + mt * 16 + (lane >> 4) * 4;
            asv[mt] = *(const float4*)(att_s + cbase);
            adv[mt] = *(const float4*)(att_d + cbase);
        }
#pragma unroll
        for (int nt = 0; nt < 4; ++nt) {
            float ds = 0.f, dd = 0.f;
#pragma unroll
            for (int mt = 0; mt < 4; ++mt) {
                ds += dot4(acc[mt][nt], asv[mt]);
                dd += dot4(acc[mt][nt], adv[mt]);
            }
            ds += __shfl_xor(ds, 16); ds += __shfl_xor(ds, 32);
            dd += __shfl_xor(dd, 16); dd += __shfl_xor(dd, 32);
            if (lane < 16) {
                atomicAdd(&sas[(wc << 6) + nt * 16 + lane], ds);
                atomicAdd(&sad[(wc << 6) + nt * 16 + lane], dd);
            }
        }
        __syncthreads();
        if (t < 128) {
            int node = (blockIdx.x << 7) + t;
            if (node < nrows) a_s[node * 4 + h] = sas[t];
        } else {
            int t2 = t - 128;
            int node = (blockIdx.x << 7) + t2;
            if (node < nrows) a_d[node * 4 + h] = sad[t2];
        }
    }
}

// ---------------- MFMA GEMM, fp32 features in (layer-1: reads x directly) ---
__global__ __launch_bounds__(TPB, 2) void k_gemm_mfma_f32(const float* __restrict__ feat,
                                                          const unsigned short* __restrict__ Wt,
                                                          unsigned short* __restrict__ C,
                                                          int nrows, int ocols) {
    __shared__ uint4 wl[2048];
    int t = threadIdx.x;
    int cb = blockIdx.y << 7;
#pragma unroll
    for (int i = 0; i < 8; ++i) {
        int fi = i * 256 + t;
        int l = fi & 63, ct = (fi >> 6) & 7, ks = fi >> 9;
        int chan = cb + ct * 16 + (l & 15);
        wl[fi] = ((const uint4*)(Wt + (size_t)chan * 128))[ks * 4 + (l >> 4)];
    }
    __syncthreads();

    int wave = t >> 6, lane = t & 63;
    int wr = wave >> 1, wc = wave & 1;
    int nbase = (blockIdx.x << 7) + (wc << 6);
    const float4* brow[4];
#pragma unroll
    for (int nt = 0; nt < 4; ++nt) {
        int node = nbase + nt * 16 + (lane & 15);
        node = node < nrows ? node : (nrows - 1);
        brow[nt] = (const float4*)(feat + (size_t)node * 128);
    }
    f32x4 acc[4][4];
#pragma unroll
    for (int mt = 0; mt < 4; ++mt)
#pragma unroll
        for (int nt = 0; nt < 4; ++nt) acc[mt][nt] = (f32x4)0.f;

    int kq = lane >> 4;
#pragma unroll
    for (int ks = 0; ks < 4; ++ks) {
        U4S8 a[4], b[4];
#pragma unroll
        for (int mt = 0; mt < 4; ++mt)
            a[mt].u = wl[(ks * 8 + wr * 4 + mt) * 64 + lane];
#pragma unroll
        for (int nt = 0; nt < 4; ++nt) {
            float4 f0 = brow[nt][ks * 8 + kq * 2];
            float4 f1 = brow[nt][ks * 8 + kq * 2 + 1];
            b[nt].u.x = (unsigned int)f2bf(f0.x) | ((unsigned int)f2bf(f0.y) << 16);
            b[nt].u.y = (unsigned int)f2bf(f0.z) | ((unsigned int)f2bf(f0.w) << 16);
            b[nt].u.z = (unsigned int)f2bf(f1.x) | ((unsigned int)f2bf(f1.y) << 16);
            b[nt].u.w = (unsigned int)f2bf(f1.z) | ((unsigned int)f2bf(f1.w) << 16);
        }
#pragma unroll
        for (int mt = 0; mt < 4; ++mt)
#pragma unroll
            for (int nt = 0; nt < 4; ++nt)
                acc[mt][nt] = __builtin_amdgcn_mfma_f32_16x16x32_bf16(
                    a[mt].s, b[nt].s, acc[mt][nt], 0, 0, 0);
    }
#pragma unroll
    for (int nt = 0; nt < 4; ++nt) {
        int node = nbase + nt * 16 + (lane & 15);
        if (node >= nrows) continue;
#pragma unroll
        for (int mt = 0; mt < 4; ++mt) {
            int chan = cb + (wr << 6) + mt * 16 + (lane >> 4) * 4;
            f32x4 v = acc[mt][nt];
            unsigned int p0 = (unsigned int)f2bf(v.x) | ((unsigned int)f2bf(v.y) << 16);
            unsigned int p1 = (unsigned int)f2bf(v.z) | ((unsigned int)f2bf(v.w) << 16);
            *(uint2*)(C + (size_t)node * ocols + chan) = make_uint2(p0, p1);
        }
    }
}

// ---------------- fused GCN: 16B/lane gather (8 edges/iter) + LN + ReLU -----
// wave per node; lane = (quarter q=lane>>4, fl=lane&15); 8 feats/lane.
__global__ __launch_bounds__(TPB) void k_gcn_fused(const unsigned short* __restrict__ hb,
                                                   const int* __restrict__ csr_src,
                                                   const int* __restrict__ row_start,
                                                   const float* __restrict__ dis,
                                                   const float* __restrict__ b,
                                                   const float* __restrict__ g,
                                                   const float* __restrict__ beta,
                                                   unsigned short* __restrict__ out, int n) {
    __shared__ int   ssrc[4][64];
    __shared__ float swt[4][64];
    int node = (blockIdx.x * TPB + threadIdx.x) >> 6;
    int lane = threadIdx.x & 63;
    int wid = threadIdx.x >> 6;
    if (node >= n) return;
    int s0 = row_start[node], s1 = row_start[node + 1];
    float dn = dis[node];
    const uint4* hq = (const uint4*)hb;   // row = 16 uint4 (128 bf16)
    int q = lane >> 4, fl = lane & 15;
    float acc[8];
#pragma unroll
    for (int i = 0; i < 8; ++i) acc[i] = 0.f;
    for (int base = s0; base < s1; base += 64) {
        int cnt = min(64, s1 - base);
        int sidx = 0; float w = 0.f;
        if (lane < cnt) { sidx = csr_src[base + lane]; w = dis[sidx]; }
        ssrc[wid][lane] = sidx;
        swt[wid][lane] = w;
        for (int j = 0; j < cnt; j += 8) {   // 2 rows in flight per quarter
            int j0 = j + q, j1 = j + 4 + q;
            int ok0 = j0 < cnt, ok1 = j1 < cnt;
            int sA = ssrc[wid][ok0 ? j0 : 0];
            int sB = ssrc[wid][ok1 ? j1 : 0];
            float wA = ok0 ? swt[wid][j0] : 0.f;
            float wB = ok1 ? swt[wid][j1] : 0.f;
            uint4 uA = hq[(size_t)sA * 16 + fl];
            uint4 uB = hq[(size_t)sB * 16 + fl];
            float2 p0 = bf2x(uA.x), p1 = bf2x(uA.y), p2 = bf2x(uA.z), p3 = bf2x(uA.w);
            acc[0] += wA * p0.x; acc[1] += wA * p0.y;
            acc[2] += wA * p1.x; acc[3] += wA * p1.y;
            acc[4] += wA * p2.x; acc[5] += wA * p2.y;
            acc[6] += wA * p3.x; acc[7] += wA * p3.y;
            p0 = bf2x(uB.x); p1 = bf2x(uB.y); p2 = bf2x(uB.z); p3 = bf2x(uB.w);
            acc[0] += wB * p0.x; acc[1] += wB * p0.y;
            acc[2] += wB * p1.x; acc[3] += wB * p1.y;
            acc[4] += wB * p2.x; acc[5] += wB * p2.y;
            acc[6] += wB * p3.x; acc[7] += wB * p3.y;
        }
    }
    // combine quarters: lanes with same fl hold disjoint edge subsets
#pragma unroll
    for (int i = 0; i < 8; ++i) {
        acc[i] += __shfl_xor(acc[i], 16);
        acc[i] += __shfl_xor(acc[i], 32);
    }
    float sl = dn * dn;
    uint4 us = hq[(size_t)node * 16 + fl];
    float2 h0 = bf2x(us.x), h1 = bf2x(us.y), h2 = bf2x(us.z), h3 = bf2x(us.w);
    float4 b0 = ((const float4*)b)[fl * 2], b1 = ((const float4*)b)[fl * 2 + 1];
    float v[8];
    v[0] = dn * acc[0] + sl * h0.x + b0.x;
    v[1] = dn * acc[1] + sl * h0.y + b0.y;
    v[2] = dn * acc[2] + sl * h1.x + b0.z;
    v[3] = dn * acc[3] + sl * h1.y + b0.w;
    v[4] = dn * acc[4] + sl * h2.x + b1.x;
    v[5] = dn * acc[5] + sl * h2.y + b1.y;
    v[6] = dn * acc[6] + sl * h3.x + b1.z;
    v[7] = dn * acc[7] + sl * h3.y + b1.w;
    float s = 0.f, sq = 0.f;
#pragma unroll
    for (int i = 0; i < 8; ++i) { s += v[i]; sq += v[i] * v[i]; }
#pragma unroll
    for (int o = 8; o > 0; o >>= 1) {
        s  += __shfl_xor(s, o);
        sq += __shfl_xor(sq, o);
    }
    float mu = s * (1.f / 128.f);
    float var = sq * (1.f / 128.f) - mu * mu;
    float rstd = rsqrtf(var + 1e-5f);
    float4 g0  = ((const float4*)g)[fl * 2],    g1v = ((const float4*)g)[fl * 2 + 1];
    float4 bt0 = ((const float4*)beta)[fl * 2], bt1 = ((const float4*)beta)[fl * 2 + 1];
    float o0 = fmaxf((v[0] - mu) * rstd * g0.x + bt0.x, 0.f);
    float o1 = fmaxf((v[1] - mu) * rstd * g0.y + bt0.y, 0.f);
    float o2 = fmaxf((v[2] - mu) * rstd * g0.z + bt0.z, 0.f);
    float o3 = fmaxf((v[3] - mu) * rstd * g0.w + bt0.w, 0.f);
    float o4 = fmaxf((v[4] - mu) * rstd * g1v.x + bt1.x, 0.f);
    float o5 = fmaxf((v[5] - mu) * rstd * g1v.y + bt1.y, 0.f);
    float o6 = fmaxf((v[6] - mu) * rstd * g1v.z + bt1.z, 0.f);
    float o7 = fmaxf((v[7] - mu) * rstd * g1v.w + bt1.w, 0.f);
    if (q == 0) {
        uint4 pk;
        pk.x = (unsigned int)f2bf(o0) | ((unsigned int)f2bf(o1) << 16);
        pk.y = (unsigned int)f2bf(o2) | ((unsigned int)f2bf(o3) << 16);
        pk.z = (unsigned int)f2bf(o4) | ((unsigned int)f2bf(o5) << 16);
        pk.w = (unsigned int)f2bf(o6) | ((unsigned int)f2bf(o7) << 16);
        ((uint4*)out)[(size_t)node * 16 + fl] = pk;
    }
}

// ---------------- fused GAT: softmax + gather (x4 unroll) + bias/relu -------
__global__ __launch_bounds__(TPB) void k_gat_fused(const unsigned short* __restrict__ hgb,
                                                   const float* __restrict__ a_s,
                                                   const float* __restrict__ a_d,
                                                   const int* __restrict__ csr_src,
                                                   const int* __restrict__ row_start,
                                                   const float* __restrict__ gat_b,
                                                   float* __restrict__ node_out, int n) {
    __shared__ int   ssrc[4][64];
    __shared__ float swt[4][4][65];
    int node = (blockIdx.x * TPB + threadIdx.x) >> 6;
    int lane = threadIdx.x & 63;
    int wid = threadIdx.x >> 6;
    if (node >= n) return;
    int s0 = row_start[node], s1 = row_start[node + 1];
    int h = lane >> 4;
    const float4* as4 = (const float4*)a_s;
    float4 ad = ((const float4*)a_d)[node];
    float4 asn = as4[node];
    float4 wself;
    wself.x = __expf(lrelu(asn.x + ad.x));
    wself.y = __expf(lrelu(asn.y + ad.y));
    wself.z = __expf(lrelu(asn.z + ad.z));
    wself.w = __expf(lrelu(asn.w + ad.w));
    const uint4* hq = (const uint4*)hgb;
    float acc[8];
    {
        float wsh = sel4(wself, h);
        uint4 u = hq[(size_t)node * 64 + lane];
        float2 p0 = bf2x(u.x), p1 = bf2x(u.y), p2 = bf2x(u.z), p3 = bf2x(u.w);
        acc[0] = wsh * p0.x; acc[1] = wsh * p0.y;
        acc[2] = wsh * p1.x; acc[3] = wsh * p1.y;
        acc[4] = wsh * p2.x; acc[5] = wsh * p2.y;
        acc[6] = wsh * p3.x; acc[7] = wsh * p3.y;
    }
    float4 den = make_float4(0.f, 0.f, 0.f, 0.f);
    for (int base = s0; base < s1; base += 64) {
        int cnt = min(64, s1 - base);
        int sidx = 0;
        float4 w4 = make_float4(0.f, 0.f, 0.f, 0.f);
        if (lane < cnt) {
            sidx = csr_src[base + lane];
            float4 a = as4[sidx];
            w4.x = __expf(lrelu(a.x + ad.x));
            w4.y = __expf(lrelu(a.y + ad.y));
            w4.z = __expf(lrelu(a.z + ad.z));
            w4.w = __expf(lrelu(a.w + ad.w));
            den.x += w4.x; den.y += w4.y; den.z += w4.z; den.w += w4.w;
        }
        ssrc[wid][lane] = sidx;
        swt[wid][0][lane] = w4.x;
        swt[wid][1][lane] = w4.y;
        swt[wid][2][lane] = w4.z;
        swt[wid][3][lane] = w4.w;
        int j = 0;
        for (; j + 4 <= cnt; j += 4) {
            int sa = ssrc[wid][j + 0], sb = ssrc[wid][j + 1];
            int sc = ssrc[wid][j + 2], sd = ssrc[wid][j + 3];
            float wa = swt[wid][h][j + 0], wb = swt[wid][h][j + 1];
            float wc = swt[wid][h][j + 2], wd = swt[wid][h][j + 3];
            uint4 ua = hq[(size_t)sa * 64 + lane];
            uint4 ub = hq[(size_t)sb * 64 + lane];
            uint4 uc = hq[(size_t)sc * 64 + lane];
            uint4 ud = hq[(size_t)sd * 64 + lane];
            float2 p0, p1, p2, p3;
            p0 = bf2x(ua.x); p1 = bf2x(ua.y); p2 = bf2x(ua.z); p3 = bf2x(ua.w);
            acc[0] += wa * p0.x; acc[1] += wa * p0.y; acc[2] += wa * p1.x; acc[3] += wa * p1.y;
            acc[4] += wa * p2.x; acc[5] += wa * p2.y; acc[6] += wa * p3.x; acc[7] += wa * p3.y;
            p0 = bf2x(ub.x); p1 = bf2x(ub.y); p2 = bf2x(ub.z); p3 = bf2x(ub.w);
            acc[0] += wb * p0.x; acc[1] += wb * p0.y; acc[2] += wb * p1.x; acc[3] += wb * p1.y;
            acc[4] += wb * p2.x; acc[5] += wb * p2.y; acc[6] += wb * p3.x; acc[7] += wb * p3.y;
            p0 = bf2x(uc.x); p1 = bf2x(uc.y); p2 = bf2x(uc.z); p3 = bf2x(uc.w);
            acc[0] += wc * p0.x; acc[1] += wc * p0.y; acc[2] += wc * p1.x; acc[3] += wc * p1.y;
            acc[4] += wc * p2.x; acc[5] += wc * p2.y; acc[6] += wc * p3.x; acc[7] += wc * p3.y;
            p0 = bf2x(ud.x); p1 = bf2x(ud.y); p2 = bf2x(ud.z); p3 = bf2x(ud.w);
            acc[0] += wd * p0.x; acc[1] += wd * p0.y; acc[2] += wd * p1.x; acc[3] += wd * p1.y;
            acc[4] += wd * p2.x; acc[5] += wd * p2.y; acc[6] += wd * p3.x; acc[7] += wd * p3.y;
        }
        for (; j < cnt; ++j) {
            int s = ssrc[wid][j];
            float wj = swt[wid][h][j];
            uint4 u = hq[(size_t)s * 64 + lane];
            float2 p0 = bf2x(u.x), p1 = bf2x(u.y), p2 = bf2x(u.z), p3 = bf2x(u.w);
            acc[0] += wj * p0.x; acc[1] += wj * p0.y;
            acc[2] += wj * p1.x; acc[3] += wj * p1.y;
            acc[4] += wj * p2.x; acc[5] += wj * p2.y;
            acc[6] += wj * p3.x; acc[7] += wj * p3.y;
        }
    }
#pragma unroll
    for (int o = 32; o > 0; o >>= 1) {
        den.x += __shfl_xor(den.x, o);
        den.y += __shfl_xor(den.y, o);
        den.z += __shfl_xor(den.z, o);
        den.w += __shfl_xor(den.w, o);
    }
    den.x += wself.x; den.y += wself.y; den.z += wself.z; den.w += wself.w;
    float winv = 0.25f / sel4(den, h);
#pragma unroll
    for (int j = 0; j < 8; ++j) acc[j] *= winv;
#pragma unroll
    for (int j = 0; j < 8; ++j) acc[j] += __shfl_xor(acc[j], 16);
#pragma unroll
    for (int j = 0; j < 8; ++j) acc[j] += __shfl_xor(acc[j], 32);
    int fl = lane & 15;
    float4 gb0 = ((const float4*)gat_b)[fl * 2], gb1 = ((const float4*)gat_b)[fl * 2 + 1];
    if (lane < 16) {
        float4* o4 = (float4*)(node_out + (size_t)node * 128 + fl * 8);
        o4[0] = make_float4(fmaxf(acc[0] + gb0.x, 0.f), fmaxf(acc[1] + gb0.y, 0.f),
                            fmaxf(acc[2] + gb0.z, 0.f), fmaxf(acc[3] + gb0.w, 0.f));
        o4[1] = make_float4(fmaxf(acc[4] + gb1.x, 0.f), fmaxf(acc[5] + gb1.y, 0.f),
                            fmaxf(acc[6] + gb1.z, 0.f), fmaxf(acc[7] + gb1.w, 0.f));
    }
}

// ---------------- pooling: run-batched atomics over sorted batch ------------
__global__ __launch_bounds__(TPB) void k_pool(const float* __restrict__ node_out,
                                              const int* __restrict__ batch,
                                              float* __restrict__ mean_acc,
                                              float* __restrict__ max_acc,
                                              float* __restrict__ cnt, int n) {
    int wave = (blockIdx.x * TPB + threadIdx.x) >> 6;
    int lane = threadIdx.x & 63;
    int n0 = wave * 16;
    if (n0 >= n) return;
    int n1 = min(n0 + 16, n);
    float2 bsum = make_float2(0.f, 0.f), bmax = make_float2(0.f, 0.f);
    int cur_g = batch[n0];
    int cntloc = 0;
    for (int nn = n0; nn < n1; ++nn) {
        int g = batch[nn];
        if (g != cur_g) {
            float* ma = mean_acc + cur_g * 128 + lane * 2;
            atomicAdd(ma + 0, bsum.x);
            atomicAdd(ma + 1, bsum.y);
            int* mxp = (int*)(max_acc + cur_g * 128 + lane * 2);
            atomicMax(mxp + 0, __float_as_int(bmax.x));
            atomicMax(mxp + 1, __float_as_int(bmax.y));
            if (lane == 0) atomicAdd(&cnt[cur_g], (float)cntloc);
            bsum = make_float2(0.f, 0.f);
            bmax = make_float2(0.f, 0.f);
            cntloc = 0;
            cur_g = g;
        }
        float2 o = ((const float2*)node_out)[(size_t)nn * 64 + lane];
        bsum.x += o.x; bsum.y += o.y;
        bmax.x = fmaxf(bmax.x, o.x); bmax.y = fmaxf(bmax.y, o.y);
        ++cntloc;
    }
    float* ma = mean_acc + cur_g * 128 + lane * 2;
    atomicAdd(ma + 0, bsum.x);
    atomicAdd(ma + 1, bsum.y);
    int* mxp = (int*)(max_acc + cur_g * 128 + lane * 2);
    atomicMax(mxp + 0, __float_as_int(bmax.x));
    atomicMax(mxp + 1, __float_as_int(bmax.y));
    if (lane == 0) atomicAdd(&cnt[cur_g], (float)cntloc);
}

__global__ __launch_bounds__(TPB) void k_pool_final(const float* __restrict__ mean_acc,
                                                    const float* __restrict__ max_acc,
                                                    const float* __restrict__ cnt,
                                                    float* __restrict__ gout, int g128) {
    int i = blockIdx.x * TPB + threadIdx.x;
    if (i >= g128) return;
    int g = i >> 7, d = i & 127;
    float c = fmaxf(cnt[g], 1.f);
    gout[g * 256 + d] = mean_acc[i] / c;
    gout[g * 256 + 128 + d] = max_acc[i];
}

// ---------------------------------------------------------------------------
extern "C" void kernel_launch(void* const* d_in, const int* in_sizes, int n_in,
                              void* d_out, int out_size, void* d_ws, size_t ws_size,
                              hipStream_t stream) {
    const float* x       = (const float*)d_in[0];
    const int*   ei      = (const int*)d_in[1];
    const int*   batch   = (const int*)d_in[2];
    const float* W1      = (const float*)d_in[3];
    const float* b1      = (const float*)d_in[4];
    const float* g1      = (const float*)d_in[5];
    const float* beta1   = (const float*)d_in[6];
    const float* W2      = (const float*)d_in[7];
    const float* b2      = (const float*)d_in[8];
    const float* g2      = (const float*)d_in[9];
    const float* beta2   = (const float*)d_in[10];
    const float* gat_W   = (const float*)d_in[11];
    const float* att_src = (const float*)d_in[12];
    const float* att_dst = (const float*)d_in[13];
    const float* gat_b   = (const float*)d_in[14];

    const int N = in_sizes[0] / 128;
    const int E = in_sizes[1] / 2;
    const int G = (out_size - N * 128) / 256;
    const int* src = ei;
    const int* dst = ei + E;

    float* ws = (float*)d_ws;
    float* dis      = ws; ws += N;
    float* a_s      = ws; ws += N * 4;
    float* a_d      = ws; ws += N * 4;
    float* mean_acc = ws; ws += G * 128;
    float* max_acc  = ws; ws += G * 128;
    float* cnt      = ws; ws += G;
    unsigned short* Hbf = (unsigned short*)ws; ws += (size_t)N * 64;
    unsigned short* Bbf = (unsigned short*)ws; ws += (size_t)N * 64;
    unsigned short* Cbf = (unsigned short*)ws; ws += (size_t)N * 64;
    unsigned short* hgb = (unsigned short*)ws; ws += (size_t)N * 256;
    unsigned short* Wt1 = (unsigned short*)ws; ws += 128 * 64;
    unsigned short* Wt2 = (unsigned short*)ws; ws += 128 * 64;
    unsigned short* Wtg = (unsigned short*)ws; ws += 512 * 64;
    int* deg       = (int*)ws; ws += N;
    int* part      = (int*)ws; ws += 256;
    int* row_start = (int*)ws; ws += N + 1;
    int* cursor    = (int*)ws; ws += N + 1;
    int* csr_src   = (int*)ws; ws += E;

    float* gout = (float*)d_out;        // [G, 256]
    float* node_out = gout + G * 256;   // [N, 128]

    auto cdiv = [](long a, long b) { return (int)((a + b - 1) / b); };
    const int nb = cdiv(N, TPB);

    // CSR build (by dst) + degrees; parallel 3-pass scan
    hipMemsetAsync(deg, 0, (size_t)N * 4, stream);
    k_hist<<<cdiv(E, TPB), TPB, 0, stream>>>(dst, deg, E);
    k_scan_part<<<nb, TPB, 0, stream>>>(deg, part, N);
    k_scan_top<<<1, TPB, 0, stream>>>(part, nb);
    k_scan_apply<<<nb, TPB, 0, stream>>>(deg, part, row_start, cursor, dis, N, E);
    k_scatter<<<cdiv(E, TPB), TPB, 0, stream>>>(src, dst, cursor, csr_src, E);

    // weight transposes (one launch)
    k_wt_all<<<cdiv(98304, TPB), TPB, 0, stream>>>(W1, W2, gat_W, Wt1, Wt2, Wtg);

    // GCN layer 1 (gemm reads fp32 x directly)
    k_gemm_mfma_f32<<<dim3(cdiv(N, 128), 1), TPB, 0, stream>>>(x, Wt1, Hbf, N, 128);
    k_gcn_fused<<<cdiv((long)N * 64, TPB), TPB, 0, stream>>>(Hbf, csr_src, row_start, dis,
                                                             b1, g1, beta1, Bbf, N);
    // GCN layer 2
    k_gemm_mfma<<<dim3(cdiv(N, 128), 1), TPB, 0, stream>>>(Bbf, Wt2, Hbf, N, 128,
                                                           nullptr, nullptr, nullptr, nullptr);
    k_gcn_fused<<<cdiv((long)N * 64, TPB), TPB, 0, stream>>>(Hbf, csr_src, row_start, dis,
                                                             b2, g2, beta2, Cbf, N);
    // GAT gemm (+fused attention dots per head slice)
    k_gemm_mfma<<<dim3(cdiv(N, 128), 4), TPB, 0, stream>>>(Cbf, Wtg, hgb, N, 512,
                                                           att_src, att_dst, a_s, a_d);
    k_gat_fused<<<cdiv((long)N * 64, TPB), TPB, 0, stream>>>(hgb, a_s, a_d, csr_src, row_start,
                                                             gat_b, node_out, N);

    // pooling
    hipMemsetAsync(mean_acc, 0, (size_t)(G * 256 + G) * 4, stream);
    k_pool<<<cdiv((long)cdiv(N, 16) * 64, TPB), TPB, 0, stream>>>(node_out, batch,
                                                                  mean_acc, max_acc, cnt, N);
    k_pool_final<<<cdiv((long)G * 128, TPB), TPB, 0, stream>>>(mean_acc, max_acc, cnt, gout, G * 128);
}

// Round 9
// 424.059 us; speedup vs baseline: 1.0737x; 1.0187x over previous
//
#include <hip/hip_runtime.h>
#include <math.h>

// ---------------------------------------------------------------------------
// HOGGraphNet: 2x GCNConv(+LN+ReLU) -> GATConv(4 heads, mean) -> mean/max pool
// N=50000, E=600000, D=128, H=4, G=64. CSR gather-side aggregation.
// bf16 feature pipeline; GEMMs on MFMA (16x16x32 bf16, fp32 accumulate).
// GAT gemm computes attention dots in-epilogue. k_gat_fused is at the
// ~5.75 TB/s random-gather roofline (600MB/106us) -- anchor kernel.
// ---------------------------------------------------------------------------

#define TPB 256

typedef __attribute__((ext_vector_type(8))) short short8;
typedef __attribute__((ext_vector_type(4))) float f32x4;
union U4S8 { uint4 u; short8 s; };

__device__ __forceinline__ float lrelu(float x) { return x > 0.f ? x : 0.2f * x; }

__device__ __forceinline__ unsigned short f2bf(float f) {  // RTNE
    unsigned int u = __float_as_uint(f);
    u += 0x7fffu + ((u >> 16) & 1u);
    return (unsigned short)(u >> 16);
}
__device__ __forceinline__ float2 bf2x(unsigned int u) {   // [lo,hi] bf16 pair
    return make_float2(__uint_as_float(u << 16), __uint_as_float(u & 0xffff0000u));
}
__device__ __forceinline__ float sel4(float4 v, int h) {
    float r = v.x;
    r = (h == 1) ? v.y : r;
    r = (h == 2) ? v.z : r;
    r = (h == 3) ? v.w : r;
    return r;
}
__device__ __forceinline__ float dot4(f32x4 a, float4 b) {
    return a.x * b.x + a.y * b.y + a.z * b.z + a.w * b.w;
}

// ---------------- CSR build ----------------
__global__ __launch_bounds__(TPB) void k_hist(const int* __restrict__ dst,
                                              int* __restrict__ deg, int e) {
    int i = blockIdx.x * TPB + threadIdx.x;
    if (i < e) atomicAdd(&deg[dst[i]], 1);
}

// merged: blocks [0,nb) do per-block deg sums; blocks [nb,..) do W transposes
__global__ __launch_bounds__(TPB) void k_scan_part_wt(const int* __restrict__ deg,
                                                      int* __restrict__ part, int n, int nb,
                                                      const float* __restrict__ W1,
                                                      const float* __restrict__ W2,
                                                      const float* __restrict__ Wg,
                                                      unsigned short* __restrict__ Wt1,
                                                      unsigned short* __restrict__ Wt2,
                                                      unsigned short* __restrict__ Wtg) {
    int bid = blockIdx.x;
    if (bid < nb) {
        int i = bid * TPB + threadIdx.x;
        int v = (i < n) ? deg[i] : 0;
#pragma unroll
        for (int o = 32; o > 0; o >>= 1) v += __shfl_xor(v, o);
        __shared__ int sw[4];
        if ((threadIdx.x & 63) == 0) sw[threadIdx.x >> 6] = v;
        __syncthreads();
        if (threadIdx.x == 0) part[bid] = sw[0] + sw[1] + sw[2] + sw[3];
    } else {
        int i = (bid - nb) * TPB + threadIdx.x;  // 0..98303
        if (i < 16384) {
            int k = i >> 7, c = i & 127;
            Wt1[c * 128 + k] = f2bf(W1[i]);
        } else if (i < 32768) {
            int j = i - 16384;
            int k = j >> 7, c = j & 127;
            Wt2[c * 128 + k] = f2bf(W2[j]);
        } else if (i < 98304) {
            int j = i - 32768;
            int k = j >> 9, c = j & 511;
            Wtg[c * 128 + k] = f2bf(Wg[j]);
        }
    }
}

// in-block exclusive scan; block base = reduce of preceding partials (nb<=256)
__global__ __launch_bounds__(TPB) void k_scan_apply(const int* __restrict__ deg,
                                                    const int* __restrict__ part,
                                                    int* __restrict__ row_start,
                                                    int* __restrict__ cursor,
                                                    float* __restrict__ dis,
                                                    int n, int e_total) {
    __shared__ int sm[TPB];
    __shared__ int sred[4];
    int t = threadIdx.x;
    int bid = blockIdx.x;
    int pv = (t < bid) ? part[t] : 0;
#pragma unroll
    for (int o = 32; o > 0; o >>= 1) pv += __shfl_xor(pv, o);
    if ((t & 63) == 0) sred[t >> 6] = pv;
    __syncthreads();
    int basep = sred[0] + sred[1] + sred[2] + sred[3];
    int i = bid * TPB + t;
    int d = (i < n) ? deg[i] : 0;
    sm[t] = d;
    __syncthreads();
    for (int off = 1; off < TPB; off <<= 1) {
        int u = (t >= off) ? sm[t - off] : 0;
        __syncthreads();
        sm[t] += u;
        __syncthreads();
    }
    if (i < n) {
        int rs = basep + sm[t] - d;
        row_start[i] = rs;
        cursor[i] = rs;
        dis[i] = rsqrtf((float)(d + 1));
    }
    if (bid == 0 && t == 0) row_start[n] = e_total;
}

__global__ __launch_bounds__(TPB) void k_scatter(const int* __restrict__ src,
                                                 const int* __restrict__ dst,
                                                 int* __restrict__ cursor,
                                                 int* __restrict__ csr_src, int e) {
    int i = blockIdx.x * TPB + threadIdx.x;
    if (i < e) {
        int p = atomicAdd(&cursor[dst[i]], 1);
        csr_src[p] = src[i];
    }
}

// ---------------- MFMA GEMM core (bf16 features in) -------------------------
__global__ __launch_bounds__(TPB, 2) void k_gemm_mfma(const unsigned short* __restrict__ feat,
                                                      const unsigned short* __restrict__ Wt,
                                                      unsigned short* __restrict__ C,
                                                      int nrows, int ocols,
                                                      const float* __restrict__ att_s,
                                                      const float* __restrict__ att_d,
                                                      float* __restrict__ a_s,
                                                      float* __restrict__ a_d) {
    __shared__ uint4 wl[2048];  // 32KB fragment-linear Wt tile
    __shared__ float sas[128], sad[128];
    int t = threadIdx.x;
    int cb = blockIdx.y << 7;
#pragma unroll
    for (int i = 0; i < 8; ++i) {
        int fi = i * 256 + t;
        int l = fi & 63, ct = (fi >> 6) & 7, ks = fi >> 9;
        int chan = cb + ct * 16 + (l & 15);
        wl[fi] = ((const uint4*)(Wt + (size_t)chan * 128))[ks * 4 + (l >> 4)];
    }
    __syncthreads();

    int wave = t >> 6, lane = t & 63;
    int wr = wave >> 1, wc = wave & 1;
    int nbase = (blockIdx.x << 7) + (wc << 6);
    const uint4* brow[4];
#pragma unroll
    for (int nt = 0; nt < 4; ++nt) {
        int node = nbase + nt * 16 + (lane & 15);
        node = node < nrows ? node : (nrows - 1);
        brow[nt] = (const uint4*)(feat + (size_t)node * 128);
    }
    f32x4 acc[4][4];
#pragma unroll
    for (int mt = 0; mt < 4; ++mt)
#pragma unroll
        for (int nt = 0; nt < 4; ++nt) acc[mt][nt] = (f32x4)0.f;

    int kq = lane >> 4;
#pragma unroll
    for (int ks = 0; ks < 4; ++ks) {
        U4S8 a[4], b[4];
#pragma unroll
        for (int mt = 0; mt < 4; ++mt)
            a[mt].u = wl[(ks * 8 + wr * 4 + mt) * 64 + lane];
#pragma unroll
        for (int nt = 0; nt < 4; ++nt)
            b[nt].u = brow[nt][ks * 4 + kq];
#pragma unroll
        for (int mt = 0; mt < 4; ++mt)
#pragma unroll
            for (int nt = 0; nt < 4; ++nt)
                acc[mt][nt] = __builtin_amdgcn_mfma_f32_16x16x32_bf16(
                    a[mt].s, b[nt].s, acc[mt][nt], 0, 0, 0);
    }
    // C/D layout: col(node)=lane&15, row(chan)=(lane>>4)*4+reg
#pragma unroll
    for (int nt = 0; nt < 4; ++nt) {
        int node = nbase + nt * 16 + (lane & 15);
        if (node >= nrows) continue;
#pragma unroll
        for (int mt = 0; mt < 4; ++mt) {
            int chan = cb + (wr << 6) + mt * 16 + (lane >> 4) * 4;
            f32x4 v = acc[mt][nt];
            unsigned int p0 = (unsigned int)f2bf(v.x) | ((unsigned int)f2bf(v.y) << 16);
            unsigned int p1 = (unsigned int)f2bf(v.z) | ((unsigned int)f2bf(v.w) << 16);
            *(uint2*)(C + (size_t)node * ocols + chan) = make_uint2(p0, p1);
        }
    }
    // ---- fused attention dots (GAT gemm only): head h = blockIdx.y ----
    if (att_s) {
        if (t < 128) { sas[t] = 0.f; sad[t] = 0.f; }
        __syncthreads();
        int h = blockIdx.y;
        float4 asv[4], adv[4];
#pragma unroll
        for (int mt = 0; mt < 4; ++mt) {
            int cbase = h * 128 + (wr << 6) + mt * 16 + (lane >> 4) * 4;
            asv[mt] = *(const float4*)(att_s + cbase);
            adv[mt] = *(const float4*)(att_d + cbase);
        }
#pragma unroll
        for (int nt = 0; nt < 4; ++nt) {
            float ds = 0.f, dd = 0.f;
#pragma unroll
            for (int mt = 0; mt < 4; ++mt) {
                ds += dot4(acc[mt][nt], asv[mt]);
                dd += dot4(acc[mt][nt], adv[mt]);
            }
            ds += __shfl_xor(ds, 16); ds += __shfl_xor(ds, 32);
            dd += __shfl_xor(dd, 16); dd += __shfl_xor(dd, 32);
            if (lane < 16) {
                atomicAdd(&sas[(wc << 6) + nt * 16 + lane], ds);
                atomicAdd(&sad[(wc << 6) + nt * 16 + lane], dd);
            }
        }
        __syncthreads();
        if (t < 128) {
            int node = (blockIdx.x << 7) + t;
            if (node < nrows) a_s[node * 4 + h] = sas[t];
        } else {
            int t2 = t - 128;
            int node = (blockIdx.x << 7) + t2;
            if (node < nrows) a_d[node * 4 + h] = sad[t2];
        }
    }
}

// ---------------- MFMA GEMM, fp32 features in (layer-1: reads x directly) ---
__global__ __launch_bounds__(TPB, 2) void k_gemm_mfma_f32(const float* __restrict__ feat,
                                                          const unsigned short* __restrict__ Wt,
                                                          unsigned short* __restrict__ C,
                                                          int nrows, int ocols) {
    __shared__ uint4 wl[2048];
    int t = threadIdx.x;
    int cb = blockIdx.y << 7;
#pragma unroll
    for (int i = 0; i < 8; ++i) {
        int fi = i * 256 + t;
        int l = fi & 63, ct = (fi >> 6) & 7, ks = fi >> 9;
        int chan = cb + ct * 16 + (l & 15);
        wl[fi] = ((const uint4*)(Wt + (size_t)chan * 128))[ks * 4 + (l >> 4)];
    }
    __syncthreads();

    int wave = t >> 6, lane = t & 63;
    int wr = wave >> 1, wc = wave & 1;
    int nbase = (blockIdx.x << 7) + (wc << 6);
    const float4* brow[4];
#pragma unroll
    for (int nt = 0; nt < 4; ++nt) {
        int node = nbase + nt * 16 + (lane & 15);
        node = node < nrows ? node : (nrows - 1);
        brow[nt] = (const float4*)(feat + (size_t)node * 128);
    }
    f32x4 acc[4][4];
#pragma unroll
    for (int mt = 0; mt < 4; ++mt)
#pragma unroll
        for (int nt = 0; nt < 4; ++nt) acc[mt][nt] = (f32x4)0.f;

    int kq = lane >> 4;
#pragma unroll
    for (int ks = 0; ks < 4; ++ks) {
        U4S8 a[4], b[4];
#pragma unroll
        for (int mt = 0; mt < 4; ++mt)
            a[mt].u = wl[(ks * 8 + wr * 4 + mt) * 64 + lane];
#pragma unroll
        for (int nt = 0; nt < 4; ++nt) {
            float4 f0 = brow[nt][ks * 8 + kq * 2];
            float4 f1 = brow[nt][ks * 8 + kq * 2 + 1];
            b[nt].u.x = (unsigned int)f2bf(f0.x) | ((unsigned int)f2bf(f0.y) << 16);
            b[nt].u.y = (unsigned int)f2bf(f0.z) | ((unsigned int)f2bf(f0.w) << 16);
            b[nt].u.z = (unsigned int)f2bf(f1.x) | ((unsigned int)f2bf(f1.y) << 16);
            b[nt].u.w = (unsigned int)f2bf(f1.z) | ((unsigned int)f2bf(f1.w) << 16);
        }
#pragma unroll
        for (int mt = 0; mt < 4; ++mt)
#pragma unroll
            for (int nt = 0; nt < 4; ++nt)
                acc[mt][nt] = __builtin_amdgcn_mfma_f32_16x16x32_bf16(
                    a[mt].s, b[nt].s, acc[mt][nt], 0, 0, 0);
    }
#pragma unroll
    for (int nt = 0; nt < 4; ++nt) {
        int node = nbase + nt * 16 + (lane & 15);
        if (node >= nrows) continue;
#pragma unroll
        for (int mt = 0; mt < 4; ++mt) {
            int chan = cb + (wr << 6) + mt * 16 + (lane >> 4) * 4;
            f32x4 v = acc[mt][nt];
            unsigned int p0 = (unsigned int)f2bf(v.x) | ((unsigned int)f2bf(v.y) << 16);
            unsigned int p1 = (unsigned int)f2bf(v.z) | ((unsigned int)f2bf(v.w) << 16);
            *(uint2*)(C + (size_t)node * ocols + chan) = make_uint2(p0, p1);
        }
    }
}

// ---------------- fused GCN: 16B/lane gather, 4 rows in flight, LN + ReLU ---
// wave per node; lane = (quarter q=lane>>4, fl=lane&15); 8 feats/lane.
// indices/weights broadcast via shfl (lanes >= cnt carry w=0 -> no masking).
__global__ __launch_bounds__(TPB) void k_gcn_fused(const unsigned short* __restrict__ hb,
                                                   const int* __restrict__ csr_src,
                                                   const int* __restrict__ row_start,
                                                   const float* __restrict__ dis,
                                                   const float* __restrict__ b,
                                                   const float* __restrict__ g,
                                                   const float* __restrict__ beta,
                                                   unsigned short* __restrict__ out, int n) {
    int node = (blockIdx.x * TPB + threadIdx.x) >> 6;
    int lane = threadIdx.x & 63;
    if (node >= n) return;
    int s0 = row_start[node], s1 = row_start[node + 1];
    float dn = dis[node];
    const uint4* hq = (const uint4*)hb;   // row = 16 uint4 (128 bf16)
    int q = lane >> 4, fl = lane & 15;
    float acc[8];
#pragma unroll
    for (int i = 0; i < 8; ++i) acc[i] = 0.f;
    for (int base = s0; base < s1; base += 64) {
        int cnt = min(64, s1 - base);
        int sidx = 0; float w = 0.f;
        if (lane < cnt) { sidx = csr_src[base + lane]; w = dis[sidx]; }
        for (int j = 0; j < cnt; j += 16) {   // 4 rows in flight per quarter
            int j0 = j + q, j1 = j + 4 + q, j2 = j + 8 + q, j3 = j + 12 + q;
            int   sA = __shfl(sidx, j0), sB = __shfl(sidx, j1);
            int   sC = __shfl(sidx, j2), sD = __shfl(sidx, j3);
            float wA = __shfl(w, j0), wB = __shfl(w, j1);
            float wC = __shfl(w, j2), wD = __shfl(w, j3);
            uint4 uA = hq[(size_t)sA * 16 + fl];
            uint4 uB = hq[(size_t)sB * 16 + fl];
            uint4 uC = hq[(size_t)sC * 16 + fl];
            uint4 uD = hq[(size_t)sD * 16 + fl];
            float2 p0 = bf2x(uA.x), p1 = bf2x(uA.y), p2 = bf2x(uA.z), p3 = bf2x(uA.w);
            acc[0] += wA * p0.x; acc[1] += wA * p0.y;
            acc[2] += wA * p1.x; acc[3] += wA * p1.y;
            acc[4] += wA * p2.x; acc[5] += wA * p2.y;
            acc[6] += wA * p3.x; acc[7] += wA * p3.y;
            p0 = bf2x(uB.x); p1 = bf2x(uB.y); p2 = bf2x(uB.z); p3 = bf2x(uB.w);
            acc[0] += wB * p0.x; acc[1] += wB * p0.y;
            acc[2] += wB * p1.x; acc[3] += wB * p1.y;
            acc[4] += wB * p2.x; acc[5] += wB * p2.y;
            acc[6] += wB * p3.x; acc[7] += wB * p3.y;
            p0 = bf2x(uC.x); p1 = bf2x(uC.y); p2 = bf2x(uC.z); p3 = bf2x(uC.w);
            acc[0] += wC * p0.x; acc[1] += wC * p0.y;
            acc[2] += wC * p1.x; acc[3] += wC * p1.y;
            acc[4] += wC * p2.x; acc[5] += wC * p2.y;
            acc[6] += wC * p3.x; acc[7] += wC * p3.y;
            p0 = bf2x(uD.x); p1 = bf2x(uD.y); p2 = bf2x(uD.z); p3 = bf2x(uD.w);
            acc[0] += wD * p0.x; acc[1] += wD * p0.y;
            acc[2] += wD * p1.x; acc[3] += wD * p1.y;
            acc[4] += wD * p2.x; acc[5] += wD * p2.y;
            acc[6] += wD * p3.x; acc[7] += wD * p3.y;
        }
    }
    // combine quarters: lanes with same fl hold disjoint edge subsets
#pragma unroll
    for (int i = 0; i < 8; ++i) {
        acc[i] += __shfl_xor(acc[i], 16);
        acc[i] += __shfl_xor(acc[i], 32);
    }
    float sl = dn * dn;
    uint4 us = hq[(size_t)node * 16 + fl];
    float2 h0 = bf2x(us.x), h1 = bf2x(us.y), h2 = bf2x(us.z), h3 = bf2x(us.w);
    float4 b0 = ((const float4*)b)[fl * 2], b1 = ((const float4*)b)[fl * 2 + 1];
    float v[8];
    v[0] = dn * acc[0] + sl * h0.x + b0.x;
    v[1] = dn * acc[1] + sl * h0.y + b0.y;
    v[2] = dn * acc[2] + sl * h1.x + b0.z;
    v[3] = dn * acc[3] + sl * h1.y + b0.w;
    v[4] = dn * acc[4] + sl * h2.x + b1.x;
    v[5] = dn * acc[5] + sl * h2.y + b1.y;
    v[6] = dn * acc[6] + sl * h3.x + b1.z;
    v[7] = dn * acc[7] + sl * h3.y + b1.w;
    float s = 0.f, sq = 0.f;
#pragma unroll
    for (int i = 0; i < 8; ++i) { s += v[i]; sq += v[i] * v[i]; }
#pragma unroll
    for (int o = 8; o > 0; o >>= 1) {
        s  += __shfl_xor(s, o);
        sq += __shfl_xor(sq, o);
    }
    float mu = s * (1.f / 128.f);
    float var = sq * (1.f / 128.f) - mu * mu;
    float rstd = rsqrtf(var + 1e-5f);
    float4 g0  = ((const float4*)g)[fl * 2],    g1v = ((const float4*)g)[fl * 2 + 1];
    float4 bt0 = ((const float4*)beta)[fl * 2], bt1 = ((const float4*)beta)[fl * 2 + 1];
    float o0 = fmaxf((v[0] - mu) * rstd * g0.x + bt0.x, 0.f);
    float o1 = fmaxf((v[1] - mu) * rstd * g0.y + bt0.y, 0.f);
    float o2 = fmaxf((v[2] - mu) * rstd * g0.z + bt0.z, 0.f);
    float o3 = fmaxf((v[3] - mu) * rstd * g0.w + bt0.w, 0.f);
    float o4 = fmaxf((v[4] - mu) * rstd * g1v.x + bt1.x, 0.f);
    float o5 = fmaxf((v[5] - mu) * rstd * g1v.y + bt1.y, 0.f);
    float o6 = fmaxf((v[6] - mu) * rstd * g1v.z + bt1.z, 0.f);
    float o7 = fmaxf((v[7] - mu) * rstd * g1v.w + bt1.w, 0.f);
    if (q == 0) {
        uint4 pk;
        pk.x = (unsigned int)f2bf(o0) | ((unsigned int)f2bf(o1) << 16);
        pk.y = (unsigned int)f2bf(o2) | ((unsigned int)f2bf(o3) << 16);
        pk.z = (unsigned int)f2bf(o4) | ((unsigned int)f2bf(o5) << 16);
        pk.w = (unsigned int)f2bf(o6) | ((unsigned int)f2bf(o7) << 16);
        ((uint4*)out)[(size_t)node * 16 + fl] = pk;
    }
}

// ---------------- fused GAT: softmax + gather (x4 unroll) + bias/relu -------
__global__ __launch_bounds__(TPB) void k_gat_fused(const unsigned short* __restrict__ hgb,
                                                   const float* __restrict__ a_s,
                                                   const float* __restrict__ a_d,
                                                   const int* __restrict__ csr_src,
                                                   const int* __restrict__ row_start,
                                                   const float* __restrict__ gat_b,
                                                   float* __restrict__ node_out, int n) {
    __shared__ int   ssrc[4][64];
    __shared__ float swt[4][4][65];
    int node = (blockIdx.x * TPB + threadIdx.x) >> 6;
    int lane = threadIdx.x & 63;
    int wid = threadIdx.x >> 6;
    if (node >= n) return;
    int s0 = row_start[node], s1 = row_start[node + 1];
    int h = lane >> 4;
    const float4* as4 = (const float4*)a_s;
    float4 ad = ((const float4*)a_d)[node];
    float4 asn = as4[node];
    float4 wself;
    wself.x = __expf(lrelu(asn.x + ad.x));
    wself.y = __expf(lrelu(asn.y + ad.y));
    wself.z = __expf(lrelu(asn.z + ad.z));
    wself.w = __expf(lrelu(asn.w + ad.w));
    const uint4* hq = (const uint4*)hgb;
    float acc[8];
    {
        float wsh = sel4(wself, h);
        uint4 u = hq[(size_t)node * 64 + lane];
        float2 p0 = bf2x(u.x), p1 = bf2x(u.y), p2 = bf2x(u.z), p3 = bf2x(u.w);
        acc[0] = wsh * p0.x; acc[1] = wsh * p0.y;
        acc[2] = wsh * p1.x; acc[3] = wsh * p1.y;
        acc[4] = wsh * p2.x; acc[5] = wsh * p2.y;
        acc[6] = wsh * p3.x; acc[7] = wsh * p3.y;
    }
    float4 den = make_float4(0.f, 0.f, 0.f, 0.f);
    for (int base = s0; base < s1; base += 64) {
        int cnt = min(64, s1 - base);
        int sidx = 0;
        float4 w4 = make_float4(0.f, 0.f, 0.f, 0.f);
        if (lane < cnt) {
            sidx = csr_src[base + lane];
            float4 a = as4[sidx];
            w4.x = __expf(lrelu(a.x + ad.x));
            w4.y = __expf(lrelu(a.y + ad.y));
            w4.z = __expf(lrelu(a.z + ad.z));
            w4.w = __expf(lrelu(a.w + ad.w));
            den.x += w4.x; den.y += w4.y; den.z += w4.z; den.w += w4.w;
        }
        ssrc[wid][lane] = sidx;
        swt[wid][0][lane] = w4.x;
        swt[wid][1][lane] = w4.y;
        swt[wid][2][lane] = w4.z;
        swt[wid][3][lane] = w4.w;
        int j = 0;
        for (; j + 4 <= cnt; j += 4) {
            int sa = ssrc[wid][j + 0], sb = ssrc[wid][j + 1];
            int sc = ssrc[wid][j + 2], sd = ssrc[wid][j + 3];
            float wa = swt[wid][h][j + 0], wb = swt[wid][h][j + 1];
            float wc = swt[wid][h][j + 2], wd = swt[wid][h][j + 3];
            uint4 ua = hq[(size_t)sa * 64 + lane];
            uint4 ub = hq[(size_t)sb * 64 + lane];
            uint4 uc = hq[(size_t)sc * 64 + lane];
            uint4 ud = hq[(size_t)sd * 64 + lane];
            float2 p0, p1, p2, p3;
            p0 = bf2x(ua.x); p1 = bf2x(ua.y); p2 = bf2x(ua.z); p3 = bf2x(ua.w);
            acc[0] += wa * p0.x; acc[1] += wa * p0.y; acc[2] += wa * p1.x; acc[3] += wa * p1.y;
            acc[4] += wa * p2.x; acc[5] += wa * p2.y; acc[6] += wa * p3.x; acc[7] += wa * p3.y;
            p0 = bf2x(ub.x); p1 = bf2x(ub.y); p2 = bf2x(ub.z); p3 = bf2x(ub.w);
            acc[0] += wb * p0.x; acc[1] += wb * p0.y; acc[2] += wb * p1.x; acc[3] += wb * p1.y;
            acc[4] += wb * p2.x; acc[5] += wb * p2.y; acc[6] += wb * p3.x; acc[7] += wb * p3.y;
            p0 = bf2x(uc.x); p1 = bf2x(uc.y); p2 = bf2x(uc.z); p3 = bf2x(uc.w);
            acc[0] += wc * p0.x; acc[1] += wc * p0.y; acc[2] += wc * p1.x; acc[3] += wc * p1.y;
            acc[4] += wc * p2.x; acc[5] += wc * p2.y; acc[6] += wc * p3.x; acc[7] += wc * p3.y;
            p0 = bf2x(ud.x); p1 = bf2x(ud.y); p2 = bf2x(ud.z); p3 = bf2x(ud.w);
            acc[0] += wd * p0.x; acc[1] += wd * p0.y; acc[2] += wd * p1.x; acc[3] += wd * p1.y;
            acc[4] += wd * p2.x; acc[5] += wd * p2.y; acc[6] += wd * p3.x; acc[7] += wd * p3.y;
        }
        for (; j < cnt; ++j) {
            int s = ssrc[wid][j];
            float wj = swt[wid][h][j];
            uint4 u = hq[(size_t)s * 64 + lane];
            float2 p0 = bf2x(u.x), p1 = bf2x(u.y), p2 = bf2x(u.z), p3 = bf2x(u.w);
            acc[0] += wj * p0.x; acc[1] += wj * p0.y;
            acc[2] += wj * p1.x; acc[3] += wj * p1.y;
            acc[4] += wj * p2.x; acc[5] += wj * p2.y;
            acc[6] += wj * p3.x; acc[7] += wj * p3.y;
        }
    }
#pragma unroll
    for (int o = 32; o > 0; o >>= 1) {
        den.x += __shfl_xor(den.x, o);
        den.y += __shfl_xor(den.y, o);
        den.z += __shfl_xor(den.z, o);
        den.w += __shfl_xor(den.w, o);
    }
    den.x += wself.x; den.y += wself.y; den.z += wself.z; den.w += wself.w;
    float winv = 0.25f / sel4(den, h);
#pragma unroll
    for (int j = 0; j < 8; ++j) acc[j] *= winv;
#pragma unroll
    for (int j = 0; j < 8; ++j) acc[j] += __shfl_xor(acc[j], 16);
#pragma unroll
    for (int j = 0; j < 8; ++j) acc[j] += __shfl_xor(acc[j], 32);
    int fl = lane & 15;
    float4 gb0 = ((const float4*)gat_b)[fl * 2], gb1 = ((const float4*)gat_b)[fl * 2 + 1];
    if (lane < 16) {
        float4* o4 = (float4*)(node_out + (size_t)node * 128 + fl * 8);
        o4[0] = make_float4(fmaxf(acc[0] + gb0.x, 0.f), fmaxf(acc[1] + gb0.y, 0.f),
                            fmaxf(acc[2] + gb0.z, 0.f), fmaxf(acc[3] + gb0.w, 0.f));
        o4[1] = make_float4(fmaxf(acc[4] + gb1.x, 0.f), fmaxf(acc[5] + gb1.y, 0.f),
                            fmaxf(acc[6] + gb1.z, 0.f), fmaxf(acc[7] + gb1.w, 0.f));
    }
}

// ---------------- pooling: run-batched atomics over sorted batch ------------
__global__ __launch_bounds__(TPB) void k_pool(const float* __restrict__ node_out,
                                              const int* __restrict__ batch,
                                              float* __restrict__ mean_acc,
                                              float* __restrict__ max_acc,
                                              float* __restrict__ cnt, int n) {
    int wave = (blockIdx.x * TPB + threadIdx.x) >> 6;
    int lane = threadIdx.x & 63;
    int n0 = wave * 16;
    if (n0 >= n) return;
    int n1 = min(n0 + 16, n);
    float2 bsum = make_float2(0.f, 0.f), bmax = make_float2(0.f, 0.f);
    int cur_g = batch[n0];
    int cntloc = 0;
    for (int nn = n0; nn < n1; ++nn) {
        int g = batch[nn];
        if (g != cur_g) {
            float* ma = mean_acc + cur_g * 128 + lane * 2;
            atomicAdd(ma + 0, bsum.x);
            atomicAdd(ma + 1, bsum.y);
            int* mxp = (int*)(max_acc + cur_g * 128 + lane * 2);
            atomicMax(mxp + 0, __float_as_int(bmax.x));
            atomicMax(mxp + 1, __float_as_int(bmax.y));
            if (lane == 0) atomicAdd(&cnt[cur_g], (float)cntloc);
            bsum = make_float2(0.f, 0.f);
            bmax = make_float2(0.f, 0.f);
            cntloc = 0;
            cur_g = g;
        }
        float2 o = ((const float2*)node_out)[(size_t)nn * 64 + lane];
        bsum.x += o.x; bsum.y += o.y;
        bmax.x = fmaxf(bmax.x, o.x); bmax.y = fmaxf(bmax.y, o.y);
        ++cntloc;
    }
    float* ma = mean_acc + cur_g * 128 + lane * 2;
    atomicAdd(ma + 0, bsum.x);
    atomicAdd(ma + 1, bsum.y);
    int* mxp = (int*)(max_acc + cur_g * 128 + lane * 2);
    atomicMax(mxp + 0, __float_as_int(bmax.x));
    atomicMax(mxp + 1, __float_as_int(bmax.y));
    if (lane == 0) atomicAdd(&cnt[cur_g], (float)cntloc);
}

__global__ __launch_bounds__(TPB) void k_pool_final(const float* __restrict__ mean_acc,
                                                    const float* __restrict__ max_acc,
                                                    const float* __restrict__ cnt,
                                                    float* __restrict__ gout, int g128) {
    int i = blockIdx.x * TPB + threadIdx.x;
    if (i >= g128) return;
    int g = i >> 7, d = i & 127;
    float c = fmaxf(cnt[g], 1.f);
    gout[g * 256 + d] = mean_acc[i] / c;
    gout[g * 256 + 128 + d] = max_acc[i];
}

// ---------------------------------------------------------------------------
extern "C" void kernel_launch(void* const* d_in, const int* in_sizes, int n_in,
                              void* d_out, int out_size, void* d_ws, size_t ws_size,
                              hipStream_t stream) {
    const float* x       = (const float*)d_in[0];
    const int*   ei      = (const int*)d_in[1];
    const int*   batch   = (const int*)d_in[2];
    const float* W1      = (const float*)d_in[3];
    const float* b1      = (const float*)d_in[4];
    const float* g1      = (const float*)d_in[5];
    const float* beta1   = (const float*)d_in[6];
    const float* W2      = (const float*)d_in[7];
    const float* b2      = (const float*)d_in[8];
    const float* g2      = (const float*)d_in[9];
    const float* beta2   = (const float*)d_in[10];
    const float* gat_W   = (const float*)d_in[11];
    const float* att_src = (const float*)d_in[12];
    const float* att_dst = (const float*)d_in[13];
    const float* gat_b   = (const float*)d_in[14];

    const int N = in_sizes[0] / 128;
    const int E = in_sizes[1] / 2;
    const int G = (out_size - N * 128) / 256;
    const int* src = ei;
    const int* dst = ei + E;

    float* ws = (float*)d_ws;
    float* dis      = ws; ws += N;
    float* a_s      = ws; ws += N * 4;
    float* a_d      = ws; ws += N * 4;
    float* mean_acc = ws; ws += G * 128;
    float* max_acc  = ws; ws += G * 128;
    float* cnt      = ws; ws += G;
    unsigned short* Hbf = (unsigned short*)ws; ws += (size_t)N * 64;
    unsigned short* Bbf = (unsigned short*)ws; ws += (size_t)N * 64;
    unsigned short* Cbf = (unsigned short*)ws; ws += (size_t)N * 64;
    unsigned short* hgb = (unsigned short*)ws; ws += (size_t)N * 256;
    unsigned short* Wt1 = (unsigned short*)ws; ws += 128 * 64;
    unsigned short* Wt2 = (unsigned short*)ws; ws += 128 * 64;
    unsigned short* Wtg = (unsigned short*)ws; ws += 512 * 64;
    int* deg       = (int*)ws; ws += N;
    int* part      = (int*)ws; ws += 256;
    int* row_start = (int*)ws; ws += N + 1;
    int* cursor    = (int*)ws; ws += N + 1;
    int* csr_src   = (int*)ws; ws += E;

    float* gout = (float*)d_out;        // [G, 256]
    float* node_out = gout + G * 256;   // [N, 128]

    auto cdiv = [](long a, long b) { return (int)((a + b - 1) / b); };
    const int nb = cdiv(N, TPB);

    // CSR build (by dst) + degrees; scan merged with weight transposes
    hipMemsetAsync(deg, 0, (size_t)N * 4, stream);
    k_hist<<<cdiv(E, TPB), TPB, 0, stream>>>(dst, deg, E);
    k_scan_part_wt<<<nb + cdiv(98304, TPB), TPB, 0, stream>>>(deg, part, N, nb,
                                                              W1, W2, gat_W, Wt1, Wt2, Wtg);
    k_scan_apply<<<nb, TPB, 0, stream>>>(deg, part, row_start, cursor, dis, N, E);
    k_scatter<<<cdiv(E, TPB), TPB, 0, stream>>>(src, dst, cursor, csr_src, E);

    // GCN layer 1 (gemm reads fp32 x directly)
    k_gemm_mfma_f32<<<dim3(cdiv(N, 128), 1), TPB, 0, stream>>>(x, Wt1, Hbf, N, 128);
    k_gcn_fused<<<cdiv((long)N * 64, TPB), TPB, 0, stream>>>(Hbf, csr_src, row_start, dis,
                                                             b1, g1, beta1, Bbf, N);
    // GCN layer 2
    k_gemm_mfma<<<dim3(cdiv(N, 128), 1), TPB, 0, stream>>>(Bbf, Wt2, Hbf, N, 128,
                                                           nullptr, nullptr, nullptr, nullptr);
    k_gcn_fused<<<cdiv((long)N * 64, TPB), TPB, 0, stream>>>(Hbf, csr_src, row_start, dis,
                                                             b2, g2, beta2, Cbf, N);
    // GAT gemm (+fused attention dots per head slice)
    k_gemm_mfma<<<dim3(cdiv(N, 128), 4), TPB, 0, stream>>>(Cbf, Wtg, hgb, N, 512,
                                                           att_src, att_dst, a_s, a_d);
    k_gat_fused<<<cdiv((long)N * 64, TPB), TPB, 0, stream>>>(hgb, a_s, a_d, csr_src, row_start,
                                                             gat_b, node_out, N);

    // pooling
    hipMemsetAsync(mean_acc, 0, (size_t)(G * 256 + G) * 4, stream);
    k_pool<<<cdiv((long)cdiv(N, 16) * 64, TPB), TPB, 0, stream>>>(node_out, batch,
                                                                  mean_acc, max_acc, cnt, N);
    k_pool_final<<<cdiv((long)G * 128, TPB), TPB, 0, stream>>>(mean_acc, max_acc, cnt, gout, G * 128);
}

// Round 10
// 407.200 us; speedup vs baseline: 1.1182x; 1.0414x over previous
//
#include <hip/hip_runtime.h>
#include <math.h>

// ---------------------------------------------------------------------------
// HOGGraphNet: 2x GCNConv(+LN+ReLU) -> GATConv(4 heads, mean) -> mean/max pool
// N=50000, E=600000, D=128, H=4, G=64. CSR gather-side aggregation.
// bf16 features; GEMMs on MFMA. k_gat_fused pinned at the random-gather
// HBM floor (~362MB fetch @ ~3.7TB/s). CSR carries precomputed edge weights.
// ---------------------------------------------------------------------------

#define TPB 256

typedef __attribute__((ext_vector_type(8))) short short8;
typedef __attribute__((ext_vector_type(4))) float f32x4;
union U4S8 { uint4 u; short8 s; };

__device__ __forceinline__ float lrelu(float x) { return x > 0.f ? x : 0.2f * x; }

__device__ __forceinline__ unsigned short f2bf(float f) {  // RTNE
    unsigned int u = __float_as_uint(f);
    u += 0x7fffu + ((u >> 16) & 1u);
    return (unsigned short)(u >> 16);
}
__device__ __forceinline__ float2 bf2x(unsigned int u) {   // [lo,hi] bf16 pair
    return make_float2(__uint_as_float(u << 16), __uint_as_float(u & 0xffff0000u));
}
__device__ __forceinline__ float sel4(float4 v, int h) {
    float r = v.x;
    r = (h == 1) ? v.y : r;
    r = (h == 2) ? v.z : r;
    r = (h == 3) ? v.w : r;
    return r;
}
__device__ __forceinline__ float dot4(f32x4 a, float4 b) {
    return a.x * b.x + a.y * b.y + a.z * b.z + a.w * b.w;
}

// ---------------- CSR build ----------------
__global__ __launch_bounds__(TPB) void k_hist(const int* __restrict__ dst,
                                              int* __restrict__ deg, int e) {
    int i = blockIdx.x * TPB + threadIdx.x;
    if (i < e) atomicAdd(&deg[dst[i]], 1);
}

// merged: blocks [0,nb) do per-block deg sums; blocks [nb,..) do W transposes
__global__ __launch_bounds__(TPB) void k_scan_part_wt(const int* __restrict__ deg,
                                                      int* __restrict__ part, int n, int nb,
                                                      const float* __restrict__ W1,
                                                      const float* __restrict__ W2,
                                                      const float* __restrict__ Wg,
                                                      unsigned short* __restrict__ Wt1,
                                                      unsigned short* __restrict__ Wt2,
                                                      unsigned short* __restrict__ Wtg) {
    int bid = blockIdx.x;
    if (bid < nb) {
        int i = bid * TPB + threadIdx.x;
        int v = (i < n) ? deg[i] : 0;
#pragma unroll
        for (int o = 32; o > 0; o >>= 1) v += __shfl_xor(v, o);
        __shared__ int sw[4];
        if ((threadIdx.x & 63) == 0) sw[threadIdx.x >> 6] = v;
        __syncthreads();
        if (threadIdx.x == 0) part[bid] = sw[0] + sw[1] + sw[2] + sw[3];
    } else {
        int i = (bid - nb) * TPB + threadIdx.x;  // 0..98303
        if (i < 16384) {
            int k = i >> 7, c = i & 127;
            Wt1[c * 128 + k] = f2bf(W1[i]);
        } else if (i < 32768) {
            int j = i - 16384;
            int k = j >> 7, c = j & 127;
            Wt2[c * 128 + k] = f2bf(W2[j]);
        } else if (i < 98304) {
            int j = i - 32768;
            int k = j >> 9, c = j & 511;
            Wtg[c * 128 + k] = f2bf(Wg[j]);
        }
    }
}

// in-block exclusive scan; block base = reduce of preceding partials (nb<=256)
__global__ __launch_bounds__(TPB) void k_scan_apply(const int* __restrict__ deg,
                                                    const int* __restrict__ part,
                                                    int* __restrict__ row_start,
                                                    int* __restrict__ cursor,
                                                    float* __restrict__ dis,
                                                    int n, int e_total) {
    __shared__ int sm[TPB];
    __shared__ int sred[4];
    int t = threadIdx.x;
    int bid = blockIdx.x;
    int pv = (t < bid) ? part[t] : 0;
#pragma unroll
    for (int o = 32; o > 0; o >>= 1) pv += __shfl_xor(pv, o);
    if ((t & 63) == 0) sred[t >> 6] = pv;
    __syncthreads();
    int basep = sred[0] + sred[1] + sred[2] + sred[3];
    int i = bid * TPB + t;
    int d = (i < n) ? deg[i] : 0;
    sm[t] = d;
    __syncthreads();
    for (int off = 1; off < TPB; off <<= 1) {
        int u = (t >= off) ? sm[t - off] : 0;
        __syncthreads();
        sm[t] += u;
        __syncthreads();
    }
    if (i < n) {
        int rs = basep + sm[t] - d;
        row_start[i] = rs;
        cursor[i] = rs;
        dis[i] = rsqrtf((float)(d + 1));
    }
    if (bid == 0 && t == 0) row_start[n] = e_total;
}

// ---------------- merged: gemm1 (fp32 x -> Hbf) || CSR scatter --------------
// blocks [0,gb): MFMA gemm (layer-1, fp32 features); blocks [gb,..): scatter
// writing csr_src + precomputed edge weight csr_w = dis[src].
__global__ __launch_bounds__(TPB, 2) void k_gemm1_scatter(const float* __restrict__ feat,
                                                          const unsigned short* __restrict__ Wt,
                                                          unsigned short* __restrict__ C,
                                                          int nrows, int gb,
                                                          const int* __restrict__ src,
                                                          const int* __restrict__ dst,
                                                          const float* __restrict__ dis,
                                                          int* __restrict__ cursor,
                                                          int* __restrict__ csr_src,
                                                          float* __restrict__ csr_w, int e) {
    __shared__ uint4 wl[2048];
    int t = threadIdx.x;
    if (blockIdx.x >= gb) {
        int i = (blockIdx.x - gb) * TPB + t;
        if (i < e) {
            int s = src[i];
            int p = atomicAdd(&cursor[dst[i]], 1);
            csr_src[p] = s;
            csr_w[p] = dis[s];
        }
        return;
    }
#pragma unroll
    for (int i = 0; i < 8; ++i) {
        int fi = i * 256 + t;
        int l = fi & 63, ct = (fi >> 6) & 7, ks = fi >> 9;
        int chan = ct * 16 + (l & 15);
        wl[fi] = ((const uint4*)(Wt + (size_t)chan * 128))[ks * 4 + (l >> 4)];
    }
    __syncthreads();

    int wave = t >> 6, lane = t & 63;
    int wr = wave >> 1, wc = wave & 1;
    int nbase = (blockIdx.x << 7) + (wc << 6);
    const float4* brow[4];
#pragma unroll
    for (int nt = 0; nt < 4; ++nt) {
        int node = nbase + nt * 16 + (lane & 15);
        node = node < nrows ? node : (nrows - 1);
        brow[nt] = (const float4*)(feat + (size_t)node * 128);
    }
    f32x4 acc[4][4];
#pragma unroll
    for (int mt = 0; mt < 4; ++mt)
#pragma unroll
        for (int nt = 0; nt < 4; ++nt) acc[mt][nt] = (f32x4)0.f;

    int kq = lane >> 4;
#pragma unroll
    for (int ks = 0; ks < 4; ++ks) {
        U4S8 a[4], b[4];
#pragma unroll
        for (int mt = 0; mt < 4; ++mt)
            a[mt].u = wl[(ks * 8 + wr * 4 + mt) * 64 + lane];
#pragma unroll
        for (int nt = 0; nt < 4; ++nt) {
            float4 f0 = brow[nt][ks * 8 + kq * 2];
            float4 f1 = brow[nt][ks * 8 + kq * 2 + 1];
            b[nt].u.x = (unsigned int)f2bf(f0.x) | ((unsigned int)f2bf(f0.y) << 16);
            b[nt].u.y = (unsigned int)f2bf(f0.z) | ((unsigned int)f2bf(f0.w) << 16);
            b[nt].u.z = (unsigned int)f2bf(f1.x) | ((unsigned int)f2bf(f1.y) << 16);
            b[nt].u.w = (unsigned int)f2bf(f1.z) | ((unsigned int)f2bf(f1.w) << 16);
        }
#pragma unroll
        for (int mt = 0; mt < 4; ++mt)
#pragma unroll
            for (int nt = 0; nt < 4; ++nt)
                acc[mt][nt] = __builtin_amdgcn_mfma_f32_16x16x32_bf16(
                    a[mt].s, b[nt].s, acc[mt][nt], 0, 0, 0);
    }
#pragma unroll
    for (int nt = 0; nt < 4; ++nt) {
        int node = nbase + nt * 16 + (lane & 15);
        if (node >= nrows) continue;
#pragma unroll
        for (int mt = 0; mt < 4; ++mt) {
            int chan = (wr << 6) + mt * 16 + (lane >> 4) * 4;
            f32x4 v = acc[mt][nt];
            unsigned int p0 = (unsigned int)f2bf(v.x) | ((unsigned int)f2bf(v.y) << 16);
            unsigned int p1 = (unsigned int)f2bf(v.z) | ((unsigned int)f2bf(v.w) << 16);
            *(uint2*)(C + (size_t)node * 128 + chan) = make_uint2(p0, p1);
        }
    }
}

// ---------------- MFMA GEMM core (bf16 features in) -------------------------
__global__ __launch_bounds__(TPB, 2) void k_gemm_mfma(const unsigned short* __restrict__ feat,
                                                      const unsigned short* __restrict__ Wt,
                                                      unsigned short* __restrict__ C,
                                                      int nrows, int ocols,
                                                      const float* __restrict__ att_s,
                                                      const float* __restrict__ att_d,
                                                      float* __restrict__ a_s,
                                                      float* __restrict__ a_d) {
    __shared__ uint4 wl[2048];  // 32KB fragment-linear Wt tile
    __shared__ float sas[128], sad[128];
    int t = threadIdx.x;
    int cb = blockIdx.y << 7;
#pragma unroll
    for (int i = 0; i < 8; ++i) {
        int fi = i * 256 + t;
        int l = fi & 63, ct = (fi >> 6) & 7, ks = fi >> 9;
        int chan = cb + ct * 16 + (l & 15);
        wl[fi] = ((const uint4*)(Wt + (size_t)chan * 128))[ks * 4 + (l >> 4)];
    }
    __syncthreads();

    int wave = t >> 6, lane = t & 63;
    int wr = wave >> 1, wc = wave & 1;
    int nbase = (blockIdx.x << 7) + (wc << 6);
    const uint4* brow[4];
#pragma unroll
    for (int nt = 0; nt < 4; ++nt) {
        int node = nbase + nt * 16 + (lane & 15);
        node = node < nrows ? node : (nrows - 1);
        brow[nt] = (const uint4*)(feat + (size_t)node * 128);
    }
    f32x4 acc[4][4];
#pragma unroll
    for (int mt = 0; mt < 4; ++mt)
#pragma unroll
        for (int nt = 0; nt < 4; ++nt) acc[mt][nt] = (f32x4)0.f;

    int kq = lane >> 4;
#pragma unroll
    for (int ks = 0; ks < 4; ++ks) {
        U4S8 a[4], b[4];
#pragma unroll
        for (int mt = 0; mt < 4; ++mt)
            a[mt].u = wl[(ks * 8 + wr * 4 + mt) * 64 + lane];
#pragma unroll
        for (int nt = 0; nt < 4; ++nt)
            b[nt].u = brow[nt][ks * 4 + kq];
#pragma unroll
        for (int mt = 0; mt < 4; ++mt)
#pragma unroll
            for (int nt = 0; nt < 4; ++nt)
                acc[mt][nt] = __builtin_amdgcn_mfma_f32_16x16x32_bf16(
                    a[mt].s, b[nt].s, acc[mt][nt], 0, 0, 0);
    }
    // C/D layout: col(node)=lane&15, row(chan)=(lane>>4)*4+reg
#pragma unroll
    for (int nt = 0; nt < 4; ++nt) {
        int node = nbase + nt * 16 + (lane & 15);
        if (node >= nrows) continue;
#pragma unroll
        for (int mt = 0; mt < 4; ++mt) {
            int chan = cb + (wr << 6) + mt * 16 + (lane >> 4) * 4;
            f32x4 v = acc[mt][nt];
            unsigned int p0 = (unsigned int)f2bf(v.x) | ((unsigned int)f2bf(v.y) << 16);
            unsigned int p1 = (unsigned int)f2bf(v.z) | ((unsigned int)f2bf(v.w) << 16);
            *(uint2*)(C + (size_t)node * ocols + chan) = make_uint2(p0, p1);
        }
    }
    // ---- fused attention dots (GAT gemm only): head h = blockIdx.y ----
    if (att_s) {
        if (t < 128) { sas[t] = 0.f; sad[t] = 0.f; }
        __syncthreads();
        int h = blockIdx.y;
        float4 asv[4], adv[4];
#pragma unroll
        for (int mt = 0; mt < 4; ++mt) {
            int cbase = h * 128 + (wr << 6) + mt * 16 + (lane >> 4) * 4;
            asv[mt] = *(const float4*)(att_s + cbase);
            adv[mt] = *(const float4*)(att_d + cbase);
        }
#pragma unroll
        for (int nt = 0; nt < 4; ++nt) {
            float ds = 0.f, dd = 0.f;
#pragma unroll
            for (int mt = 0; mt < 4; ++mt) {
                ds += dot4(acc[mt][nt], asv[mt]);
                dd += dot4(acc[mt][nt], adv[mt]);
            }
            ds += __shfl_xor(ds, 16); ds += __shfl_xor(ds, 32);
            dd += __shfl_xor(dd, 16); dd += __shfl_xor(dd, 32);
            if (lane < 16) {
                atomicAdd(&sas[(wc << 6) + nt * 16 + lane], ds);
                atomicAdd(&sad[(wc << 6) + nt * 16 + lane], dd);
            }
        }
        __syncthreads();
        if (t < 128) {
            int node = (blockIdx.x << 7) + t;
            if (node < nrows) a_s[node * 4 + h] = sas[t];
        } else {
            int t2 = t - 128;
            int node = (blockIdx.x << 7) + t2;
            if (node < nrows) a_d[node * 4 + h] = sad[t2];
        }
    }
}

// ---------------- fused GCN: coalesced idx+weight, 4 rows in flight ---------
// wave per node; lane = (quarter q=lane>>4, fl=lane&15); 8 feats/lane.
__global__ __launch_bounds__(TPB) void k_gcn_fused(const unsigned short* __restrict__ hb,
                                                   const int* __restrict__ csr_src,
                                                   const float* __restrict__ csr_w,
                                                   const int* __restrict__ row_start,
                                                   const float* __restrict__ dis,
                                                   const float* __restrict__ b,
                                                   const float* __restrict__ g,
                                                   const float* __restrict__ beta,
                                                   unsigned short* __restrict__ out, int n) {
    int node = (blockIdx.x * TPB + threadIdx.x) >> 6;
    int lane = threadIdx.x & 63;
    if (node >= n) return;
    int s0 = row_start[node], s1 = row_start[node + 1];
    float dn = dis[node];
    const uint4* hq = (const uint4*)hb;   // row = 16 uint4 (128 bf16)
    int q = lane >> 4, fl = lane & 15;
    float acc[8];
#pragma unroll
    for (int i = 0; i < 8; ++i) acc[i] = 0.f;
    for (int base = s0; base < s1; base += 64) {
        int cnt = min(64, s1 - base);
        int sidx = 0; float w = 0.f;
        if (lane < cnt) {
            sidx = csr_src[base + lane];
            w = csr_w[base + lane];      // coalesced (no random dis gather)
        }
        for (int j = 0; j < cnt; j += 16) {   // 4 rows in flight per quarter
            int j0 = j + q, j1 = j + 4 + q, j2 = j + 8 + q, j3 = j + 12 + q;
            int   sA = __shfl(sidx, j0), sB = __shfl(sidx, j1);
            int   sC = __shfl(sidx, j2), sD = __shfl(sidx, j3);
            float wA = __shfl(w, j0), wB = __shfl(w, j1);
            float wC = __shfl(w, j2), wD = __shfl(w, j3);
            uint4 uA = hq[(size_t)sA * 16 + fl];
            uint4 uB = hq[(size_t)sB * 16 + fl];
            uint4 uC = hq[(size_t)sC * 16 + fl];
            uint4 uD = hq[(size_t)sD * 16 + fl];
            float2 p0 = bf2x(uA.x), p1 = bf2x(uA.y), p2 = bf2x(uA.z), p3 = bf2x(uA.w);
            acc[0] += wA * p0.x; acc[1] += wA * p0.y;
            acc[2] += wA * p1.x; acc[3] += wA * p1.y;
            acc[4] += wA * p2.x; acc[5] += wA * p2.y;
            acc[6] += wA * p3.x; acc[7] += wA * p3.y;
            p0 = bf2x(uB.x); p1 = bf2x(uB.y); p2 = bf2x(uB.z); p3 = bf2x(uB.w);
            acc[0] += wB * p0.x; acc[1] += wB * p0.y;
            acc[2] += wB * p1.x; acc[3] += wB * p1.y;
            acc[4] += wB * p2.x; acc[5] += wB * p2.y;
            acc[6] += wB * p3.x; acc[7] += wB * p3.y;
            p0 = bf2x(uC.x); p1 = bf2x(uC.y); p2 = bf2x(uC.z); p3 = bf2x(uC.w);
            acc[0] += wC * p0.x; acc[1] += wC * p0.y;
            acc[2] += wC * p1.x; acc[3] += wC * p1.y;
            acc[4] += wC * p2.x; acc[5] += wC * p2.y;
            acc[6] += wC * p3.x; acc[7] += wC * p3.y;
            p0 = bf2x(uD.x); p1 = bf2x(uD.y); p2 = bf2x(uD.z); p3 = bf2x(uD.w);
            acc[0] += wD * p0.x; acc[1] += wD * p0.y;
            acc[2] += wD * p1.x; acc[3] += wD * p1.y;
            acc[4] += wD * p2.x; acc[5] += wD * p2.y;
            acc[6] += wD * p3.x; acc[7] += wD * p3.y;
        }
    }
    // combine quarters: lanes with same fl hold disjoint edge subsets
#pragma unroll
    for (int i = 0; i < 8; ++i) {
        acc[i] += __shfl_xor(acc[i], 16);
        acc[i] += __shfl_xor(acc[i], 32);
    }
    float sl = dn * dn;
    uint4 us = hq[(size_t)node * 16 + fl];
    float2 h0 = bf2x(us.x), h1 = bf2x(us.y), h2 = bf2x(us.z), h3 = bf2x(us.w);
    float4 b0 = ((const float4*)b)[fl * 2], b1 = ((const float4*)b)[fl * 2 + 1];
    float v[8];
    v[0] = dn * acc[0] + sl * h0.x + b0.x;
    v[1] = dn * acc[1] + sl * h0.y + b0.y;
    v[2] = dn * acc[2] + sl * h1.x + b0.z;
    v[3] = dn * acc[3] + sl * h1.y + b0.w;
    v[4] = dn * acc[4] + sl * h2.x + b1.x;
    v[5] = dn * acc[5] + sl * h2.y + b1.y;
    v[6] = dn * acc[6] + sl * h3.x + b1.z;
    v[7] = dn * acc[7] + sl * h3.y + b1.w;
    float s = 0.f, sq = 0.f;
#pragma unroll
    for (int i = 0; i < 8; ++i) { s += v[i]; sq += v[i] * v[i]; }
#pragma unroll
    for (int o = 8; o > 0; o >>= 1) {
        s  += __shfl_xor(s, o);
        sq += __shfl_xor(sq, o);
    }
    float mu = s * (1.f / 128.f);
    float var = sq * (1.f / 128.f) - mu * mu;
    float rstd = rsqrtf(var + 1e-5f);
    float4 g0  = ((const float4*)g)[fl * 2],    g1v = ((const float4*)g)[fl * 2 + 1];
    float4 bt0 = ((const float4*)beta)[fl * 2], bt1 = ((const float4*)beta)[fl * 2 + 1];
    float o0 = fmaxf((v[0] - mu) * rstd * g0.x + bt0.x, 0.f);
    float o1 = fmaxf((v[1] - mu) * rstd * g0.y + bt0.y, 0.f);
    float o2 = fmaxf((v[2] - mu) * rstd * g0.z + bt0.z, 0.f);
    float o3 = fmaxf((v[3] - mu) * rstd * g0.w + bt0.w, 0.f);
    float o4 = fmaxf((v[4] - mu) * rstd * g1v.x + bt1.x, 0.f);
    float o5 = fmaxf((v[5] - mu) * rstd * g1v.y + bt1.y, 0.f);
    float o6 = fmaxf((v[6] - mu) * rstd * g1v.z + bt1.z, 0.f);
    float o7 = fmaxf((v[7] - mu) * rstd * g1v.w + bt1.w, 0.f);
    if (q == 0) {
        uint4 pk;
        pk.x = (unsigned int)f2bf(o0) | ((unsigned int)f2bf(o1) << 16);
        pk.y = (unsigned int)f2bf(o2) | ((unsigned int)f2bf(o3) << 16);
        pk.z = (unsigned int)f2bf(o4) | ((unsigned int)f2bf(o5) << 16);
        pk.w = (unsigned int)f2bf(o6) | ((unsigned int)f2bf(o7) << 16);
        ((uint4*)out)[(size_t)node * 16 + fl] = pk;
    }
}

// ---------------- fused GAT: softmax + gather (x4 unroll) + bias/relu -------
__global__ __launch_bounds__(TPB) void k_gat_fused(const unsigned short* __restrict__ hgb,
                                                   const float* __restrict__ a_s,
                                                   const float* __restrict__ a_d,
                                                   const int* __restrict__ csr_src,
                                                   const int* __restrict__ row_start,
                                                   const float* __restrict__ gat_b,
                                                   float* __restrict__ node_out, int n) {
    __shared__ int   ssrc[4][64];
    __shared__ float swt[4][4][65];
    int node = (blockIdx.x * TPB + threadIdx.x) >> 6;
    int lane = threadIdx.x & 63;
    int wid = threadIdx.x >> 6;
    if (node >= n) return;
    int s0 = row_start[node], s1 = row_start[node + 1];
    int h = lane >> 4;
    const float4* as4 = (const float4*)a_s;
    float4 ad = ((const float4*)a_d)[node];
    float4 asn = as4[node];
    float4 wself;
    wself.x = __expf(lrelu(asn.x + ad.x));
    wself.y = __expf(lrelu(asn.y + ad.y));
    wself.z = __expf(lrelu(asn.z + ad.z));
    wself.w = __expf(lrelu(asn.w + ad.w));
    const uint4* hq = (const uint4*)hgb;
    float acc[8];
    {
        float wsh = sel4(wself, h);
        uint4 u = hq[(size_t)node * 64 + lane];
        float2 p0 = bf2x(u.x), p1 = bf2x(u.y), p2 = bf2x(u.z), p3 = bf2x(u.w);
        acc[0] = wsh * p0.x; acc[1] = wsh * p0.y;
        acc[2] = wsh * p1.x; acc[3] = wsh * p1.y;
        acc[4] = wsh * p2.x; acc[5] = wsh * p2.y;
        acc[6] = wsh * p3.x; acc[7] = wsh * p3.y;
    }
    float4 den = make_float4(0.f, 0.f, 0.f, 0.f);
    for (int base = s0; base < s1; base += 64) {
        int cnt = min(64, s1 - base);
        int sidx = 0;
        float4 w4 = make_float4(0.f, 0.f, 0.f, 0.f);
        if (lane < cnt) {
            sidx = csr_src[base + lane];
            float4 a = as4[sidx];
            w4.x = __expf(lrelu(a.x + ad.x));
            w4.y = __expf(lrelu(a.y + ad.y));
            w4.z = __expf(lrelu(a.z + ad.z));
            w4.w = __expf(lrelu(a.w + ad.w));
            den.x += w4.x; den.y += w4.y; den.z += w4.z; den.w += w4.w;
        }
        ssrc[wid][lane] = sidx;
        swt[wid][0][lane] = w4.x;
        swt[wid][1][lane] = w4.y;
        swt[wid][2][lane] = w4.z;
        swt[wid][3][lane] = w4.w;
        int j = 0;
        for (; j + 4 <= cnt; j += 4) {
            int sa = ssrc[wid][j + 0], sb = ssrc[wid][j + 1];
            int sc = ssrc[wid][j + 2], sd = ssrc[wid][j + 3];
            float wa = swt[wid][h][j + 0], wb = swt[wid][h][j + 1];
            float wc = swt[wid][h][j + 2], wd = swt[wid][h][j + 3];
            uint4 ua = hq[(size_t)sa * 64 + lane];
            uint4 ub = hq[(size_t)sb * 64 + lane];
            uint4 uc = hq[(size_t)sc * 64 + lane];
            uint4 ud = hq[(size_t)sd * 64 + lane];
            float2 p0, p1, p2, p3;
            p0 = bf2x(ua.x); p1 = bf2x(ua.y); p2 = bf2x(ua.z); p3 = bf2x(ua.w);
            acc[0] += wa * p0.x; acc[1] += wa * p0.y; acc[2] += wa * p1.x; acc[3] += wa * p1.y;
            acc[4] += wa * p2.x; acc[5] += wa * p2.y; acc[6] += wa * p3.x; acc[7] += wa * p3.y;
            p0 = bf2x(ub.x); p1 = bf2x(ub.y); p2 = bf2x(ub.z); p3 = bf2x(ub.w);
            acc[0] += wb * p0.x; acc[1] += wb * p0.y; acc[2] += wb * p1.x; acc[3] += wb * p1.y;
            acc[4] += wb * p2.x; acc[5] += wb * p2.y; acc[6] += wb * p3.x; acc[7] += wb * p3.y;
            p0 = bf2x(uc.x); p1 = bf2x(uc.y); p2 = bf2x(uc.z); p3 = bf2x(uc.w);
            acc[0] += wc * p0.x; acc[1] += wc * p0.y; acc[2] += wc * p1.x; acc[3] += wc * p1.y;
            acc[4] += wc * p2.x; acc[5] += wc * p2.y; acc[6] += wc * p3.x; acc[7] += wc * p3.y;
            p0 = bf2x(ud.x); p1 = bf2x(ud.y); p2 = bf2x(ud.z); p3 = bf2x(ud.w);
            acc[0] += wd * p0.x; acc[1] += wd * p0.y; acc[2] += wd * p1.x; acc[3] += wd * p1.y;
            acc[4] += wd * p2.x; acc[5] += wd * p2.y; acc[6] += wd * p3.x; acc[7] += wd * p3.y;
        }
        for (; j < cnt; ++j) {
            int s = ssrc[wid][j];
            float wj = swt[wid][h][j];
            uint4 u = hq[(size_t)s * 64 + lane];
            float2 p0 = bf2x(u.x), p1 = bf2x(u.y), p2 = bf2x(u.z), p3 = bf2x(u.w);
            acc[0] += wj * p0.x; acc[1] += wj * p0.y;
            acc[2] += wj * p1.x; acc[3] += wj * p1.y;
            acc[4] += wj * p2.x; acc[5] += wj * p2.y;
            acc[6] += wj * p3.x; acc[7] += wj * p3.y;
        }
    }
#pragma unroll
    for (int o = 32; o > 0; o >>= 1) {
        den.x += __shfl_xor(den.x, o);
        den.y += __shfl_xor(den.y, o);
        den.z += __shfl_xor(den.z, o);
        den.w += __shfl_xor(den.w, o);
    }
    den.x += wself.x; den.y += wself.y; den.z += wself.z; den.w += wself.w;
    float winv = 0.25f / sel4(den, h);
#pragma unroll
    for (int j = 0; j < 8; ++j) acc[j] *= winv;
#pragma unroll
    for (int j = 0; j < 8; ++j) acc[j] += __shfl_xor(acc[j], 16);
#pragma unroll
    for (int j = 0; j < 8; ++j) acc[j] += __shfl_xor(acc[j], 32);
    int fl = lane & 15;
    float4 gb0 = ((const float4*)gat_b)[fl * 2], gb1 = ((const float4*)gat_b)[fl * 2 + 1];
    if (lane < 16) {
        float4* o4 = (float4*)(node_out + (size_t)node * 128 + fl * 8);
        o4[0] = make_float4(fmaxf(acc[0] + gb0.x, 0.f), fmaxf(acc[1] + gb0.y, 0.f),
                            fmaxf(acc[2] + gb0.z, 0.f), fmaxf(acc[3] + gb0.w, 0.f));
        o4[1] = make_float4(fmaxf(acc[4] + gb1.x, 0.f), fmaxf(acc[5] + gb1.y, 0.f),
                            fmaxf(acc[6] + gb1.z, 0.f), fmaxf(acc[7] + gb1.w, 0.f));
    }
}

// ---------------- pooling: run-batched atomics over sorted batch ------------
__global__ __launch_bounds__(TPB) void k_pool(const float* __restrict__ node_out,
                                              const int* __restrict__ batch,
                                              float* __restrict__ mean_acc,
                                              float* __restrict__ max_acc,
                                              float* __restrict__ cnt, int n) {
    int wave = (blockIdx.x * TPB + threadIdx.x) >> 6;
    int lane = threadIdx.x & 63;
    int n0 = wave * 16;
    if (n0 >= n) return;
    int n1 = min(n0 + 16, n);
    float2 bsum = make_float2(0.f, 0.f), bmax = make_float2(0.f, 0.f);
    int cur_g = batch[n0];
    int cntloc = 0;
    for (int nn = n0; nn < n1; ++nn) {
        int g = batch[nn];
        if (g != cur_g) {
            float* ma = mean_acc + cur_g * 128 + lane * 2;
            atomicAdd(ma + 0, bsum.x);
            atomicAdd(ma + 1, bsum.y);
            int* mxp = (int*)(max_acc + cur_g * 128 + lane * 2);
            atomicMax(mxp + 0, __float_as_int(bmax.x));
            atomicMax(mxp + 1, __float_as_int(bmax.y));
            if (lane == 0) atomicAdd(&cnt[cur_g], (float)cntloc);
            bsum = make_float2(0.f, 0.f);
            bmax = make_float2(0.f, 0.f);
            cntloc = 0;
            cur_g = g;
        }
        float2 o = ((const float2*)node_out)[(size_t)nn * 64 + lane];
        bsum.x += o.x; bsum.y += o.y;
        bmax.x = fmaxf(bmax.x, o.x); bmax.y = fmaxf(bmax.y, o.y);
        ++cntloc;
    }
    float* ma = mean_acc + cur_g * 128 + lane * 2;
    atomicAdd(ma + 0, bsum.x);
    atomicAdd(ma + 1, bsum.y);
    int* mxp = (int*)(max_acc + cur_g * 128 + lane * 2);
    atomicMax(mxp + 0, __float_as_int(bmax.x));
    atomicMax(mxp + 1, __float_as_int(bmax.y));
    if (lane == 0) atomicAdd(&cnt[cur_g], (float)cntloc);
}

__global__ __launch_bounds__(TPB) void k_pool_final(const float* __restrict__ mean_acc,
                                                    const float* __restrict__ max_acc,
                                                    const float* __restrict__ cnt,
                                                    float* __restrict__ gout, int g128) {
    int i = blockIdx.x * TPB + threadIdx.x;
    if (i >= g128) return;
    int g = i >> 7, d = i & 127;
    float c = fmaxf(cnt[g], 1.f);
    gout[g * 256 + d] = mean_acc[i] / c;
    gout[g * 256 + 128 + d] = max_acc[i];
}

// ---------------------------------------------------------------------------
extern "C" void kernel_launch(void* const* d_in, const int* in_sizes, int n_in,
                              void* d_out, int out_size, void* d_ws, size_t ws_size,
                              hipStream_t stream) {
    const float* x       = (const float*)d_in[0];
    const int*   ei      = (const int*)d_in[1];
    const int*   batch   = (const int*)d_in[2];
    const float* W1      = (const float*)d_in[3];
    const float* b1      = (const float*)d_in[4];
    const float* g1      = (const float*)d_in[5];
    const float* beta1   = (const float*)d_in[6];
    const float* W2      = (const float*)d_in[7];
    const float* b2      = (const float*)d_in[8];
    const float* g2      = (const float*)d_in[9];
    const float* beta2   = (const float*)d_in[10];
    const float* gat_W   = (const float*)d_in[11];
    const float* att_src = (const float*)d_in[12];
    const float* att_dst = (const float*)d_in[13];
    const float* gat_b   = (const float*)d_in[14];

    const int N = in_sizes[0] / 128;
    const int E = in_sizes[1] / 2;
    const int G = (out_size - N * 128) / 256;
    const int* src = ei;
    const int* dst = ei + E;

    float* ws = (float*)d_ws;
    float* dis      = ws; ws += N;
    float* a_s      = ws; ws += N * 4;
    float* a_d      = ws; ws += N * 4;
    // zero-init block: mean_acc, max_acc, cnt, deg contiguous -> one memset
    float* mean_acc = ws; ws += G * 128;
    float* max_acc  = ws; ws += G * 128;
    float* cnt      = ws; ws += G;
    int* deg        = (int*)ws; ws += N;
    float* csr_w    = ws; ws += E;
    unsigned short* Hbf = (unsigned short*)ws; ws += (size_t)N * 64;
    unsigned short* Bbf = (unsigned short*)ws; ws += (size_t)N * 64;
    unsigned short* Cbf = (unsigned short*)ws; ws += (size_t)N * 64;
    unsigned short* hgb = (unsigned short*)ws; ws += (size_t)N * 256;
    unsigned short* Wt1 = (unsigned short*)ws; ws += 128 * 64;
    unsigned short* Wt2 = (unsigned short*)ws; ws += 128 * 64;
    unsigned short* Wtg = (unsigned short*)ws; ws += 512 * 64;
    int* part      = (int*)ws; ws += 256;
    int* row_start = (int*)ws; ws += N + 1;
    int* cursor    = (int*)ws; ws += N + 1;
    int* csr_src   = (int*)ws; ws += E;

    float* gout = (float*)d_out;        // [G, 256]
    float* node_out = gout + G * 256;   // [N, 128]

    auto cdiv = [](long a, long b) { return (int)((a + b - 1) / b); };
    const int nb = cdiv(N, TPB);

    // one memset zeroes mean_acc/max_acc/cnt/deg
    hipMemsetAsync(mean_acc, 0, (size_t)(G * 256 + G + N) * 4, stream);
    k_hist<<<cdiv(E, TPB), TPB, 0, stream>>>(dst, deg, E);
    k_scan_part_wt<<<nb + cdiv(98304, TPB), TPB, 0, stream>>>(deg, part, N, nb,
                                                              W1, W2, gat_W, Wt1, Wt2, Wtg);
    k_scan_apply<<<nb, TPB, 0, stream>>>(deg, part, row_start, cursor, dis, N, E);

    // gemm1 (fp32 x) merged with CSR scatter (independent work)
    const int gb = cdiv(N, 128);
    k_gemm1_scatter<<<gb + cdiv(E, TPB), TPB, 0, stream>>>(x, Wt1, Hbf, N, gb,
                                                           src, dst, dis, cursor,
                                                           csr_src, csr_w, E);
    k_gcn_fused<<<cdiv((long)N * 64, TPB), TPB, 0, stream>>>(Hbf, csr_src, csr_w, row_start, dis,
                                                             b1, g1, beta1, Bbf, N);
    // GCN layer 2
    k_gemm_mfma<<<dim3(cdiv(N, 128), 1), TPB, 0, stream>>>(Bbf, Wt2, Hbf, N, 128,
                                                           nullptr, nullptr, nullptr, nullptr);
    k_gcn_fused<<<cdiv((long)N * 64, TPB), TPB, 0, stream>>>(Hbf, csr_src, csr_w, row_start, dis,
                                                             b2, g2, beta2, Cbf, N);
    // GAT gemm (+fused attention dots per head slice)
    k_gemm_mfma<<<dim3(cdiv(N, 128), 4), TPB, 0, stream>>>(Cbf, Wtg, hgb, N, 512,
                                                           att_src, att_dst, a_s, a_d);
    k_gat_fused<<<cdiv((long)N * 64, TPB), TPB, 0, stream>>>(hgb, a_s, a_d, csr_src, row_start,
                                                             gat_b, node_out, N);

    // pooling
    k_pool<<<cdiv((long)cdiv(N, 16) * 64, TPB), TPB, 0, stream>>>(node_out, batch,
                                                                  mean_acc, max_acc, cnt, N);
    k_pool_final<<<cdiv((long)G * 128, TPB), TPB, 0, stream>>>(mean_acc, max_acc, cnt, gout, G * 128);
}

// Round 11
// 376.145 us; speedup vs baseline: 1.2105x; 1.0826x over previous
//
#include <hip/hip_runtime.h>
#include <math.h>

// ---------------------------------------------------------------------------
// HOGGraphNet: 2x GCNConv(+LN+ReLU) -> GATConv(4 heads, mean) -> mean/max pool
// N=50000, E=600000, D=128, H=4, G=64. CSR gather-side aggregation.
// bf16 features for GCN; GAT features int8 with exact per-(node,head) scales
// (computed from fp32 MFMA accumulators in the gemm3 epilogue). Scale folded
// into the edge weight -> zero extra loads in the gather.
// ---------------------------------------------------------------------------

#define TPB 256

typedef __attribute__((ext_vector_type(8))) short short8;
typedef __attribute__((ext_vector_type(4))) float f32x4;
union U4S8 { uint4 u; short8 s; };

__device__ __forceinline__ float lrelu(float x) { return x > 0.f ? x : 0.2f * x; }

__device__ __forceinline__ unsigned short f2bf(float f) {  // RTNE
    unsigned int u = __float_as_uint(f);
    u += 0x7fffu + ((u >> 16) & 1u);
    return (unsigned short)(u >> 16);
}
__device__ __forceinline__ float2 bf2x(unsigned int u) {   // [lo,hi] bf16 pair
    return make_float2(__uint_as_float(u << 16), __uint_as_float(u & 0xffff0000u));
}
__device__ __forceinline__ float sel4(float4 v, int h) {
    float r = v.x;
    r = (h == 1) ? v.y : r;
    r = (h == 2) ? v.z : r;
    r = (h == 3) ? v.w : r;
    return r;
}
__device__ __forceinline__ float dot4(f32x4 a, float4 b) {
    return a.x * b.x + a.y * b.y + a.z * b.z + a.w * b.w;
}
__device__ __forceinline__ void unp8(uint2 u, float* f) {  // 8 signed int8 -> f32
    f[0] = (float)(int)(char)(u.x & 0xff);
    f[1] = (float)(int)(char)((u.x >> 8) & 0xff);
    f[2] = (float)(int)(char)((u.x >> 16) & 0xff);
    f[3] = (float)(int)(char)(u.x >> 24);
    f[4] = (float)(int)(char)(u.y & 0xff);
    f[5] = (float)(int)(char)((u.y >> 8) & 0xff);
    f[6] = (float)(int)(char)((u.y >> 16) & 0xff);
    f[7] = (float)(int)(char)(u.y >> 24);
}

// ---------------- CSR build ----------------
__global__ __launch_bounds__(TPB) void k_hist(const int* __restrict__ dst,
                                              int* __restrict__ deg, int e) {
    int i = blockIdx.x * TPB + threadIdx.x;
    if (i < e) atomicAdd(&deg[dst[i]], 1);
}

// merged: blocks [0,nb) do per-block deg sums; blocks [nb,..) do W transposes
__global__ __launch_bounds__(TPB) void k_scan_part_wt(const int* __restrict__ deg,
                                                      int* __restrict__ part, int n, int nb,
                                                      const float* __restrict__ W1,
                                                      const float* __restrict__ W2,
                                                      const float* __restrict__ Wg,
                                                      unsigned short* __restrict__ Wt1,
                                                      unsigned short* __restrict__ Wt2,
                                                      unsigned short* __restrict__ Wtg) {
    int bid = blockIdx.x;
    if (bid < nb) {
        int i = bid * TPB + threadIdx.x;
        int v = (i < n) ? deg[i] : 0;
#pragma unroll
        for (int o = 32; o > 0; o >>= 1) v += __shfl_xor(v, o);
        __shared__ int sw[4];
        if ((threadIdx.x & 63) == 0) sw[threadIdx.x >> 6] = v;
        __syncthreads();
        if (threadIdx.x == 0) part[bid] = sw[0] + sw[1] + sw[2] + sw[3];
    } else {
        int i = (bid - nb) * TPB + threadIdx.x;  // 0..98303
        if (i < 16384) {
            int k = i >> 7, c = i & 127;
            Wt1[c * 128 + k] = f2bf(W1[i]);
        } else if (i < 32768) {
            int j = i - 16384;
            int k = j >> 7, c = j & 127;
            Wt2[c * 128 + k] = f2bf(W2[j]);
        } else if (i < 98304) {
            int j = i - 32768;
            int k = j >> 9, c = j & 511;
            Wtg[c * 128 + k] = f2bf(Wg[j]);
        }
    }
}

// in-block exclusive scan; block base = reduce of preceding partials (nb<=256)
__global__ __launch_bounds__(TPB) void k_scan_apply(const int* __restrict__ deg,
                                                    const int* __restrict__ part,
                                                    int* __restrict__ row_start,
                                                    int* __restrict__ cursor,
                                                    float* __restrict__ dis,
                                                    int n, int e_total) {
    __shared__ int sm[TPB];
    __shared__ int sred[4];
    int t = threadIdx.x;
    int bid = blockIdx.x;
    int pv = (t < bid) ? part[t] : 0;
#pragma unroll
    for (int o = 32; o > 0; o >>= 1) pv += __shfl_xor(pv, o);
    if ((t & 63) == 0) sred[t >> 6] = pv;
    __syncthreads();
    int basep = sred[0] + sred[1] + sred[2] + sred[3];
    int i = bid * TPB + t;
    int d = (i < n) ? deg[i] : 0;
    sm[t] = d;
    __syncthreads();
    for (int off = 1; off < TPB; off <<= 1) {
        int u = (t >= off) ? sm[t - off] : 0;
        __syncthreads();
        sm[t] += u;
        __syncthreads();
    }
    if (i < n) {
        int rs = basep + sm[t] - d;
        row_start[i] = rs;
        cursor[i] = rs;
        dis[i] = rsqrtf((float)(d + 1));
    }
    if (bid == 0 && t == 0) row_start[n] = e_total;
}

// ---------------- merged: gemm1 (fp32 x -> Hbf) || CSR scatter --------------
__global__ __launch_bounds__(TPB, 2) void k_gemm1_scatter(const float* __restrict__ feat,
                                                          const unsigned short* __restrict__ Wt,
                                                          unsigned short* __restrict__ C,
                                                          int nrows, int gb,
                                                          const int* __restrict__ src,
                                                          const int* __restrict__ dst,
                                                          const float* __restrict__ dis,
                                                          int* __restrict__ cursor,
                                                          int* __restrict__ csr_src,
                                                          float* __restrict__ csr_w, int e) {
    __shared__ uint4 wl[2048];
    int t = threadIdx.x;
    if (blockIdx.x >= gb) {
        int i = (blockIdx.x - gb) * TPB + t;
        if (i < e) {
            int s = src[i];
            int p = atomicAdd(&cursor[dst[i]], 1);
            csr_src[p] = s;
            csr_w[p] = dis[s];
        }
        return;
    }
#pragma unroll
    for (int i = 0; i < 8; ++i) {
        int fi = i * 256 + t;
        int l = fi & 63, ct = (fi >> 6) & 7, ks = fi >> 9;
        int chan = ct * 16 + (l & 15);
        wl[fi] = ((const uint4*)(Wt + (size_t)chan * 128))[ks * 4 + (l >> 4)];
    }
    __syncthreads();

    int wave = t >> 6, lane = t & 63;
    int wr = wave >> 1, wc = wave & 1;
    int nbase = (blockIdx.x << 7) + (wc << 6);
    const float4* brow[4];
#pragma unroll
    for (int nt = 0; nt < 4; ++nt) {
        int node = nbase + nt * 16 + (lane & 15);
        node = node < nrows ? node : (nrows - 1);
        brow[nt] = (const float4*)(feat + (size_t)node * 128);
    }
    f32x4 acc[4][4];
#pragma unroll
    for (int mt = 0; mt < 4; ++mt)
#pragma unroll
        for (int nt = 0; nt < 4; ++nt) acc[mt][nt] = (f32x4)0.f;

    int kq = lane >> 4;
#pragma unroll
    for (int ks = 0; ks < 4; ++ks) {
        U4S8 a[4], b[4];
#pragma unroll
        for (int mt = 0; mt < 4; ++mt)
            a[mt].u = wl[(ks * 8 + wr * 4 + mt) * 64 + lane];
#pragma unroll
        for (int nt = 0; nt < 4; ++nt) {
            float4 f0 = brow[nt][ks * 8 + kq * 2];
            float4 f1 = brow[nt][ks * 8 + kq * 2 + 1];
            b[nt].u.x = (unsigned int)f2bf(f0.x) | ((unsigned int)f2bf(f0.y) << 16);
            b[nt].u.y = (unsigned int)f2bf(f0.z) | ((unsigned int)f2bf(f0.w) << 16);
            b[nt].u.z = (unsigned int)f2bf(f1.x) | ((unsigned int)f2bf(f1.y) << 16);
            b[nt].u.w = (unsigned int)f2bf(f1.z) | ((unsigned int)f2bf(f1.w) << 16);
        }
#pragma unroll
        for (int mt = 0; mt < 4; ++mt)
#pragma unroll
            for (int nt = 0; nt < 4; ++nt)
                acc[mt][nt] = __builtin_amdgcn_mfma_f32_16x16x32_bf16(
                    a[mt].s, b[nt].s, acc[mt][nt], 0, 0, 0);
    }
#pragma unroll
    for (int nt = 0; nt < 4; ++nt) {
        int node = nbase + nt * 16 + (lane & 15);
        if (node >= nrows) continue;
#pragma unroll
        for (int mt = 0; mt < 4; ++mt) {
            int chan = (wr << 6) + mt * 16 + (lane >> 4) * 4;
            f32x4 v = acc[mt][nt];
            unsigned int p0 = (unsigned int)f2bf(v.x) | ((unsigned int)f2bf(v.y) << 16);
            unsigned int p1 = (unsigned int)f2bf(v.z) | ((unsigned int)f2bf(v.w) << 16);
            *(uint2*)(C + (size_t)node * 128 + chan) = make_uint2(p0, p1);
        }
    }
}

// ---------------- MFMA GEMM core (bf16 features in) -------------------------
// att_s==null: bf16 C store. att_s!=null (GAT gemm, blockIdx.y==head):
// epilogue computes per-node head dots, per-(node,head) absmax, writes
// asn_sc = {a_s[4], scale[4]} per node, a_d, and int8-quantized hgq.
__global__ __launch_bounds__(TPB, 2) void k_gemm_mfma(const unsigned short* __restrict__ feat,
                                                      const unsigned short* __restrict__ Wt,
                                                      unsigned short* __restrict__ C,
                                                      int nrows, int ocols,
                                                      const float* __restrict__ att_s,
                                                      const float* __restrict__ att_d,
                                                      float* __restrict__ asn_sc,
                                                      float* __restrict__ a_d,
                                                      unsigned char* __restrict__ hgq) {
    __shared__ uint4 wl[2048];  // 32KB fragment-linear Wt tile
    __shared__ float sas[128], sad[128], smax[128];
    int t = threadIdx.x;
    int cb = blockIdx.y << 7;
#pragma unroll
    for (int i = 0; i < 8; ++i) {
        int fi = i * 256 + t;
        int l = fi & 63, ct = (fi >> 6) & 7, ks = fi >> 9;
        int chan = cb + ct * 16 + (l & 15);
        wl[fi] = ((const uint4*)(Wt + (size_t)chan * 128))[ks * 4 + (l >> 4)];
    }
    __syncthreads();

    int wave = t >> 6, lane = t & 63;
    int wr = wave >> 1, wc = wave & 1;
    int nbase = (blockIdx.x << 7) + (wc << 6);
    const uint4* brow[4];
#pragma unroll
    for (int nt = 0; nt < 4; ++nt) {
        int node = nbase + nt * 16 + (lane & 15);
        node = node < nrows ? node : (nrows - 1);
        brow[nt] = (const uint4*)(feat + (size_t)node * 128);
    }
    f32x4 acc[4][4];
#pragma unroll
    for (int mt = 0; mt < 4; ++mt)
#pragma unroll
        for (int nt = 0; nt < 4; ++nt) acc[mt][nt] = (f32x4)0.f;

    int kq = lane >> 4;
#pragma unroll
    for (int ks = 0; ks < 4; ++ks) {
        U4S8 a[4], b[4];
#pragma unroll
        for (int mt = 0; mt < 4; ++mt)
            a[mt].u = wl[(ks * 8 + wr * 4 + mt) * 64 + lane];
#pragma unroll
        for (int nt = 0; nt < 4; ++nt)
            b[nt].u = brow[nt][ks * 4 + kq];
#pragma unroll
        for (int mt = 0; mt < 4; ++mt)
#pragma unroll
            for (int nt = 0; nt < 4; ++nt)
                acc[mt][nt] = __builtin_amdgcn_mfma_f32_16x16x32_bf16(
                    a[mt].s, b[nt].s, acc[mt][nt], 0, 0, 0);
    }
    // C/D layout: col(node)=lane&15, row(chan)=(lane>>4)*4+reg
    if (att_s == nullptr) {
#pragma unroll
        for (int nt = 0; nt < 4; ++nt) {
            int node = nbase + nt * 16 + (lane & 15);
            if (node >= nrows) continue;
#pragma unroll
            for (int mt = 0; mt < 4; ++mt) {
                int chan = cb + (wr << 6) + mt * 16 + (lane >> 4) * 4;
                f32x4 v = acc[mt][nt];
                unsigned int p0 = (unsigned int)f2bf(v.x) | ((unsigned int)f2bf(v.y) << 16);
                unsigned int p1 = (unsigned int)f2bf(v.z) | ((unsigned int)f2bf(v.w) << 16);
                *(uint2*)(C + (size_t)node * ocols + chan) = make_uint2(p0, p1);
            }
        }
        return;
    }
    // ---- GAT path: head h = blockIdx.y ----
    if (t < 128) { sas[t] = 0.f; sad[t] = 0.f; smax[t] = 0.f; }
    __syncthreads();
    int h = blockIdx.y;
    float4 asv[4], adv[4];
#pragma unroll
    for (int mt = 0; mt < 4; ++mt) {
        int cbase = h * 128 + (wr << 6) + mt * 16 + (lane >> 4) * 4;
        asv[mt] = *(const float4*)(att_s + cbase);
        adv[mt] = *(const float4*)(att_d + cbase);
    }
#pragma unroll
    for (int nt = 0; nt < 4; ++nt) {
        float ds = 0.f, dd = 0.f, mx = 0.f;
#pragma unroll
        for (int mt = 0; mt < 4; ++mt) {
            f32x4 v = acc[mt][nt];
            ds += dot4(v, asv[mt]);
            dd += dot4(v, adv[mt]);
            mx = fmaxf(mx, fmaxf(fmaxf(fabsf(v.x), fabsf(v.y)),
                                 fmaxf(fabsf(v.z), fabsf(v.w))));
        }
        ds += __shfl_xor(ds, 16); ds += __shfl_xor(ds, 32);
        dd += __shfl_xor(dd, 16); dd += __shfl_xor(dd, 32);
        mx = fmaxf(mx, __shfl_xor(mx, 16));
        mx = fmaxf(mx, __shfl_xor(mx, 32));
        if (lane < 16) {
            int sl = (wc << 6) + nt * 16 + lane;
            atomicAdd(&sas[sl], ds);
            atomicAdd(&sad[sl], dd);
            atomicMax((int*)&smax[sl], __float_as_int(mx));  // mx >= 0
        }
    }
    __syncthreads();
    if (t < 128) {
        int node = (blockIdx.x << 7) + t;
        if (node < nrows) {
            asn_sc[(size_t)node * 8 + h] = sas[t];
            asn_sc[(size_t)node * 8 + 4 + h] = smax[t] * (1.f / 127.f);
        }
    } else {
        int t2 = t - 128;
        int node = (blockIdx.x << 7) + t2;
        if (node < nrows) a_d[(size_t)node * 4 + h] = sad[t2];
    }
    // quantize fp32 acc -> int8 (exact per-(node,head) scale)
#pragma unroll
    for (int nt = 0; nt < 4; ++nt) {
        int node = nbase + nt * 16 + (lane & 15);
        if (node >= nrows) continue;
        float mxv = smax[(wc << 6) + nt * 16 + (lane & 15)];
        float rs = mxv > 0.f ? 127.f / mxv : 0.f;
#pragma unroll
        for (int mt = 0; mt < 4; ++mt) {
            int chan = (wr << 6) + mt * 16 + (lane >> 4) * 4;
            f32x4 v = acc[mt][nt];
            int q0 = (int)rintf(v.x * rs), q1 = (int)rintf(v.y * rs);
            int q2 = (int)rintf(v.z * rs), q3 = (int)rintf(v.w * rs);
            unsigned int pk = (q0 & 0xff) | ((q1 & 0xff) << 8) |
                              ((q2 & 0xff) << 16) | ((unsigned int)(q3 & 0xff) << 24);
            *(unsigned int*)(hgq + (size_t)node * 512 + h * 128 + chan) = pk;
        }
    }
}

// ---------------- fused GCN: coalesced idx+weight, 4 rows in flight ---------
__global__ __launch_bounds__(TPB) void k_gcn_fused(const unsigned short* __restrict__ hb,
                                                   const int* __restrict__ csr_src,
                                                   const float* __restrict__ csr_w,
                                                   const int* __restrict__ row_start,
                                                   const float* __restrict__ dis,
                                                   const float* __restrict__ b,
                                                   const float* __restrict__ g,
                                                   const float* __restrict__ beta,
                                                   unsigned short* __restrict__ out, int n) {
    int node = (blockIdx.x * TPB + threadIdx.x) >> 6;
    int lane = threadIdx.x & 63;
    if (node >= n) return;
    int s0 = row_start[node], s1 = row_start[node + 1];
    float dn = dis[node];
    const uint4* hq = (const uint4*)hb;   // row = 16 uint4 (128 bf16)
    int q = lane >> 4, fl = lane & 15;
    float acc[8];
#pragma unroll
    for (int i = 0; i < 8; ++i) acc[i] = 0.f;
    for (int base = s0; base < s1; base += 64) {
        int cnt = min(64, s1 - base);
        int sidx = 0; float w = 0.f;
        if (lane < cnt) {
            sidx = csr_src[base + lane];
            w = csr_w[base + lane];
        }
        for (int j = 0; j < cnt; j += 16) {
            int j0 = j + q, j1 = j + 4 + q, j2 = j + 8 + q, j3 = j + 12 + q;
            int   sA = __shfl(sidx, j0), sB = __shfl(sidx, j1);
            int   sC = __shfl(sidx, j2), sD = __shfl(sidx, j3);
            float wA = __shfl(w, j0), wB = __shfl(w, j1);
            float wC = __shfl(w, j2), wD = __shfl(w, j3);
            uint4 uA = hq[(size_t)sA * 16 + fl];
            uint4 uB = hq[(size_t)sB * 16 + fl];
            uint4 uC = hq[(size_t)sC * 16 + fl];
            uint4 uD = hq[(size_t)sD * 16 + fl];
            float2 p0 = bf2x(uA.x), p1 = bf2x(uA.y), p2 = bf2x(uA.z), p3 = bf2x(uA.w);
            acc[0] += wA * p0.x; acc[1] += wA * p0.y;
            acc[2] += wA * p1.x; acc[3] += wA * p1.y;
            acc[4] += wA * p2.x; acc[5] += wA * p2.y;
            acc[6] += wA * p3.x; acc[7] += wA * p3.y;
            p0 = bf2x(uB.x); p1 = bf2x(uB.y); p2 = bf2x(uB.z); p3 = bf2x(uB.w);
            acc[0] += wB * p0.x; acc[1] += wB * p0.y;
            acc[2] += wB * p1.x; acc[3] += wB * p1.y;
            acc[4] += wB * p2.x; acc[5] += wB * p2.y;
            acc[6] += wB * p3.x; acc[7] += wB * p3.y;
            p0 = bf2x(uC.x); p1 = bf2x(uC.y); p2 = bf2x(uC.z); p3 = bf2x(uC.w);
            acc[0] += wC * p0.x; acc[1] += wC * p0.y;
            acc[2] += wC * p1.x; acc[3] += wC * p1.y;
            acc[4] += wC * p2.x; acc[5] += wC * p2.y;
            acc[6] += wC * p3.x; acc[7] += wC * p3.y;
            p0 = bf2x(uD.x); p1 = bf2x(uD.y); p2 = bf2x(uD.z); p3 = bf2x(uD.w);
            acc[0] += wD * p0.x; acc[1] += wD * p0.y;
            acc[2] += wD * p1.x; acc[3] += wD * p1.y;
            acc[4] += wD * p2.x; acc[5] += wD * p2.y;
            acc[6] += wD * p3.x; acc[7] += wD * p3.y;
        }
    }
#pragma unroll
    for (int i = 0; i < 8; ++i) {
        acc[i] += __shfl_xor(acc[i], 16);
        acc[i] += __shfl_xor(acc[i], 32);
    }
    float sl = dn * dn;
    uint4 us = hq[(size_t)node * 16 + fl];
    float2 h0 = bf2x(us.x), h1 = bf2x(us.y), h2 = bf2x(us.z), h3 = bf2x(us.w);
    float4 b0 = ((const float4*)b)[fl * 2], b1 = ((const float4*)b)[fl * 2 + 1];
    float v[8];
    v[0] = dn * acc[0] + sl * h0.x + b0.x;
    v[1] = dn * acc[1] + sl * h0.y + b0.y;
    v[2] = dn * acc[2] + sl * h1.x + b0.z;
    v[3] = dn * acc[3] + sl * h1.y + b0.w;
    v[4] = dn * acc[4] + sl * h2.x + b1.x;
    v[5] = dn * acc[5] + sl * h2.y + b1.y;
    v[6] = dn * acc[6] + sl * h3.x + b1.z;
    v[7] = dn * acc[7] + sl * h3.y + b1.w;
    float s = 0.f, sq = 0.f;
#pragma unroll
    for (int i = 0; i < 8; ++i) { s += v[i]; sq += v[i] * v[i]; }
#pragma unroll
    for (int o = 8; o > 0; o >>= 1) {
        s  += __shfl_xor(s, o);
        sq += __shfl_xor(sq, o);
    }
    float mu = s * (1.f / 128.f);
    float var = sq * (1.f / 128.f) - mu * mu;
    float rstd = rsqrtf(var + 1e-5f);
    float4 g0  = ((const float4*)g)[fl * 2],    g1v = ((const float4*)g)[fl * 2 + 1];
    float4 bt0 = ((const float4*)beta)[fl * 2], bt1 = ((const float4*)beta)[fl * 2 + 1];
    float o0 = fmaxf((v[0] - mu) * rstd * g0.x + bt0.x, 0.f);
    float o1 = fmaxf((v[1] - mu) * rstd * g0.y + bt0.y, 0.f);
    float o2 = fmaxf((v[2] - mu) * rstd * g0.z + bt0.z, 0.f);
    float o3 = fmaxf((v[3] - mu) * rstd * g0.w + bt0.w, 0.f);
    float o4 = fmaxf((v[4] - mu) * rstd * g1v.x + bt1.x, 0.f);
    float o5 = fmaxf((v[5] - mu) * rstd * g1v.y + bt1.y, 0.f);
    float o6 = fmaxf((v[6] - mu) * rstd * g1v.z + bt1.z, 0.f);
    float o7 = fmaxf((v[7] - mu) * rstd * g1v.w + bt1.w, 0.f);
    if (q == 0) {
        uint4 pk;
        pk.x = (unsigned int)f2bf(o0) | ((unsigned int)f2bf(o1) << 16);
        pk.y = (unsigned int)f2bf(o2) | ((unsigned int)f2bf(o3) << 16);
        pk.z = (unsigned int)f2bf(o4) | ((unsigned int)f2bf(o5) << 16);
        pk.w = (unsigned int)f2bf(o6) | ((unsigned int)f2bf(o7) << 16);
        ((uint4*)out)[(size_t)node * 16 + fl] = pk;
    }
}

// ---------------- fused GAT: int8 gather, scale folded into edge weight -----
__global__ __launch_bounds__(TPB) void k_gat_fused(const unsigned char* __restrict__ hgq,
                                                   const float* __restrict__ asn_sc,
                                                   const float* __restrict__ a_d,
                                                   const int* __restrict__ csr_src,
                                                   const int* __restrict__ row_start,
                                                   const float* __restrict__ gat_b,
                                                   float* __restrict__ node_out, int n) {
    __shared__ int   ssrc[4][64];
    __shared__ float swt[4][4][65];
    int node = (blockIdx.x * TPB + threadIdx.x) >> 6;
    int lane = threadIdx.x & 63;
    int wid = threadIdx.x >> 6;
    if (node >= n) return;
    int s0 = row_start[node], s1 = row_start[node + 1];
    int h = lane >> 4, fl = lane & 15;
    const float4* asc4 = (const float4*)asn_sc;   // [node*2]=a_s, [node*2+1]=scale
    float4 ad = ((const float4*)a_d)[node];
    float4 asn = asc4[node * 2];
    float4 scn = asc4[node * 2 + 1];
    float4 eself;
    eself.x = __expf(lrelu(asn.x + ad.x));
    eself.y = __expf(lrelu(asn.y + ad.y));
    eself.z = __expf(lrelu(asn.z + ad.z));
    eself.w = __expf(lrelu(asn.w + ad.w));
    const uint2* hq2 = (const uint2*)hgq;         // row = 64 uint2 (512 int8)
    int hoff = (h << 4) + fl;
    float acc[8];
    {
        float wsh = sel4(eself, h) * sel4(scn, h);
        float f[8];
        unp8(hq2[(size_t)node * 64 + hoff], f);
#pragma unroll
        for (int i = 0; i < 8; ++i) acc[i] = wsh * f[i];
    }
    float4 den = make_float4(0.f, 0.f, 0.f, 0.f);
    for (int base = s0; base < s1; base += 64) {
        int cnt = min(64, s1 - base);
        int sidx = 0;
        float4 w4 = make_float4(0.f, 0.f, 0.f, 0.f);
        if (lane < cnt) {
            sidx = csr_src[base + lane];
            float4 a = asc4[sidx * 2];
            float4 sc = asc4[sidx * 2 + 1];
            float4 e4;
            e4.x = __expf(lrelu(a.x + ad.x));
            e4.y = __expf(lrelu(a.y + ad.y));
            e4.z = __expf(lrelu(a.z + ad.z));
            e4.w = __expf(lrelu(a.w + ad.w));
            den.x += e4.x; den.y += e4.y; den.z += e4.z; den.w += e4.w;
            w4 = make_float4(e4.x * sc.x, e4.y * sc.y, e4.z * sc.z, e4.w * sc.w);
        }
        ssrc[wid][lane] = sidx;
        swt[wid][0][lane] = w4.x;
        swt[wid][1][lane] = w4.y;
        swt[wid][2][lane] = w4.z;
        swt[wid][3][lane] = w4.w;
        int j = 0;
        for (; j + 4 <= cnt; j += 4) {   // 4 independent 512B row loads in flight
            int sa = ssrc[wid][j + 0], sb = ssrc[wid][j + 1];
            int sc = ssrc[wid][j + 2], sd = ssrc[wid][j + 3];
            float wa = swt[wid][h][j + 0], wb = swt[wid][h][j + 1];
            float wc = swt[wid][h][j + 2], wd = swt[wid][h][j + 3];
            uint2 ua = hq2[(size_t)sa * 64 + hoff];
            uint2 ub = hq2[(size_t)sb * 64 + hoff];
            uint2 uc = hq2[(size_t)sc * 64 + hoff];
            uint2 ud = hq2[(size_t)sd * 64 + hoff];
            float f[8];
            unp8(ua, f);
#pragma unroll
            for (int i = 0; i < 8; ++i) acc[i] += wa * f[i];
            unp8(ub, f);
#pragma unroll
            for (int i = 0; i < 8; ++i) acc[i] += wb * f[i];
            unp8(uc, f);
#pragma unroll
            for (int i = 0; i < 8; ++i) acc[i] += wc * f[i];
            unp8(ud, f);
#pragma unroll
            for (int i = 0; i < 8; ++i) acc[i] += wd * f[i];
        }
        for (; j < cnt; ++j) {
            int s = ssrc[wid][j];
            float wj = swt[wid][h][j];
            float f[8];
            unp8(hq2[(size_t)s * 64 + hoff], f);
#pragma unroll
            for (int i = 0; i < 8; ++i) acc[i] += wj * f[i];
        }
    }
#pragma unroll
    for (int o = 32; o > 0; o >>= 1) {
        den.x += __shfl_xor(den.x, o);
        den.y += __shfl_xor(den.y, o);
        den.z += __shfl_xor(den.z, o);
        den.w += __shfl_xor(den.w, o);
    }
    den.x += eself.x; den.y += eself.y; den.z += eself.z; den.w += eself.w;
    float winv = 0.25f / sel4(den, h);
#pragma unroll
    for (int j = 0; j < 8; ++j) acc[j] *= winv;
#pragma unroll
    for (int j = 0; j < 8; ++j) acc[j] += __shfl_xor(acc[j], 16);
#pragma unroll
    for (int j = 0; j < 8; ++j) acc[j] += __shfl_xor(acc[j], 32);
    float4 gb0 = ((const float4*)gat_b)[fl * 2], gb1 = ((const float4*)gat_b)[fl * 2 + 1];
    if (lane < 16) {
        float4* o4 = (float4*)(node_out + (size_t)node * 128 + fl * 8);
        o4[0] = make_float4(fmaxf(acc[0] + gb0.x, 0.f), fmaxf(acc[1] + gb0.y, 0.f),
                            fmaxf(acc[2] + gb0.z, 0.f), fmaxf(acc[3] + gb0.w, 0.f));
        o4[1] = make_float4(fmaxf(acc[4] + gb1.x, 0.f), fmaxf(acc[5] + gb1.y, 0.f),
                            fmaxf(acc[6] + gb1.z, 0.f), fmaxf(acc[7] + gb1.w, 0.f));
    }
}

// ---------------- pooling: run-batched atomics over sorted batch ------------
__global__ __launch_bounds__(TPB) void k_pool(const float* __restrict__ node_out,
                                              const int* __restrict__ batch,
                                              float* __restrict__ mean_acc,
                                              float* __restrict__ max_acc,
                                              float* __restrict__ cnt, int n) {
    int wave = (blockIdx.x * TPB + threadIdx.x) >> 6;
    int lane = threadIdx.x & 63;
    int n0 = wave * 16;
    if (n0 >= n) return;
    int n1 = min(n0 + 16, n);
    float2 bsum = make_float2(0.f, 0.f), bmax = make_float2(0.f, 0.f);
    int cur_g = batch[n0];
    int cntloc = 0;
    for (int nn = n0; nn < n1; ++nn) {
        int g = batch[nn];
        if (g != cur_g) {
            float* ma = mean_acc + cur_g * 128 + lane * 2;
            atomicAdd(ma + 0, bsum.x);
            atomicAdd(ma + 1, bsum.y);
            int* mxp = (int*)(max_acc + cur_g * 128 + lane * 2);
            atomicMax(mxp + 0, __float_as_int(bmax.x));
            atomicMax(mxp + 1, __float_as_int(bmax.y));
            if (lane == 0) atomicAdd(&cnt[cur_g], (float)cntloc);
            bsum = make_float2(0.f, 0.f);
            bmax = make_float2(0.f, 0.f);
            cntloc = 0;
            cur_g = g;
        }
        float2 o = ((const float2*)node_out)[(size_t)nn * 64 + lane];
        bsum.x += o.x; bsum.y += o.y;
        bmax.x = fmaxf(bmax.x, o.x); bmax.y = fmaxf(bmax.y, o.y);
        ++cntloc;
    }
    float* ma = mean_acc + cur_g * 128 + lane * 2;
    atomicAdd(ma + 0, bsum.x);
    atomicAdd(ma + 1, bsum.y);
    int* mxp = (int*)(max_acc + cur_g * 128 + lane * 2);
    atomicMax(mxp + 0, __float_as_int(bmax.x));
    atomicMax(mxp + 1, __float_as_int(bmax.y));
    if (lane == 0) atomicAdd(&cnt[cur_g], (float)cntloc);
}

__global__ __launch_bounds__(TPB) void k_pool_final(const float* __restrict__ mean_acc,
                                                    const float* __restrict__ max_acc,
                                                    const float* __restrict__ cnt,
                                                    float* __restrict__ gout, int g128) {
    int i = blockIdx.x * TPB + threadIdx.x;
    if (i >= g128) return;
    int g = i >> 7, d = i & 127;
    float c = fmaxf(cnt[g], 1.f);
    gout[g * 256 + d] = mean_acc[i] / c;
    gout[g * 256 + 128 + d] = max_acc[i];
}

// ---------------------------------------------------------------------------
extern "C" void kernel_launch(void* const* d_in, const int* in_sizes, int n_in,
                              void* d_out, int out_size, void* d_ws, size_t ws_size,
                              hipStream_t stream) {
    const float* x       = (const float*)d_in[0];
    const int*   ei      = (const int*)d_in[1];
    const int*   batch   = (const int*)d_in[2];
    const float* W1      = (const float*)d_in[3];
    const float* b1      = (const float*)d_in[4];
    const float* g1      = (const float*)d_in[5];
    const float* beta1   = (const float*)d_in[6];
    const float* W2      = (const float*)d_in[7];
    const float* b2      = (const float*)d_in[8];
    const float* g2      = (const float*)d_in[9];
    const float* beta2   = (const float*)d_in[10];
    const float* gat_W   = (const float*)d_in[11];
    const float* att_src = (const float*)d_in[12];
    const float* att_dst = (const float*)d_in[13];
    const float* gat_b   = (const float*)d_in[14];

    const int N = in_sizes[0] / 128;
    const int E = in_sizes[1] / 2;
    const int G = (out_size - N * 128) / 256;
    const int* src = ei;
    const int* dst = ei + E;

    float* ws = (float*)d_ws;
    float* dis      = ws; ws += N;
    float* asn_sc   = ws; ws += (size_t)N * 8;   // {a_s[4], scale[4]} per node
    float* a_d      = ws; ws += N * 4;
    // zero-init block: mean_acc, max_acc, cnt, deg contiguous -> one memset
    float* mean_acc = ws; ws += G * 128;
    float* max_acc  = ws; ws += G * 128;
    float* cnt      = ws; ws += G;
    int* deg        = (int*)ws; ws += N;
    float* csr_w    = ws; ws += E;
    unsigned short* Hbf = (unsigned short*)ws; ws += (size_t)N * 64;
    unsigned short* Bbf = (unsigned short*)ws; ws += (size_t)N * 64;
    unsigned short* Cbf = (unsigned short*)ws; ws += (size_t)N * 64;
    unsigned char* hgq  = (unsigned char*)ws; ws += (size_t)N * 128;  // N*512 bytes
    unsigned short* Wt1 = (unsigned short*)ws; ws += 128 * 64;
    unsigned short* Wt2 = (unsigned short*)ws; ws += 128 * 64;
    unsigned short* Wtg = (unsigned short*)ws; ws += 512 * 64;
    int* part      = (int*)ws; ws += 256;
    int* row_start = (int*)ws; ws += N + 1;
    int* cursor    = (int*)ws; ws += N + 1;
    int* csr_src   = (int*)ws; ws += E;

    float* gout = (float*)d_out;        // [G, 256]
    float* node_out = gout + G * 256;   // [N, 128]

    auto cdiv = [](long a, long b) { return (int)((a + b - 1) / b); };
    const int nb = cdiv(N, TPB);

    // one memset zeroes mean_acc/max_acc/cnt/deg
    hipMemsetAsync(mean_acc, 0, (size_t)(G * 256 + G + N) * 4, stream);
    k_hist<<<cdiv(E, TPB), TPB, 0, stream>>>(dst, deg, E);
    k_scan_part_wt<<<nb + cdiv(98304, TPB), TPB, 0, stream>>>(deg, part, N, nb,
                                                              W1, W2, gat_W, Wt1, Wt2, Wtg);
    k_scan_apply<<<nb, TPB, 0, stream>>>(deg, part, row_start, cursor, dis, N, E);

    // gemm1 (fp32 x) merged with CSR scatter (independent work)
    const int gb = cdiv(N, 128);
    k_gemm1_scatter<<<gb + cdiv(E, TPB), TPB, 0, stream>>>(x, Wt1, Hbf, N, gb,
                                                           src, dst, dis, cursor,
                                                           csr_src, csr_w, E);
    k_gcn_fused<<<cdiv((long)N * 64, TPB), TPB, 0, stream>>>(Hbf, csr_src, csr_w, row_start, dis,
                                                             b1, g1, beta1, Bbf, N);
    // GCN layer 2
    k_gemm_mfma<<<dim3(cdiv(N, 128), 1), TPB, 0, stream>>>(Bbf, Wt2, Hbf, N, 128,
                                                           nullptr, nullptr, nullptr, nullptr, nullptr);
    k_gcn_fused<<<cdiv((long)N * 64, TPB), TPB, 0, stream>>>(Hbf, csr_src, csr_w, row_start, dis,
                                                             b2, g2, beta2, Cbf, N);
    // GAT gemm: dots + int8 quantize in epilogue (no bf16 hg materialized)
    k_gemm_mfma<<<dim3(cdiv(N, 128), 4), TPB, 0, stream>>>(Cbf, Wtg, nullptr, N, 512,
                                                           att_src, att_dst, asn_sc, a_d, hgq);
    k_gat_fused<<<cdiv((long)N * 64, TPB), TPB, 0, stream>>>(hgq, asn_sc, a_d, csr_src, row_start,
                                                             gat_b, node_out, N);

    // pooling
    k_pool<<<cdiv((long)cdiv(N, 16) * 64, TPB), TPB, 0, stream>>>(node_out, batch,
                                                                  mean_acc, max_acc, cnt, N);
    k_pool_final<<<cdiv((long)G * 128, TPB), TPB, 0, stream>>>(mean_acc, max_acc, cnt, gout, G * 128);
}

// Round 12
// 366.163 us; speedup vs baseline: 1.2435x; 1.0273x over previous
//
#include <hip/hip_runtime.h>
#include <math.h>

// ---------------------------------------------------------------------------
// HOGGraphNet: 2x GCNConv(+LN+ReLU) -> GATConv(4 heads, mean) -> mean/max pool
// N=50000, E=600000, D=128, H=4, G=64. CSR gather-side aggregation.
// bf16 features for GCN; GAT features biased-uint8 (q+128) with exact
// per-(node,head) scales; bias corrected via wsum once per node.
// CSR record = {src, weight} int2 (one 8B store/load per edge).
// ---------------------------------------------------------------------------

#define TPB 256

typedef __attribute__((ext_vector_type(8))) short short8;
typedef __attribute__((ext_vector_type(4))) float f32x4;
union U4S8 { uint4 u; short8 s; };

__device__ __forceinline__ float lrelu(float x) { return x > 0.f ? x : 0.2f * x; }

__device__ __forceinline__ unsigned short f2bf(float f) {  // RTNE
    unsigned int u = __float_as_uint(f);
    u += 0x7fffu + ((u >> 16) & 1u);
    return (unsigned short)(u >> 16);
}
__device__ __forceinline__ float2 bf2x(unsigned int u) {   // [lo,hi] bf16 pair
    return make_float2(__uint_as_float(u << 16), __uint_as_float(u & 0xffff0000u));
}
__device__ __forceinline__ float sel4(float4 v, int h) {
    float r = v.x;
    r = (h == 1) ? v.y : r;
    r = (h == 2) ? v.z : r;
    r = (h == 3) ? v.w : r;
    return r;
}
__device__ __forceinline__ float dot4(f32x4 a, float4 b) {
    return a.x * b.x + a.y * b.y + a.z * b.z + a.w * b.w;
}
// 8 biased uint8 -> f32 (v_cvt_f32_ubyteN, 1 op each)
__device__ __forceinline__ void unp8u(uint2 u, float* f) {
    f[0] = (float)(u.x & 0xffu);
    f[1] = (float)((u.x >> 8) & 0xffu);
    f[2] = (float)((u.x >> 16) & 0xffu);
    f[3] = (float)(u.x >> 24);
    f[4] = (float)(u.y & 0xffu);
    f[5] = (float)((u.y >> 8) & 0xffu);
    f[6] = (float)((u.y >> 16) & 0xffu);
    f[7] = (float)(u.y >> 24);
}

// ---------------- CSR build ----------------
__global__ __launch_bounds__(TPB) void k_hist(const int* __restrict__ dst,
                                              int* __restrict__ deg, int e) {
    int i = blockIdx.x * TPB + threadIdx.x;
    if (i < e) atomicAdd(&deg[dst[i]], 1);
}

// merged: blocks [0,nb) do per-block deg sums; blocks [nb,..) do W transposes
__global__ __launch_bounds__(TPB) void k_scan_part_wt(const int* __restrict__ deg,
                                                      int* __restrict__ part, int n, int nb,
                                                      const float* __restrict__ W1,
                                                      const float* __restrict__ W2,
                                                      const float* __restrict__ Wg,
                                                      unsigned short* __restrict__ Wt1,
                                                      unsigned short* __restrict__ Wt2,
                                                      unsigned short* __restrict__ Wtg) {
    int bid = blockIdx.x;
    if (bid < nb) {
        int i = bid * TPB + threadIdx.x;
        int v = (i < n) ? deg[i] : 0;
#pragma unroll
        for (int o = 32; o > 0; o >>= 1) v += __shfl_xor(v, o);
        __shared__ int sw[4];
        if ((threadIdx.x & 63) == 0) sw[threadIdx.x >> 6] = v;
        __syncthreads();
        if (threadIdx.x == 0) part[bid] = sw[0] + sw[1] + sw[2] + sw[3];
    } else {
        int i = (bid - nb) * TPB + threadIdx.x;  // 0..98303
        if (i < 16384) {
            int k = i >> 7, c = i & 127;
            Wt1[c * 128 + k] = f2bf(W1[i]);
        } else if (i < 32768) {
            int j = i - 16384;
            int k = j >> 7, c = j & 127;
            Wt2[c * 128 + k] = f2bf(W2[j]);
        } else if (i < 98304) {
            int j = i - 32768;
            int k = j >> 9, c = j & 511;
            Wtg[c * 128 + k] = f2bf(Wg[j]);
        }
    }
}

// in-block exclusive scan; block base = reduce of preceding partials (nb<=256)
__global__ __launch_bounds__(TPB) void k_scan_apply(const int* __restrict__ deg,
                                                    const int* __restrict__ part,
                                                    int* __restrict__ row_start,
                                                    int* __restrict__ cursor,
                                                    float* __restrict__ dis,
                                                    int n, int e_total) {
    __shared__ int sm[TPB];
    __shared__ int sred[4];
    int t = threadIdx.x;
    int bid = blockIdx.x;
    int pv = (t < bid) ? part[t] : 0;
#pragma unroll
    for (int o = 32; o > 0; o >>= 1) pv += __shfl_xor(pv, o);
    if ((t & 63) == 0) sred[t >> 6] = pv;
    __syncthreads();
    int basep = sred[0] + sred[1] + sred[2] + sred[3];
    int i = bid * TPB + t;
    int d = (i < n) ? deg[i] : 0;
    sm[t] = d;
    __syncthreads();
    for (int off = 1; off < TPB; off <<= 1) {
        int u = (t >= off) ? sm[t - off] : 0;
        __syncthreads();
        sm[t] += u;
        __syncthreads();
    }
    if (i < n) {
        int rs = basep + sm[t] - d;
        row_start[i] = rs;
        cursor[i] = rs;
        dis[i] = rsqrtf((float)(d + 1));
    }
    if (bid == 0 && t == 0) row_start[n] = e_total;
}

// ---------------- merged: gemm1 (fp32 x -> Hbf) || CSR scatter --------------
__global__ __launch_bounds__(TPB, 2) void k_gemm1_scatter(const float* __restrict__ feat,
                                                          const unsigned short* __restrict__ Wt,
                                                          unsigned short* __restrict__ C,
                                                          int nrows, int gb,
                                                          const int* __restrict__ src,
                                                          const int* __restrict__ dst,
                                                          const float* __restrict__ dis,
                                                          int* __restrict__ cursor,
                                                          int2* __restrict__ csr_sw, int e) {
    __shared__ uint4 wl[2048];
    int t = threadIdx.x;
    if (blockIdx.x >= gb) {
        int i = (blockIdx.x - gb) * TPB + t;
        if (i < e) {
            int s = src[i];
            int p = atomicAdd(&cursor[dst[i]], 1);
            csr_sw[p] = make_int2(s, __float_as_int(dis[s]));
        }
        return;
    }
#pragma unroll
    for (int i = 0; i < 8; ++i) {
        int fi = i * 256 + t;
        int l = fi & 63, ct = (fi >> 6) & 7, ks = fi >> 9;
        int chan = ct * 16 + (l & 15);
        wl[fi] = ((const uint4*)(Wt + (size_t)chan * 128))[ks * 4 + (l >> 4)];
    }
    __syncthreads();

    int wave = t >> 6, lane = t & 63;
    int wr = wave >> 1, wc = wave & 1;
    int nbase = (blockIdx.x << 7) + (wc << 6);
    const float4* brow[4];
#pragma unroll
    for (int nt = 0; nt < 4; ++nt) {
        int node = nbase + nt * 16 + (lane & 15);
        node = node < nrows ? node : (nrows - 1);
        brow[nt] = (const float4*)(feat + (size_t)node * 128);
    }
    f32x4 acc[4][4];
#pragma unroll
    for (int mt = 0; mt < 4; ++mt)
#pragma unroll
        for (int nt = 0; nt < 4; ++nt) acc[mt][nt] = (f32x4)0.f;

    int kq = lane >> 4;
#pragma unroll
    for (int ks = 0; ks < 4; ++ks) {
        U4S8 a[4], b[4];
#pragma unroll
        for (int mt = 0; mt < 4; ++mt)
            a[mt].u = wl[(ks * 8 + wr * 4 + mt) * 64 + lane];
#pragma unroll
        for (int nt = 0; nt < 4; ++nt) {
            float4 f0 = brow[nt][ks * 8 + kq * 2];
            float4 f1 = brow[nt][ks * 8 + kq * 2 + 1];
            b[nt].u.x = (unsigned int)f2bf(f0.x) | ((unsigned int)f2bf(f0.y) << 16);
            b[nt].u.y = (unsigned int)f2bf(f0.z) | ((unsigned int)f2bf(f0.w) << 16);
            b[nt].u.z = (unsigned int)f2bf(f1.x) | ((unsigned int)f2bf(f1.y) << 16);
            b[nt].u.w = (unsigned int)f2bf(f1.z) | ((unsigned int)f2bf(f1.w) << 16);
        }
#pragma unroll
        for (int mt = 0; mt < 4; ++mt)
#pragma unroll
            for (int nt = 0; nt < 4; ++nt)
                acc[mt][nt] = __builtin_amdgcn_mfma_f32_16x16x32_bf16(
                    a[mt].s, b[nt].s, acc[mt][nt], 0, 0, 0);
    }
#pragma unroll
    for (int nt = 0; nt < 4; ++nt) {
        int node = nbase + nt * 16 + (lane & 15);
        if (node >= nrows) continue;
#pragma unroll
        for (int mt = 0; mt < 4; ++mt) {
            int chan = (wr << 6) + mt * 16 + (lane >> 4) * 4;
            f32x4 v = acc[mt][nt];
            unsigned int p0 = (unsigned int)f2bf(v.x) | ((unsigned int)f2bf(v.y) << 16);
            unsigned int p1 = (unsigned int)f2bf(v.z) | ((unsigned int)f2bf(v.w) << 16);
            *(uint2*)(C + (size_t)node * 128 + chan) = make_uint2(p0, p1);
        }
    }
}

// ---------------- MFMA GEMM core (bf16 features in) -------------------------
// att_s==null: bf16 C store. att_s!=null (GAT gemm, blockIdx.y==head):
// epilogue computes per-node head dots, per-(node,head) absmax, writes
// asn_sc = {a_s[4], scale[4]} per node, a_d, and biased-uint8 hgq (q+128).
__global__ __launch_bounds__(TPB, 2) void k_gemm_mfma(const unsigned short* __restrict__ feat,
                                                      const unsigned short* __restrict__ Wt,
                                                      unsigned short* __restrict__ C,
                                                      int nrows, int ocols,
                                                      const float* __restrict__ att_s,
                                                      const float* __restrict__ att_d,
                                                      float* __restrict__ asn_sc,
                                                      float* __restrict__ a_d,
                                                      unsigned char* __restrict__ hgq) {
    __shared__ uint4 wl[2048];  // 32KB fragment-linear Wt tile
    __shared__ float sas[128], sad[128], smax[128];
    int t = threadIdx.x;
    int cb = blockIdx.y << 7;
#pragma unroll
    for (int i = 0; i < 8; ++i) {
        int fi = i * 256 + t;
        int l = fi & 63, ct = (fi >> 6) & 7, ks = fi >> 9;
        int chan = cb + ct * 16 + (l & 15);
        wl[fi] = ((const uint4*)(Wt + (size_t)chan * 128))[ks * 4 + (l >> 4)];
    }
    __syncthreads();

    int wave = t >> 6, lane = t & 63;
    int wr = wave >> 1, wc = wave & 1;
    int nbase = (blockIdx.x << 7) + (wc << 6);
    const uint4* brow[4];
#pragma unroll
    for (int nt = 0; nt < 4; ++nt) {
        int node = nbase + nt * 16 + (lane & 15);
        node = node < nrows ? node : (nrows - 1);
        brow[nt] = (const uint4*)(feat + (size_t)node * 128);
    }
    f32x4 acc[4][4];
#pragma unroll
    for (int mt = 0; mt < 4; ++mt)
#pragma unroll
        for (int nt = 0; nt < 4; ++nt) acc[mt][nt] = (f32x4)0.f;

    int kq = lane >> 4;
#pragma unroll
    for (int ks = 0; ks < 4; ++ks) {
        U4S8 a[4], b[4];
#pragma unroll
        for (int mt = 0; mt < 4; ++mt)
            a[mt].u = wl[(ks * 8 + wr * 4 + mt) * 64 + lane];
#pragma unroll
        for (int nt = 0; nt < 4; ++nt)
            b[nt].u = brow[nt][ks * 4 + kq];
#pragma unroll
        for (int mt = 0; mt < 4; ++mt)
#pragma unroll
            for (int nt = 0; nt < 4; ++nt)
                acc[mt][nt] = __builtin_amdgcn_mfma_f32_16x16x32_bf16(
                    a[mt].s, b[nt].s, acc[mt][nt], 0, 0, 0);
    }
    // C/D layout: col(node)=lane&15, row(chan)=(lane>>4)*4+reg
    if (att_s == nullptr) {
#pragma unroll
        for (int nt = 0; nt < 4; ++nt) {
            int node = nbase + nt * 16 + (lane & 15);
            if (node >= nrows) continue;
#pragma unroll
            for (int mt = 0; mt < 4; ++mt) {
                int chan = cb + (wr << 6) + mt * 16 + (lane >> 4) * 4;
                f32x4 v = acc[mt][nt];
                unsigned int p0 = (unsigned int)f2bf(v.x) | ((unsigned int)f2bf(v.y) << 16);
                unsigned int p1 = (unsigned int)f2bf(v.z) | ((unsigned int)f2bf(v.w) << 16);
                *(uint2*)(C + (size_t)node * ocols + chan) = make_uint2(p0, p1);
            }
        }
        return;
    }
    // ---- GAT path: head h = blockIdx.y ----
    if (t < 128) { sas[t] = 0.f; sad[t] = 0.f; smax[t] = 0.f; }
    __syncthreads();
    int h = blockIdx.y;
    float4 asv[4], adv[4];
#pragma unroll
    for (int mt = 0; mt < 4; ++mt) {
        int cbase = h * 128 + (wr << 6) + mt * 16 + (lane >> 4) * 4;
        asv[mt] = *(const float4*)(att_s + cbase);
        adv[mt] = *(const float4*)(att_d + cbase);
    }
#pragma unroll
    for (int nt = 0; nt < 4; ++nt) {
        float ds = 0.f, dd = 0.f, mx = 0.f;
#pragma unroll
        for (int mt = 0; mt < 4; ++mt) {
            f32x4 v = acc[mt][nt];
            ds += dot4(v, asv[mt]);
            dd += dot4(v, adv[mt]);
            mx = fmaxf(mx, fmaxf(fmaxf(fabsf(v.x), fabsf(v.y)),
                                 fmaxf(fabsf(v.z), fabsf(v.w))));
        }
        ds += __shfl_xor(ds, 16); ds += __shfl_xor(ds, 32);
        dd += __shfl_xor(dd, 16); dd += __shfl_xor(dd, 32);
        mx = fmaxf(mx, __shfl_xor(mx, 16));
        mx = fmaxf(mx, __shfl_xor(mx, 32));
        if (lane < 16) {
            int sl = (wc << 6) + nt * 16 + lane;
            atomicAdd(&sas[sl], ds);
            atomicAdd(&sad[sl], dd);
            atomicMax((int*)&smax[sl], __float_as_int(mx));  // mx >= 0
        }
    }
    __syncthreads();
    if (t < 128) {
        int node = (blockIdx.x << 7) + t;
        if (node < nrows) {
            asn_sc[(size_t)node * 8 + h] = sas[t];
            asn_sc[(size_t)node * 8 + 4 + h] = smax[t] * (1.f / 127.f);
        }
    } else {
        int t2 = t - 128;
        int node = (blockIdx.x << 7) + t2;
        if (node < nrows) a_d[(size_t)node * 4 + h] = sad[t2];
    }
    // quantize fp32 acc -> biased uint8 (q+128), exact per-(node,head) scale
#pragma unroll
    for (int nt = 0; nt < 4; ++nt) {
        int node = nbase + nt * 16 + (lane & 15);
        if (node >= nrows) continue;
        float mxv = smax[(wc << 6) + nt * 16 + (lane & 15)];
        float rs = mxv > 0.f ? 127.f / mxv : 0.f;
#pragma unroll
        for (int mt = 0; mt < 4; ++mt) {
            int chan = (wr << 6) + mt * 16 + (lane >> 4) * 4;
            f32x4 v = acc[mt][nt];
            int q0 = (int)rintf(v.x * rs) + 128, q1 = (int)rintf(v.y * rs) + 128;
            int q2 = (int)rintf(v.z * rs) + 128, q3 = (int)rintf(v.w * rs) + 128;
            unsigned int pk = (q0 & 0xff) | ((q1 & 0xff) << 8) |
                              ((q2 & 0xff) << 16) | ((unsigned int)(q3 & 0xff) << 24);
            *(unsigned int*)(hgq + (size_t)node * 512 + h * 128 + chan) = pk;
        }
    }
}

// ---------------- fused GCN: paired 8B CSR record, 4 rows in flight ---------
__global__ __launch_bounds__(TPB) void k_gcn_fused(const unsigned short* __restrict__ hb,
                                                   const int2* __restrict__ csr_sw,
                                                   const int* __restrict__ row_start,
                                                   const float* __restrict__ dis,
                                                   const float* __restrict__ b,
                                                   const float* __restrict__ g,
                                                   const float* __restrict__ beta,
                                                   unsigned short* __restrict__ out, int n) {
    int node = (blockIdx.x * TPB + threadIdx.x) >> 6;
    int lane = threadIdx.x & 63;
    if (node >= n) return;
    int s0 = row_start[node], s1 = row_start[node + 1];
    float dn = dis[node];
    const uint4* hq = (const uint4*)hb;   // row = 16 uint4 (128 bf16)
    int q = lane >> 4, fl = lane & 15;
    float acc[8];
#pragma unroll
    for (int i = 0; i < 8; ++i) acc[i] = 0.f;
    for (int base = s0; base < s1; base += 64) {
        int cnt = min(64, s1 - base);
        int sidx = 0; float w = 0.f;
        if (lane < cnt) {
            int2 sw = csr_sw[base + lane];
            sidx = sw.x;
            w = __int_as_float(sw.y);
        }
        for (int j = 0; j < cnt; j += 16) {
            int j0 = j + q, j1 = j + 4 + q, j2 = j + 8 + q, j3 = j + 12 + q;
            int   sA = __shfl(sidx, j0), sB = __shfl(sidx, j1);
            int   sC = __shfl(sidx, j2), sD = __shfl(sidx, j3);
            float wA = __shfl(w, j0), wB = __shfl(w, j1);
            float wC = __shfl(w, j2), wD = __shfl(w, j3);
            uint4 uA = hq[(size_t)sA * 16 + fl];
            uint4 uB = hq[(size_t)sB * 16 + fl];
            uint4 uC = hq[(size_t)sC * 16 + fl];
            uint4 uD = hq[(size_t)sD * 16 + fl];
            float2 p0 = bf2x(uA.x), p1 = bf2x(uA.y), p2 = bf2x(uA.z), p3 = bf2x(uA.w);
            acc[0] += wA * p0.x; acc[1] += wA * p0.y;
            acc[2] += wA * p1.x; acc[3] += wA * p1.y;
            acc[4] += wA * p2.x; acc[5] += wA * p2.y;
            acc[6] += wA * p3.x; acc[7] += wA * p3.y;
            p0 = bf2x(uB.x); p1 = bf2x(uB.y); p2 = bf2x(uB.z); p3 = bf2x(uB.w);
            acc[0] += wB * p0.x; acc[1] += wB * p0.y;
            acc[2] += wB * p1.x; acc[3] += wB * p1.y;
            acc[4] += wB * p2.x; acc[5] += wB * p2.y;
            acc[6] += wB * p3.x; acc[7] += wB * p3.y;
            p0 = bf2x(uC.x); p1 = bf2x(uC.y); p2 = bf2x(uC.z); p3 = bf2x(uC.w);
            acc[0] += wC * p0.x; acc[1] += wC * p0.y;
            acc[2] += wC * p1.x; acc[3] += wC * p1.y;
            acc[4] += wC * p2.x; acc[5] += wC * p2.y;
            acc[6] += wC * p3.x; acc[7] += wC * p3.y;
            p0 = bf2x(uD.x); p1 = bf2x(uD.y); p2 = bf2x(uD.z); p3 = bf2x(uD.w);
            acc[0] += wD * p0.x; acc[1] += wD * p0.y;
            acc[2] += wD * p1.x; acc[3] += wD * p1.y;
            acc[4] += wD * p2.x; acc[5] += wD * p2.y;
            acc[6] += wD * p3.x; acc[7] += wD * p3.y;
        }
    }
#pragma unroll
    for (int i = 0; i < 8; ++i) {
        acc[i] += __shfl_xor(acc[i], 16);
        acc[i] += __shfl_xor(acc[i], 32);
    }
    float sl = dn * dn;
    uint4 us = hq[(size_t)node * 16 + fl];
    float2 h0 = bf2x(us.x), h1 = bf2x(us.y), h2 = bf2x(us.z), h3 = bf2x(us.w);
    float4 b0 = ((const float4*)b)[fl * 2], b1 = ((const float4*)b)[fl * 2 + 1];
    float v[8];
    v[0] = dn * acc[0] + sl * h0.x + b0.x;
    v[1] = dn * acc[1] + sl * h0.y + b0.y;
    v[2] = dn * acc[2] + sl * h1.x + b0.z;
    v[3] = dn * acc[3] + sl * h1.y + b0.w;
    v[4] = dn * acc[4] + sl * h2.x + b1.x;
    v[5] = dn * acc[5] + sl * h2.y + b1.y;
    v[6] = dn * acc[6] + sl * h3.x + b1.z;
    v[7] = dn * acc[7] + sl * h3.y + b1.w;
    float s = 0.f, sq = 0.f;
#pragma unroll
    for (int i = 0; i < 8; ++i) { s += v[i]; sq += v[i] * v[i]; }
#pragma unroll
    for (int o = 8; o > 0; o >>= 1) {
        s  += __shfl_xor(s, o);
        sq += __shfl_xor(sq, o);
    }
    float mu = s * (1.f / 128.f);
    float var = sq * (1.f / 128.f) - mu * mu;
    float rstd = rsqrtf(var + 1e-5f);
    float4 g0  = ((const float4*)g)[fl * 2],    g1v = ((const float4*)g)[fl * 2 + 1];
    float4 bt0 = ((const float4*)beta)[fl * 2], bt1 = ((const float4*)beta)[fl * 2 + 1];
    float o0 = fmaxf((v[0] - mu) * rstd * g0.x + bt0.x, 0.f);
    float o1 = fmaxf((v[1] - mu) * rstd * g0.y + bt0.y, 0.f);
    float o2 = fmaxf((v[2] - mu) * rstd * g0.z + bt0.z, 0.f);
    float o3 = fmaxf((v[3] - mu) * rstd * g0.w + bt0.w, 0.f);
    float o4 = fmaxf((v[4] - mu) * rstd * g1v.x + bt1.x, 0.f);
    float o5 = fmaxf((v[5] - mu) * rstd * g1v.y + bt1.y, 0.f);
    float o6 = fmaxf((v[6] - mu) * rstd * g1v.z + bt1.z, 0.f);
    float o7 = fmaxf((v[7] - mu) * rstd * g1v.w + bt1.w, 0.f);
    if (q == 0) {
        uint4 pk;
        pk.x = (unsigned int)f2bf(o0) | ((unsigned int)f2bf(o1) << 16);
        pk.y = (unsigned int)f2bf(o2) | ((unsigned int)f2bf(o3) << 16);
        pk.z = (unsigned int)f2bf(o4) | ((unsigned int)f2bf(o5) << 16);
        pk.w = (unsigned int)f2bf(o6) | ((unsigned int)f2bf(o7) << 16);
        ((uint4*)out)[(size_t)node * 16 + fl] = pk;
    }
}

// ---------------- fused GAT: biased-uint8 gather + wsum bias correction -----
__global__ __launch_bounds__(TPB) void k_gat_fused(const unsigned char* __restrict__ hgq,
                                                   const float* __restrict__ asn_sc,
                                                   const float* __restrict__ a_d,
                                                   const int2* __restrict__ csr_sw,
                                                   const int* __restrict__ row_start,
                                                   const float* __restrict__ gat_b,
                                                   float* __restrict__ node_out, int n) {
    __shared__ int   ssrc[4][64];
    __shared__ float swt[4][4][65];
    int node = (blockIdx.x * TPB + threadIdx.x) >> 6;
    int lane = threadIdx.x & 63;
    int wid = threadIdx.x >> 6;
    if (node >= n) return;
    int s0 = row_start[node], s1 = row_start[node + 1];
    int h = lane >> 4, fl = lane & 15;
    const float4* asc4 = (const float4*)asn_sc;   // [node*2]=a_s, [node*2+1]=scale
    float4 ad = ((const float4*)a_d)[node];
    float4 asn = asc4[node * 2];
    float4 scn = asc4[node * 2 + 1];
    float4 eself;
    eself.x = __expf(lrelu(asn.x + ad.x));
    eself.y = __expf(lrelu(asn.y + ad.y));
    eself.z = __expf(lrelu(asn.z + ad.z));
    eself.w = __expf(lrelu(asn.w + ad.w));
    const uint2* hq2 = (const uint2*)hgq;         // row = 64 uint2 (512 bytes)
    int hoff = (h << 4) + fl;
    float acc[8];
    float wsum;
    {
        float wsh = sel4(eself, h) * sel4(scn, h);
        wsum = wsh;
        float f[8];
        unp8u(hq2[(size_t)node * 64 + hoff], f);
#pragma unroll
        for (int i = 0; i < 8; ++i) acc[i] = wsh * f[i];
    }
    float4 den = make_float4(0.f, 0.f, 0.f, 0.f);
    for (int base = s0; base < s1; base += 64) {
        int cnt = min(64, s1 - base);
        int sidx = 0;
        float4 w4 = make_float4(0.f, 0.f, 0.f, 0.f);
        if (lane < cnt) {
            sidx = csr_sw[base + lane].x;
            float4 a = asc4[sidx * 2];
            float4 sc = asc4[sidx * 2 + 1];
            float4 e4;
            e4.x = __expf(lrelu(a.x + ad.x));
            e4.y = __expf(lrelu(a.y + ad.y));
            e4.z = __expf(lrelu(a.z + ad.z));
            e4.w = __expf(lrelu(a.w + ad.w));
            den.x += e4.x; den.y += e4.y; den.z += e4.z; den.w += e4.w;
            w4 = make_float4(e4.x * sc.x, e4.y * sc.y, e4.z * sc.z, e4.w * sc.w);
        }
        ssrc[wid][lane] = sidx;
        swt[wid][0][lane] = w4.x;
        swt[wid][1][lane] = w4.y;
        swt[wid][2][lane] = w4.z;
        swt[wid][3][lane] = w4.w;
        int j = 0;
        for (; j + 4 <= cnt; j += 4) {   // 4 independent 512B row loads in flight
            int sa = ssrc[wid][j + 0], sb = ssrc[wid][j + 1];
            int sc = ssrc[wid][j + 2], sd = ssrc[wid][j + 3];
            float wa = swt[wid][h][j + 0], wb = swt[wid][h][j + 1];
            float wc = swt[wid][h][j + 2], wd = swt[wid][h][j + 3];
            wsum += wa + wb + wc + wd;
            uint2 ua = hq2[(size_t)sa * 64 + hoff];
            uint2 ub = hq2[(size_t)sb * 64 + hoff];
            uint2 uc = hq2[(size_t)sc * 64 + hoff];
            uint2 ud = hq2[(size_t)sd * 64 + hoff];
            float f[8];
            unp8u(ua, f);
#pragma unroll
            for (int i = 0; i < 8; ++i) acc[i] += wa * f[i];
            unp8u(ub, f);
#pragma unroll
            for (int i = 0; i < 8; ++i) acc[i] += wb * f[i];
            unp8u(uc, f);
#pragma unroll
            for (int i = 0; i < 8; ++i) acc[i] += wc * f[i];
            unp8u(ud, f);
#pragma unroll
            for (int i = 0; i < 8; ++i) acc[i] += wd * f[i];
        }
        for (; j < cnt; ++j) {
            int s = ssrc[wid][j];
            float wj = swt[wid][h][j];
            wsum += wj;
            float f[8];
            unp8u(hq2[(size_t)s * 64 + hoff], f);
#pragma unroll
            for (int i = 0; i < 8; ++i) acc[i] += wj * f[i];
        }
    }
#pragma unroll
    for (int o = 32; o > 0; o >>= 1) {
        den.x += __shfl_xor(den.x, o);
        den.y += __shfl_xor(den.y, o);
        den.z += __shfl_xor(den.z, o);
        den.w += __shfl_xor(den.w, o);
    }
    den.x += eself.x; den.y += eself.y; den.z += eself.z; den.w += eself.w;
    float winv = 0.25f / sel4(den, h);
    float corr = 128.f * wsum;
#pragma unroll
    for (int j = 0; j < 8; ++j) acc[j] = (acc[j] - corr) * winv;
#pragma unroll
    for (int j = 0; j < 8; ++j) acc[j] += __shfl_xor(acc[j], 16);
#pragma unroll
    for (int j = 0; j < 8; ++j) acc[j] += __shfl_xor(acc[j], 32);
    float4 gb0 = ((const float4*)gat_b)[fl * 2], gb1 = ((const float4*)gat_b)[fl * 2 + 1];
    if (lane < 16) {
        float4* o4 = (float4*)(node_out + (size_t)node * 128 + fl * 8);
        o4[0] = make_float4(fmaxf(acc[0] + gb0.x, 0.f), fmaxf(acc[1] + gb0.y, 0.f),
                            fmaxf(acc[2] + gb0.z, 0.f), fmaxf(acc[3] + gb0.w, 0.f));
        o4[1] = make_float4(fmaxf(acc[4] + gb1.x, 0.f), fmaxf(acc[5] + gb1.y, 0.f),
                            fmaxf(acc[6] + gb1.z, 0.f), fmaxf(acc[7] + gb1.w, 0.f));
    }
}

// ---------------- pooling: run-batched atomics over sorted batch ------------
__global__ __launch_bounds__(TPB) void k_pool(const float* __restrict__ node_out,
                                              const int* __restrict__ batch,
                                              float* __restrict__ mean_acc,
                                              float* __restrict__ max_acc,
                                              float* __restrict__ cnt, int n) {
    int wave = (blockIdx.x * TPB + threadIdx.x) >> 6;
    int lane = threadIdx.x & 63;
    int n0 = wave * 16;
    if (n0 >= n) return;
    int n1 = min(n0 + 16, n);
    float2 bsum = make_float2(0.f, 0.f), bmax = make_float2(0.f, 0.f);
    int cur_g = batch[n0];
    int cntloc = 0;
    for (int nn = n0; nn < n1; ++nn) {
        int g = batch[nn];
        if (g != cur_g) {
            float* ma = mean_acc + cur_g * 128 + lane * 2;
            atomicAdd(ma + 0, bsum.x);
            atomicAdd(ma + 1, bsum.y);
            int* mxp = (int*)(max_acc + cur_g * 128 + lane * 2);
            atomicMax(mxp + 0, __float_as_int(bmax.x));
            atomicMax(mxp + 1, __float_as_int(bmax.y));
            if (lane == 0) atomicAdd(&cnt[cur_g], (float)cntloc);
            bsum = make_float2(0.f, 0.f);
            bmax = make_float2(0.f, 0.f);
            cntloc = 0;
            cur_g = g;
        }
        float2 o = ((const float2*)node_out)[(size_t)nn * 64 + lane];
        bsum.x += o.x; bsum.y += o.y;
        bmax.x = fmaxf(bmax.x, o.x); bmax.y = fmaxf(bmax.y, o.y);
        ++cntloc;
    }
    float* ma = mean_acc + cur_g * 128 + lane * 2;
    atomicAdd(ma + 0, bsum.x);
    atomicAdd(ma + 1, bsum.y);
    int* mxp = (int*)(max_acc + cur_g * 128 + lane * 2);
    atomicMax(mxp + 0, __float_as_int(bmax.x));
    atomicMax(mxp + 1, __float_as_int(bmax.y));
    if (lane == 0) atomicAdd(&cnt[cur_g], (float)cntloc);
}

__global__ __launch_bounds__(TPB) void k_pool_final(const float* __restrict__ mean_acc,
                                                    const float* __restrict__ max_acc,
                                                    const float* __restrict__ cnt,
                                                    float* __restrict__ gout, int g128) {
    int i = blockIdx.x * TPB + threadIdx.x;
    if (i >= g128) return;
    int g = i >> 7, d = i & 127;
    float c = fmaxf(cnt[g], 1.f);
    gout[g * 256 + d] = mean_acc[i] / c;
    gout[g * 256 + 128 + d] = max_acc[i];
}

// ---------------------------------------------------------------------------
extern "C" void kernel_launch(void* const* d_in, const int* in_sizes, int n_in,
                              void* d_out, int out_size, void* d_ws, size_t ws_size,
                              hipStream_t stream) {
    const float* x       = (const float*)d_in[0];
    const int*   ei      = (const int*)d_in[1];
    const int*   batch   = (const int*)d_in[2];
    const float* W1      = (const float*)d_in[3];
    const float* b1      = (const float*)d_in[4];
    const float* g1      = (const float*)d_in[5];
    const float* beta1   = (const float*)d_in[6];
    const float* W2      = (const float*)d_in[7];
    const float* b2      = (const float*)d_in[8];
    const float* g2      = (const float*)d_in[9];
    const float* beta2   = (const float*)d_in[10];
    const float* gat_W   = (const float*)d_in[11];
    const float* att_src = (const float*)d_in[12];
    const float* att_dst = (const float*)d_in[13];
    const float* gat_b   = (const float*)d_in[14];

    const int N = in_sizes[0] / 128;
    const int E = in_sizes[1] / 2;
    const int G = (out_size - N * 128) / 256;
    const int* src = ei;
    const int* dst = ei + E;

    float* ws = (float*)d_ws;
    float* dis      = ws; ws += N;
    float* asn_sc   = ws; ws += (size_t)N * 8;   // {a_s[4], scale[4]} per node
    float* a_d      = ws; ws += N * 4;
    // zero-init block: mean_acc, max_acc, cnt, deg contiguous -> one memset
    float* mean_acc = ws; ws += G * 128;
    float* max_acc  = ws; ws += G * 128;
    float* cnt      = ws; ws += G;
    int* deg        = (int*)ws; ws += N;
    int2* csr_sw    = (int2*)ws; ws += (size_t)E * 2;
    unsigned short* Hbf = (unsigned short*)ws; ws += (size_t)N * 64;
    unsigned short* Bbf = (unsigned short*)ws; ws += (size_t)N * 64;
    unsigned short* Cbf = (unsigned short*)ws; ws += (size_t)N * 64;
    unsigned char* hgq  = (unsigned char*)ws; ws += (size_t)N * 128;  // N*512 bytes
    unsigned short* Wt1 = (unsigned short*)ws; ws += 128 * 64;
    unsigned short* Wt2 = (unsigned short*)ws; ws += 128 * 64;
    unsigned short* Wtg = (unsigned short*)ws; ws += 512 * 64;
    int* part      = (int*)ws; ws += 256;
    int* row_start = (int*)ws; ws += N + 1;
    int* cursor    = (int*)ws; ws += N + 1;

    float* gout = (float*)d_out;        // [G, 256]
    float* node_out = gout + G * 256;   // [N, 128]

    auto cdiv = [](long a, long b) { return (int)((a + b - 1) / b); };
    const int nb = cdiv(N, TPB);

    // one memset zeroes mean_acc/max_acc/cnt/deg
    hipMemsetAsync(mean_acc, 0, (size_t)(G * 256 + G + N) * 4, stream);
    k_hist<<<cdiv(E, TPB), TPB, 0, stream>>>(dst, deg, E);
    k_scan_part_wt<<<nb + cdiv(98304, TPB), TPB, 0, stream>>>(deg, part, N, nb,
                                                              W1, W2, gat_W, Wt1, Wt2, Wtg);
    k_scan_apply<<<nb, TPB, 0, stream>>>(deg, part, row_start, cursor, dis, N, E);

    // gemm1 (fp32 x) merged with CSR scatter (independent work)
    const int gb = cdiv(N, 128);
    k_gemm1_scatter<<<gb + cdiv(E, TPB), TPB, 0, stream>>>(x, Wt1, Hbf, N, gb,
                                                           src, dst, dis, cursor,
                                                           csr_sw, E);
    k_gcn_fused<<<cdiv((long)N * 64, TPB), TPB, 0, stream>>>(Hbf, csr_sw, row_start, dis,
                                                             b1, g1, beta1, Bbf, N);
    // GCN layer 2
    k_gemm_mfma<<<dim3(cdiv(N, 128), 1), TPB, 0, stream>>>(Bbf, Wt2, Hbf, N, 128,
                                                           nullptr, nullptr, nullptr, nullptr, nullptr);
    k_gcn_fused<<<cdiv((long)N * 64, TPB), TPB, 0, stream>>>(Hbf, csr_sw, row_start, dis,
                                                             b2, g2, beta2, Cbf, N);
    // GAT gemm: dots + biased-uint8 quantize in epilogue
    k_gemm_mfma<<<dim3(cdiv(N, 128), 4), TPB, 0, stream>>>(Cbf, Wtg, nullptr, N, 512,
                                                           att_src, att_dst, asn_sc, a_d, hgq);
    k_gat_fused<<<cdiv((long)N * 64, TPB), TPB, 0, stream>>>(hgq, asn_sc, a_d, csr_sw, row_start,
                                                             gat_b, node_out, N);

    // pooling
    k_pool<<<cdiv((long)cdiv(N, 16) * 64, TPB), TPB, 0, stream>>>(node_out, batch,
                                                                  mean_acc, max_acc, cnt, N);
    k_pool_final<<<cdiv((long)G * 128, TPB), TPB, 0, stream>>>(mean_acc, max_acc, cnt, gout, G * 128);
}